// Round 3
// baseline (1534.089 us; speedup 1.0000x reference)
//
#include <hip/hip_runtime.h>
#include <math.h>

constexpr int NB=128;
constexpr int NH0=200, NW0=128, NC0=6;
constexpr int NH1=100, NW1=64,  NC1=8;
constexpr int NH2=20,  NW2=32,  NC2=16;
constexpr int NH3=4,   NW3=16,  NC3=32;
constexpr int LAT=4, NPp=11, HID=16, NT=10;
constexpr float BOUNDf=5.0f;
constexpr float LOG2PI=1.8378770664093453f;

__device__ __forceinline__ float fexpf(float v){ return __expf(v); }
__device__ __forceinline__ float flogf(float v){ return __logf(v); }
__device__ __forceinline__ float softplusf(float v){ return v>20.f ? v : __logf(1.f+__expf(v)); }
__device__ __forceinline__ float lrelu(float v){ return v>0.f ? v : 0.01f*v; }

// ============ conv1 (3x3,6->8) + lrelu + pool2x2, LDS-tiled, computes m0,m1 ============
__global__ __launch_bounds__(256) void k_conv1pool(
    const float* __restrict__ x, const float* __restrict__ w1, const float* __restrict__ b1,
    float* __restrict__ y1p, unsigned char* __restrict__ m0, unsigned char* __restrict__ m1){
  __shared__ float xs[6][34][34];
  __shared__ float ws1[54][8];
  __shared__ unsigned char ms[34][34];
  int blk = blockIdx.x;
  int b  = blk / 28;
  int t  = blk % 28;
  int th = t / 4, tw = t % 4;
  int hp0 = th*16, wp0 = tw*16;
  int h0 = hp0*2 - 1, w0 = wp0*2 - 1;
  int tid = threadIdx.x;
  for (int i=tid;i<432;i+=256) ws1[i>>3][i&7] = w1[i];
  for (int i=tid;i<6*34*34;i+=256){
    int ci=i/1156; int rem=i-ci*1156; int r=rem/34, c=rem-r*34;
    int h=h0+r, w=w0+c;
    float v=0.f;
    if (h>=0 && h<NH0 && w>=0 && w<NW0) v = x[((size_t)(b*NC0+ci)*NH0+h)*NW0+w];
    xs[ci][r][c]=v;
  }
  __syncthreads();
  for (int i=tid;i<1156;i+=256){
    int r=i/34, c=i-r*34;
    bool any=false;
    #pragma unroll
    for (int ci=0;ci<6;ci++) any |= (xs[ci][r][c]!=0.f);
    ms[r][c] = any?1:0;
  }
  __syncthreads();
  for (int i=tid;i<1024;i+=256){
    int r=(i>>5)+1, c=(i&31)+1;
    int h=h0+r, w=w0+c;
    if (h<NH0) m0[(b*NH0+h)*NW0+w] = ms[r][c];
  }
  int lhp = tid>>4, lwp = tid&15;
  int hp = hp0+lhp, wp = wp0+lwp;
  if (hp < NH1){
    float best[8];
    #pragma unroll
    for (int co=0;co<8;co++) best[co]=-1e30f;
    float bb[8];
    #pragma unroll
    for (int co=0;co<8;co++) bb[co]=b1[co];
    bool many=false;
    #pragma unroll
    for (int i=0;i<2;i++)
    #pragma unroll
    for (int j=0;j<2;j++){
      int r = lhp*2+i+1, c = lwp*2+j+1;
      if (!ms[r][c]) continue;
      many=true;
      float a[8];
      #pragma unroll
      for (int co=0;co<8;co++) a[co]=bb[co];
      #pragma unroll
      for (int kh=0;kh<3;kh++)
      #pragma unroll
      for (int kw=0;kw<3;kw++)
      #pragma unroll
      for (int ci=0;ci<6;ci++){
        float v = xs[ci][r-1+kh][c-1+kw];
        const float* wv = ws1[(kh*3+kw)*6+ci];
        #pragma unroll
        for (int co=0;co<8;co++) a[co]=fmaf(v,wv[co],a[co]);
      }
      #pragma unroll
      for (int co=0;co<8;co++) best[co]=fmaxf(best[co], lrelu(a[co]));
    }
    float* yp = y1p + (((size_t)b*NH1+hp)*NW1+wp)*8;
    #pragma unroll
    for (int co=0;co<8;co++) yp[co] = many?best[co]:0.f;
    m1[(b*NH1+hp)*NW1+wp] = many?1:0;
  }
}

// ============ conv2 (3x3,8->16) + lrelu + pool 5x2, LDS-tiled ============
// out tile 10x16; input halo 52x34 (SoA, pad 35) staged in LDS
__global__ __launch_bounds__(256) void k_conv2pool(
    const float* __restrict__ yin, const unsigned char* __restrict__ m1,
    const float* __restrict__ w2, const float* __restrict__ b2,
    float* __restrict__ yout, unsigned char* __restrict__ m2){
  __shared__ float ys[8][52][35];
  __shared__ unsigned char msl[52][35];
  __shared__ float w2s[72][16];
  __shared__ float b2s[16];
  int blk = blockIdx.x;
  int b  = blk >> 2;
  int t  = blk & 3;
  int th = t >> 1, tw = t & 1;
  int r0 = th*50 - 1, c0 = tw*32 - 1;
  int tid = threadIdx.x;
  for (int i=tid;i<1152;i+=256) w2s[i>>4][i&15] = w2[i];
  if (tid<16) b2s[tid]=b2[tid];
  for (int p=tid;p<52*34;p+=256){
    int r=p/34, c=p-(p/34)*34;
    int h1=r0+r, w1c=c0+c;
    bool ok = (h1>=0 && h1<NH1 && w1c>=0 && w1c<NW1);
    msl[r][c] = ok ? m1[(b*NH1+h1)*NW1+w1c] : 0;
    float4 v0=make_float4(0,0,0,0), v1=v0;
    if (ok){
      const float4* pp = (const float4*)(yin + (((size_t)b*NH1+h1)*NW1+w1c)*8);
      v0=pp[0]; v1=pp[1];
    }
    ys[0][r][c]=v0.x; ys[1][r][c]=v0.y; ys[2][r][c]=v0.z; ys[3][r][c]=v0.w;
    ys[4][r][c]=v1.x; ys[5][r][c]=v1.y; ys[6][r][c]=v1.z; ys[7][r][c]=v1.w;
  }
  __syncthreads();
  if (tid < 160){
    int lh = tid>>4, lw = tid&15;
    int h2 = th*10+lh, w2c = tw*16+lw;
    float best[16];
    #pragma unroll
    for (int co=0;co<16;co++) best[co]=-1e30f;
    bool many=false;
    #pragma unroll
    for (int i=0;i<5;i++)
    #pragma unroll
    for (int j=0;j<2;j++){
      int r = lh*5+i+1, c = lw*2+j+1;
      if (!msl[r][c]) continue;
      many=true;
      float a[16];
      #pragma unroll
      for (int co=0;co<16;co++) a[co]=b2s[co];
      #pragma unroll
      for (int kh=0;kh<3;kh++)
      #pragma unroll
      for (int kw=0;kw<3;kw++)
      #pragma unroll
      for (int ci=0;ci<8;ci++){
        float v = ys[ci][r-1+kh][c-1+kw];
        const float* wr = w2s[(kh*3+kw)*8+ci];
        #pragma unroll
        for (int co=0;co<16;co++) a[co]=fmaf(v,wr[co],a[co]);
      }
      #pragma unroll
      for (int co=0;co<16;co++) best[co]=fmaxf(best[co], lrelu(a[co]));
    }
    float4 o0,o1,o2,o3;
    if (many){
      o0=make_float4(best[0],best[1],best[2],best[3]);
      o1=make_float4(best[4],best[5],best[6],best[7]);
      o2=make_float4(best[8],best[9],best[10],best[11]);
      o3=make_float4(best[12],best[13],best[14],best[15]);
    } else { o0=make_float4(0,0,0,0); o1=o0; o2=o0; o3=o0; }
    float4* op = (float4*)(yout + (((size_t)b*NH2+h2)*NW2+w2c)*16);
    op[0]=o0; op[1]=o1; op[2]=o2; op[3]=o3;
    m2[(b*NH2+h2)*NW2+w2c] = many?1:0;
  }
}

// ============ conv3 (3x3,16->32) + lrelu + pool 5x2, per-batch LDS-tiled ============
__global__ __launch_bounds__(256) void k_conv3pool(
    const float* __restrict__ yin, const unsigned char* __restrict__ m2,
    const float* __restrict__ w3, const float* __restrict__ b3,
    float* __restrict__ yout, unsigned char* __restrict__ m3){
  __shared__ float ys[16][20][33];
  __shared__ unsigned char msl[20][32];
  __shared__ float w3s[144][32];
  __shared__ float b3s[32];
  int b = blockIdx.x;
  int tid = threadIdx.x;
  for (int i=tid;i<4608;i+=256) w3s[i>>5][i&31] = w3[i];
  if (tid<32) b3s[tid]=b3[tid];
  for (int p=tid;p<640;p+=256){
    int r=p>>5, c=p&31;
    msl[r][c] = m2[(b*NH2+r)*NW2+c];
    const float4* pp = (const float4*)(yin + (((size_t)b*NH2+r)*NW2+c)*16);
    float4 q0=pp[0],q1=pp[1],q2=pp[2],q3=pp[3];
    ys[0][r][c]=q0.x; ys[1][r][c]=q0.y; ys[2][r][c]=q0.z; ys[3][r][c]=q0.w;
    ys[4][r][c]=q1.x; ys[5][r][c]=q1.y; ys[6][r][c]=q1.z; ys[7][r][c]=q1.w;
    ys[8][r][c]=q2.x; ys[9][r][c]=q2.y; ys[10][r][c]=q2.z; ys[11][r][c]=q2.w;
    ys[12][r][c]=q3.x; ys[13][r][c]=q3.y; ys[14][r][c]=q3.z; ys[15][r][c]=q3.w;
  }
  __syncthreads();
  int p = tid>>2, coq = tid&3;
  int co0 = coq*8;
  int hp = p>>4, wp = p&15;
  float best[8];
  #pragma unroll
  for (int co=0;co<8;co++) best[co]=-1e30f;
  bool many=false;
  #pragma unroll
  for (int i=0;i<5;i++)
  #pragma unroll
  for (int j=0;j<2;j++){
    int h2 = hp*5+i, w2c = wp*2+j;
    if (!msl[h2][w2c]) continue;
    many=true;
    float a[8];
    #pragma unroll
    for (int co=0;co<8;co++) a[co]=b3s[co0+co];
    #pragma unroll
    for (int kh=0;kh<3;kh++){
      int hh=h2+kh-1;
      if (hh<0||hh>=NH2) continue;
      #pragma unroll
      for (int kw=0;kw<3;kw++){
        int ww=w2c+kw-1;
        if (ww<0||ww>=NW2) continue;
        #pragma unroll
        for (int ci=0;ci<16;ci++){
          float v = ys[ci][hh][ww];
          const float* wr = w3s[(kh*3+kw)*16+ci];
          #pragma unroll
          for (int co=0;co<8;co++) a[co]=fmaf(v,wr[co0+co],a[co]);
        }
      }
    }
    #pragma unroll
    for (int co=0;co<8;co++) best[co]=fmaxf(best[co], lrelu(a[co]));
  }
  float4 o0,o1;
  if (many){
    o0=make_float4(best[0],best[1],best[2],best[3]);
    o1=make_float4(best[4],best[5],best[6],best[7]);
  } else { o0=make_float4(0,0,0,0); o1=o0; }
  float4* op = (float4*)(yout + ((size_t)(b*64+p))*32 + co0);
  op[0]=o0; op[1]=o1;
  if (coq==0) m3[b*64+p] = many?1:0;
}

// ============ latent head + NSF flow + kld + dec ============
__global__ __launch_bounds__(64) void k_latent(
    const float* __restrict__ y3p, const unsigned char* __restrict__ m3,
    const float* __restrict__ eps,
    const float* __restrict__ wmu, const float* __restrict__ bmu,
    const float* __restrict__ wlv, const float* __restrict__ blv,
    const float* __restrict__ wlin, const float* __restrict__ blin,
    const float* __restrict__ fW1, const float* __restrict__ fb1,
    const float* __restrict__ fW2, const float* __restrict__ fb2,
    const float* __restrict__ fW3, const float* __restrict__ fb3,
    float* __restrict__ out_mu, float* __restrict__ out_lv,
    float* __restrict__ out_kld, float* __restrict__ out_zf,
    float* __restrict__ dec)
{
  __shared__ __align__(16) float sW1[NT*HID*LAT];
  __shared__ float sb1[NT*HID];
  __shared__ __align__(16) float sW2[NT*HID*HID];
  __shared__ float sb2[NT*HID];
  __shared__ __align__(16) float sW3[NT*LAT*NPp*HID];
  __shared__ float sb3[NT*LAT*NPp];
  __shared__ float red[64];
  int tid = threadIdx.x;
  for (int i=tid;i<NT*HID*LAT;i+=64){ int j=i&3; int r=(i>>2)%HID; sW1[i]=fW1[i]*(((r%3+1)>=(j+1))?1.f:0.f); }
  for (int i=tid;i<NT*HID;i+=64){ sb1[i]=fb1[i]; sb2[i]=fb2[i]; }
  for (int i=tid;i<NT*HID*HID;i+=64){ int j=i&15; int r=(i>>4)%HID; sW2[i]=fW2[i]*(((r%3+1)>=(j%3+1))?1.f:0.f); }
  for (int i=tid;i<NT*LAT*NPp*HID;i+=64){ int j=i&15; int r=(i>>4)%(LAT*NPp); sW3[i]=fW3[i]*(((r/NPp+1)>(j%3+1))?1.f:0.f); }
  for (int i=tid;i<NT*LAT*NPp;i+=64) sb3[i]=fb3[i];
  __syncthreads();

  int b = blockIdx.x;
  int gpos = b*64 + tid;
  bool msk = m3[gpos]!=0;
  float kld_pc=0.f;
  if (msk){
    float yv[NC3];
    const float* yp = y3p + (size_t)gpos*NC3;
    #pragma unroll
    for (int c=0;c<NC3;c++) yv[c]=yp[c];
    float muv[LAT], lvv[LAT], stdv[LAT], evv[LAT], z0[LAT], z[LAT];
    #pragma unroll
    for (int l=0;l<LAT;l++){
      float a=bmu[l], g=blv[l];
      #pragma unroll
      for (int c=0;c<NC3;c++){ a=fmaf(yv[c],wmu[l*NC3+c],a); g=fmaf(yv[c],wlv[l*NC3+c],g); }
      muv[l]=a; lvv[l]=g;
      stdv[l]=fexpf(0.5f*g);
      evv[l]=eps[(size_t)gpos*LAT+l];
      z0[l]=fmaf(evv[l], stdv[l], a);
      z[l]=z0[l];
    }
    float ld_tot=0.f;
    for (int t=0;t<NT;t++){
      float h1[HID], h2[HID];
      const float* W1t = sW1 + t*HID*LAT;
      const float* b1t = sb1 + t*HID;
      float4 zv = make_float4(z[0],z[1],z[2],z[3]);
      #pragma unroll
      for (int i2=0;i2<HID;i2++){
        float4 wr = *(const float4*)(W1t + i2*4);
        float a = b1t[i2];
        a = fmaf(zv.x,wr.x, fmaf(zv.y,wr.y, fmaf(zv.z,wr.z, fmaf(zv.w,wr.w, a))));
        h1[i2]=fmaxf(a,0.f);
      }
      const float* W2t = sW2 + t*HID*HID;
      const float* b2t = sb2 + t*HID;
      #pragma unroll
      for (int i2=0;i2<HID;i2++){
        float a=b2t[i2];
        const float4* wr = (const float4*)(W2t + i2*HID);
        #pragma unroll
        for (int q=0;q<4;q++){
          float4 w4 = wr[q];
          a = fmaf(h1[q*4+0],w4.x, fmaf(h1[q*4+1],w4.y, fmaf(h1[q*4+2],w4.z, fmaf(h1[q*4+3],w4.w, a))));
        }
        h2[i2]=fmaxf(a,0.f);
      }
      const float* W3t = sW3 + t*LAT*NPp*HID;
      const float* b3t = sb3 + t*LAT*NPp;
      float zn[LAT];
      #pragma unroll
      for (int l=0;l<LAT;l++){
        float p[NPp];
        #pragma unroll
        for (int r=0;r<NPp;r++){
          int rr=l*NPp+r;
          float a=b3t[rr];
          const float4* wr = (const float4*)(W3t + rr*HID);
          #pragma unroll
          for (int q=0;q<4;q++){
            float4 w4 = wr[q];
            a = fmaf(h2[q*4+0],w4.x, fmaf(h2[q*4+1],w4.y, fmaf(h2[q*4+2],w4.z, fmaf(h2[q*4+3],w4.w, a))));
          }
          p[r]=a;
        }
        float mw=fmaxf(fmaxf(p[0],p[1]),fmaxf(p[2],p[3]));
        float e0=fexpf(p[0]-mw), e1=fexpf(p[1]-mw), e2=fexpf(p[2]-mw), e3=fexpf(p[3]-mw);
        float wsc=10.f/(e0+e1+e2+e3);
        float xk1=fmaf(e0,wsc,-BOUNDf), xk2=fmaf(e1,wsc,xk1), xk3=fmaf(e2,wsc,xk2), xk4=fmaf(e3,wsc,xk3);
        float mh=fmaxf(fmaxf(p[4],p[5]),fmaxf(p[6],p[7]));
        float f0=fexpf(p[4]-mh), f1=fexpf(p[5]-mh), f2=fexpf(p[6]-mh), f3=fexpf(p[7]-mh);
        float hsc=10.f/(f0+f1+f2+f3);
        float yk1=fmaf(f0,hsc,-BOUNDf), yk2=fmaf(f1,hsc,yk1), yk3=fmaf(f2,hsc,yk2), yk4=fmaf(f3,hsc,yk3);
        float dk1=softplusf(p[8]), dk2=softplusf(p[9]), dk3=softplusf(p[10]);
        float xv=z[l];
        bool inside = (xv>=-BOUNDf)&&(xv<=BOUNDf);
        float xc=fminf(fmaxf(xv,-BOUNDf),BOUNDf);
        float x0=-BOUNDf, x1=xk1, y0=-BOUNDf, y1=yk1, d0=1.f, d1=dk1;
        if (xc>=xk1){x0=xk1;x1=xk2;y0=yk1;y1=yk2;d0=dk1;d1=dk2;}
        if (xc>=xk2){x0=xk2;x1=xk3;y0=yk2;y1=yk3;d0=dk2;d1=dk3;}
        if (xc>=xk3){x0=xk3;x1=xk4;y0=yk3;y1=yk4;d0=dk3;d1=1.f;}
        float dxv=x1-x0, dyv=y1-y0;
        float sl=dyv/dxv, ttv=(xc-x0)/dxv, omt=1.f-ttv;
        float den=sl + (d1+d0-2.f*sl)*ttv*omt;
        float yo=y0 + dyv*(sl*ttv*ttv + d0*ttv*omt)/den;
        float ldv=flogf(sl*sl*(d1*ttv*ttv + 2.f*sl*ttv*omt + d0*omt*omt)) - 2.f*flogf(den);
        zn[l] = inside ? yo : xv;
        ld_tot += inside ? ldv : 0.f;
      }
      if (t<NT-1){ z[0]=zn[3]; z[1]=zn[2]; z[2]=zn[1]; z[3]=zn[0]; }
      else       { z[0]=zn[0]; z[1]=zn[1]; z[2]=zn[2]; z[3]=zn[3]; }
    }
    float lq=0.f, lp=0.f;
    #pragma unroll
    for (int l=0;l<LAT;l++){
      lq += -0.5f*evv[l]*evv[l] - 0.5f*lvv[l] - 0.5f*LOG2PI;
      lp += -0.5f*z[l]*z[l] - 0.5f*LOG2PI;
    }
    kld_pc = lq - ld_tot - lp;
    #pragma unroll
    for (int l=0;l<LAT;l++){
      out_mu[(size_t)gpos*LAT+l]=muv[l];
      out_lv[(size_t)gpos*LAT+l]=lvv[l];
      out_zf[(size_t)gpos*LAT+l]=z[l];
    }
    #pragma unroll
    for (int k2=0;k2<NC3;k2++){
      float a=blin[k2];
      #pragma unroll
      for (int l=0;l<LAT;l++) a=fmaf(z[l],wlin[k2*LAT+l],a);
      dec[(size_t)gpos*NC3+k2]=a;
    }
  } else {
    #pragma unroll
    for (int l=0;l<LAT;l++){
      out_mu[(size_t)gpos*LAT+l]=0.f;
      out_lv[(size_t)gpos*LAT+l]=0.f;
      out_zf[(size_t)gpos*LAT+l]=0.f;
    }
    for (int k2=0;k2<NC3;k2++) dec[(size_t)gpos*NC3+k2]=0.f;
  }
  red[tid]=kld_pc;
  __syncthreads();
  for (int s=32;s>0;s>>=1){ if (tid<s) red[tid]+=red[tid+s]; __syncthreads(); }
  if (tid==0) out_kld[b]=red[0];
}

// ============ fused invconv1(5,2,32,32) + conv4(3x3,32->16) -> t2, mask m2 ============
__global__ __launch_bounds__(256) void k_ic4(
    const float* __restrict__ dec, const unsigned char* __restrict__ m2,
    const float* __restrict__ u1, const float* __restrict__ bu1,
    const float* __restrict__ w4, const float* __restrict__ b4,
    float* __restrict__ t2){
  __shared__ __align__(16) float vs[12][18][32];
  __shared__ __align__(16) float w4s[288][16];
  __shared__ unsigned char msl[12][18];
  int blk = blockIdx.x;
  int b  = blk >> 2;
  int t  = blk & 3;
  int th = t >> 1, tw = t & 1;
  int h0 = th*10, w0 = tw*16;
  int tid = threadIdx.x;
  for (int i=tid;i<288*16;i+=256) w4s[i>>4][i&15] = w4[i];
  if (tid < 216){
    int lr = tid/18, lc = tid%18;
    int h2 = h0-1+lr, w2 = w0-1+lc;
    bool mk = (h2>=0 && h2<NH2 && w2>=0 && w2<NW2) && m2[(b*NH2+h2)*NW2+w2];
    msl[lr][lc] = mk?1:0;
    float acc[32];
    if (mk){
      const float* dp = dec + (((size_t)b*NH3 + h2/5)*NW3 + w2/2)*NC3;
      const float* up = u1 + ((h2%5)*2 + (w2&1))*1024;
      #pragma unroll
      for (int co=0;co<32;co++) acc[co]=bu1[co];
      #pragma unroll
      for (int ci=0;ci<32;ci++){
        float dv = dp[ci];
        const float* ur = up + ci*32;
        #pragma unroll
        for (int co=0;co<32;co++) acc[co]=fmaf(dv,ur[co],acc[co]);
      }
    } else {
      #pragma unroll
      for (int co=0;co<32;co++) acc[co]=0.f;
    }
    #pragma unroll
    for (int co=0;co<32;co++) vs[lr][lc][co]=acc[co];
  }
  __syncthreads();
  if (tid < 160){
    int lh = tid/16, lw = tid%16;
    int h2 = h0+lh, w2 = w0+lw;
    float a[16];
    if (msl[lh+1][lw+1]){
      #pragma unroll
      for (int co=0;co<16;co++) a[co]=b4[co];
      #pragma unroll
      for (int kh=0;kh<3;kh++)
      #pragma unroll
      for (int kw=0;kw<3;kw++){
        const float* vp = vs[lh+kh][lw+kw];
        #pragma unroll
        for (int ci=0;ci<32;ci++){
          float v = vp[ci];
          const float* wr = w4s[(kh*3+kw)*32+ci];
          #pragma unroll
          for (int co=0;co<16;co++) a[co]=fmaf(v,wr[co],a[co]);
        }
      }
    } else {
      #pragma unroll
      for (int co=0;co<16;co++) a[co]=0.f;
    }
    float* op = t2 + (((size_t)b*NH2+h2)*NW2+w2)*NC2;
    #pragma unroll
    for (int co=0;co<16;co++) op[co]=a[co];
  }
}

// ============ fused invconv2(5,2,16,16) + conv5(3x3,16->8) -> t4, mask m1 ============
__global__ __launch_bounds__(256) void k_ic5(
    const float* __restrict__ t2, const unsigned char* __restrict__ m1,
    const float* __restrict__ u2, const float* __restrict__ bu2,
    const float* __restrict__ w5, const float* __restrict__ b5,
    float* __restrict__ t4){
  __shared__ __align__(16) float vs[12][18][16];
  __shared__ __align__(16) float w5s[144][8];
  __shared__ unsigned char msl[12][18];
  int blk = blockIdx.x;
  int b  = blk / 40;
  int t  = blk % 40;
  int th = t >> 2, tw = t & 3;
  int h0 = th*10, w0 = tw*16;
  int tid = threadIdx.x;
  for (int i=tid;i<144*8;i+=256) w5s[i>>3][i&7] = w5[i];
  if (tid < 216){
    int lr = tid/18, lc = tid%18;
    int h1 = h0-1+lr, w1c = w0-1+lc;
    bool mk = (h1>=0 && h1<NH1 && w1c>=0 && w1c<NW1) && m1[(b*NH1+h1)*NW1+w1c];
    msl[lr][lc] = mk?1:0;
    float acc[16];
    if (mk){
      const float* dp = t2 + (((size_t)b*NH2 + h1/5)*NW2 + w1c/2)*NC2;
      const float* up = u2 + ((h1%5)*2 + (w1c&1))*256;
      #pragma unroll
      for (int co=0;co<16;co++) acc[co]=bu2[co];
      #pragma unroll
      for (int ci=0;ci<16;ci++){
        float dv = dp[ci];
        const float* ur = up + ci*16;
        #pragma unroll
        for (int co=0;co<16;co++) acc[co]=fmaf(dv,ur[co],acc[co]);
      }
    } else {
      #pragma unroll
      for (int co=0;co<16;co++) acc[co]=0.f;
    }
    #pragma unroll
    for (int co=0;co<16;co++) vs[lr][lc][co]=acc[co];
  }
  __syncthreads();
  if (tid < 160){
    int lh = tid/16, lw = tid%16;
    int h1 = h0+lh, w1c = w0+lw;
    float a[8];
    if (msl[lh+1][lw+1]){
      #pragma unroll
      for (int co=0;co<8;co++) a[co]=b5[co];
      #pragma unroll
      for (int kh=0;kh<3;kh++)
      #pragma unroll
      for (int kw=0;kw<3;kw++){
        const float* vp = vs[lh+kh][lw+kw];
        #pragma unroll
        for (int ci=0;ci<16;ci++){
          float v = vp[ci];
          const float* wr = w5s[(kh*3+kw)*16+ci];
          #pragma unroll
          for (int co=0;co<8;co++) a[co]=fmaf(v,wr[co],a[co]);
        }
      }
    } else {
      #pragma unroll
      for (int co=0;co<8;co++) a[co]=0.f;
    }
    float* op = t4 + (((size_t)b*NH1+h1)*NW1+w1c)*NC1;
    #pragma unroll
    for (int co=0;co<8;co++) op[co]=a[co];
  }
}

// ============ fused invconv3 (2,2,8,8) + conv6 (3x3,8->6), LDS-tiled ============
// out tile 16x64; t4 region 10x34 (SoA pad 36); m0 tile 18x66
__global__ __launch_bounds__(256) void k_inv3conv6(
    const float* __restrict__ t4, const unsigned char* __restrict__ m0,
    const float* __restrict__ u3, const float* __restrict__ bu3,
    const float* __restrict__ w6, const float* __restrict__ b6,
    float* __restrict__ out){
  __shared__ float ts[8][10][36];
  __shared__ unsigned char msl[18][66];
  __shared__ float u3s[4][8][8];
  __shared__ float w6s[9][8][6];
  __shared__ float bu3s[8];
  __shared__ float b6s[6];
  int blk = blockIdx.x;
  int b  = blk / 26;
  int t  = blk % 26;
  int th = t >> 1, tw = t & 1;
  int h0 = th*16, w0 = tw*64;
  int base_r = 8*th - 1, base_c = 32*tw - 1;
  int tid = threadIdx.x;
  for (int i=tid;i<256;i+=256){ int pos=i>>6; int rem=i&63; u3s[pos][rem>>3][rem&7]=u3[i]; }
  for (int i=tid;i<432;i+=256){ int tap=i/48; int rem=i%48; w6s[tap][rem/6][rem%6]=w6[i]; }
  if (tid<8) bu3s[tid]=bu3[tid];
  if (tid<6) b6s[tid]=b6[tid];
  for (int p=tid;p<340;p+=256){
    int r=p/34, c=p-(p/34)*34;
    int h1=base_r+r, w1c=base_c+c;
    float4 v0=make_float4(0,0,0,0), v1=v0;
    if (h1>=0 && h1<NH1 && w1c>=0 && w1c<NW1){
      const float4* pp = (const float4*)(t4 + (((size_t)b*NH1+h1)*NW1+w1c)*8);
      v0=pp[0]; v1=pp[1];
    }
    ts[0][r][c]=v0.x; ts[1][r][c]=v0.y; ts[2][r][c]=v0.z; ts[3][r][c]=v0.w;
    ts[4][r][c]=v1.x; ts[5][r][c]=v1.y; ts[6][r][c]=v1.z; ts[7][r][c]=v1.w;
  }
  for (int p=tid;p<18*66;p+=256){
    int r=p/66, c=p-(p/66)*66;
    int h=h0-1+r, w=w0-1+c;
    msl[r][c] = (h>=0 && h<NH0 && w>=0 && w<NW0) ? m0[(b*NH0+h)*NW0+w] : 0;
  }
  __syncthreads();
  #pragma unroll
  for (int k=0;k<4;k++){
    int p = tid + k*256;
    int lh = p>>6, lw = p&63;
    int h = h0+lh, w = w0+lw;
    if (h >= NH0) continue;
    float acc[6];
    if (msl[lh+1][lw+1]){
      #pragma unroll
      for (int co=0;co<6;co++) acc[co]=b6s[co];
      #pragma unroll
      for (int kh=0;kh<3;kh++)
      #pragma unroll
      for (int kw=0;kw<3;kw++){
        if (!msl[lh+kh][lw+kw]) continue;
        int hh = h+kh-1, ww = w+kw-1;
        int tr = (hh>>1) - base_r, tc = (ww>>1) - base_c;
        int pos = (hh&1)*2 + (ww&1);
        float v8[8];
        #pragma unroll
        for (int c8=0;c8<8;c8++) v8[c8]=bu3s[c8];
        #pragma unroll
        for (int ci=0;ci<8;ci++){
          float v = ts[ci][tr][tc];
          #pragma unroll
          for (int c8=0;c8<8;c8++) v8[c8]=fmaf(v, u3s[pos][ci][c8], v8[c8]);
        }
        const float (*wt)[6] = w6s[kh*3+kw];
        #pragma unroll
        for (int ci=0;ci<8;ci++)
          #pragma unroll
          for (int co=0;co<6;co++) acc[co]=fmaf(v8[ci], wt[ci][co], acc[co]);
      }
    } else {
      #pragma unroll
      for (int co=0;co<6;co++) acc[co]=0.f;
    }
    size_t base = (size_t)b*6*NH0*NW0 + (size_t)h*NW0 + w;
    #pragma unroll
    for (int co=0;co<6;co++) out[base + (size_t)co*NH0*NW0] = acc[co];
  }
}

extern "C" void kernel_launch(void* const* d_in, const int* in_sizes, int n_in,
                              void* d_out, int out_size, void* d_ws, size_t ws_size,
                              hipStream_t stream){
  (void)in_sizes; (void)n_in; (void)out_size; (void)ws_size;
  const float* x    = (const float*)d_in[0];
  const float* eps  = (const float*)d_in[1];
  const float* w1   = (const float*)d_in[2];
  const float* b1   = (const float*)d_in[3];
  const float* w2   = (const float*)d_in[4];
  const float* b2   = (const float*)d_in[5];
  const float* w3   = (const float*)d_in[6];
  const float* b3   = (const float*)d_in[7];
  const float* wmu  = (const float*)d_in[8];
  const float* bmu  = (const float*)d_in[9];
  const float* wlv  = (const float*)d_in[10];
  const float* blv  = (const float*)d_in[11];
  const float* wlin = (const float*)d_in[12];
  const float* blin = (const float*)d_in[13];
  const float* u1   = (const float*)d_in[14];
  const float* bu1  = (const float*)d_in[15];
  const float* w4   = (const float*)d_in[16];
  const float* b4   = (const float*)d_in[17];
  const float* u2   = (const float*)d_in[18];
  const float* bu2  = (const float*)d_in[19];
  const float* w5   = (const float*)d_in[20];
  const float* b5   = (const float*)d_in[21];
  const float* u3   = (const float*)d_in[22];
  const float* bu3  = (const float*)d_in[23];
  const float* w6   = (const float*)d_in[24];
  const float* b6   = (const float*)d_in[25];
  const float* fW1  = (const float*)d_in[26];
  const float* fb1  = (const float*)d_in[27];
  const float* fW2  = (const float*)d_in[28];
  const float* fb2  = (const float*)d_in[29];
  const float* fW3  = (const float*)d_in[30];
  const float* fb3  = (const float*)d_in[31];

  char* ws = (char*)d_ws;
  unsigned char* m0 = (unsigned char*)(ws);
  unsigned char* m1 = (unsigned char*)(ws + 3276800);
  unsigned char* m2 = (unsigned char*)(ws + 4096000);
  unsigned char* m3 = (unsigned char*)(ws + 4177920);
  float* y1p = (float*)(ws + 4194304);    // [B][100][64][8]
  float* y2p = (float*)(ws + 30408704);   // [B][20][32][16]
  float* y3p = (float*)(ws + 35651584);   // [B][4][16][32]
  float* dec = (float*)(ws + 36700160);   // [B][4][16][32]
  float* t2  = y2p;  // reuse
  float* t4  = y1p;  // reuse

  float* out   = (float*)d_out;
  float* o_mu  = out + 19660800;
  float* o_lv  = out + 19693568;
  float* o_kld = out + 19726336;
  float* o_zf  = out + 19726464;

  k_conv1pool<<< 3584,256,0,stream>>>(x, w1, b1, y1p, m0, m1);
  k_conv2pool<<<  512,256,0,stream>>>(y1p, m1, w2, b2, y2p, m2);
  k_conv3pool<<<  128,256,0,stream>>>(y2p, m2, w3, b3, y3p, m3);
  k_latent   <<<  128, 64,0,stream>>>(y3p, m3, eps, wmu,bmu,wlv,blv,wlin,blin,
                                      fW1,fb1,fW2,fb2,fW3,fb3, o_mu,o_lv,o_kld,o_zf, dec);
  k_ic4      <<<  512,256,0,stream>>>(dec, m2, u1, bu1, w4, b4, t2);
  k_ic5      <<< 5120,256,0,stream>>>(t2, m1, u2, bu2, w5, b5, t4);
  k_inv3conv6<<< 3328,256,0,stream>>>(t4, m0, u3, bu3, w6, b6, out);
}

// Round 4
// 1511.330 us; speedup vs baseline: 1.0151x; 1.0151x over previous
//
#include <hip/hip_runtime.h>
#include <math.h>

constexpr int NB=128;
constexpr int NH0=200, NW0=128, NC0=6;
constexpr int NH1=100, NW1=64,  NC1=8;
constexpr int NH2=20,  NW2=32,  NC2=16;
constexpr int NH3=4,   NW3=16,  NC3=32;
constexpr int LAT=4, NPp=11, HID=16, NT=10;
constexpr float BOUNDf=5.0f;
constexpr float LOG2PI=1.8378770664093453f;

__device__ __forceinline__ float fexpf(float v){ return __expf(v); }
__device__ __forceinline__ float flogf(float v){ return __logf(v); }
__device__ __forceinline__ float softplusf(float v){ return v>20.f ? v : __logf(1.f+__expf(v)); }
__device__ __forceinline__ float lrelu(float v){ return v>0.f ? v : 0.01f*v; }

// ============ conv1 (3x3,6->8) + lrelu + pool2x2, LDS-tiled, computes m0,m1 ============
__global__ __launch_bounds__(256) void k_conv1pool(
    const float* __restrict__ x, const float* __restrict__ w1, const float* __restrict__ b1,
    float* __restrict__ y1p, unsigned char* __restrict__ m0, unsigned char* __restrict__ m1){
  __shared__ float xs[6][34][34];
  __shared__ float ws1[54][8];
  __shared__ unsigned char ms[34][34];
  int blk = blockIdx.x;
  int b  = blk / 28;
  int t  = blk % 28;
  int th = t / 4, tw = t % 4;
  int hp0 = th*16, wp0 = tw*16;
  int h0 = hp0*2 - 1, w0 = wp0*2 - 1;
  int tid = threadIdx.x;
  for (int i=tid;i<432;i+=256) ws1[i>>3][i&7] = w1[i];
  for (int i=tid;i<6*34*34;i+=256){
    int ci=i/1156; int rem=i-ci*1156; int r=rem/34, c=rem-r*34;
    int h=h0+r, w=w0+c;
    float v=0.f;
    if (h>=0 && h<NH0 && w>=0 && w<NW0) v = x[((size_t)(b*NC0+ci)*NH0+h)*NW0+w];
    xs[ci][r][c]=v;
  }
  __syncthreads();
  for (int i=tid;i<1156;i+=256){
    int r=i/34, c=i-r*34;
    bool any=false;
    #pragma unroll
    for (int ci=0;ci<6;ci++) any |= (xs[ci][r][c]!=0.f);
    ms[r][c] = any?1:0;
  }
  __syncthreads();
  for (int i=tid;i<1024;i+=256){
    int r=(i>>5)+1, c=(i&31)+1;
    int h=h0+r, w=w0+c;
    if (h<NH0) m0[(b*NH0+h)*NW0+w] = ms[r][c];
  }
  int lhp = tid>>4, lwp = tid&15;
  int hp = hp0+lhp, wp = wp0+lwp;
  if (hp < NH1){
    float best[8];
    #pragma unroll
    for (int co=0;co<8;co++) best[co]=-1e30f;
    bool many=false;
    for (int i=0;i<2;i++)
    for (int j=0;j<2;j++){
      int r = lhp*2+i+1, c = lwp*2+j+1;
      if (!ms[r][c]) continue;
      many=true;
      float a[8];
      #pragma unroll
      for (int co=0;co<8;co++) a[co]=b1[co];
      for (int kh=0;kh<3;kh++)
      for (int kw=0;kw<3;kw++){
        #pragma unroll
        for (int ci=0;ci<6;ci++){
          float v = xs[ci][r-1+kh][c-1+kw];
          const float* wv = ws1[(kh*3+kw)*6+ci];
          #pragma unroll
          for (int co=0;co<8;co++) a[co]=fmaf(v,wv[co],a[co]);
        }
      }
      #pragma unroll
      for (int co=0;co<8;co++) best[co]=fmaxf(best[co], lrelu(a[co]));
    }
    float* yp = y1p + (((size_t)b*NH1+hp)*NW1+wp)*8;
    #pragma unroll
    for (int co=0;co<8;co++) yp[co] = many?best[co]:0.f;
    m1[(b*NH1+hp)*NW1+wp] = many?1:0;
  }
}

// ============ conv2 (3x3,8->16) + lrelu + pool 5x2, LDS-tiled, rolled taps ============
__global__ __launch_bounds__(256) void k_conv2pool(
    const float* __restrict__ yin, const unsigned char* __restrict__ m1,
    const float* __restrict__ w2, const float* __restrict__ b2,
    float* __restrict__ yout, unsigned char* __restrict__ m2){
  __shared__ float ys[8][52][35];
  __shared__ unsigned char msl[52][35];
  __shared__ float w2s[72][16];
  __shared__ float b2s[16];
  int blk = blockIdx.x;
  int b  = blk >> 2;
  int t  = blk & 3;
  int th = t >> 1, tw = t & 1;
  int r0 = th*50 - 1, c0 = tw*32 - 1;
  int tid = threadIdx.x;
  for (int i=tid;i<1152;i+=256) w2s[i>>4][i&15] = w2[i];
  if (tid<16) b2s[tid]=b2[tid];
  for (int p=tid;p<52*34;p+=256){
    int r=p/34, c=p-(p/34)*34;
    int h1=r0+r, w1c=c0+c;
    bool ok = (h1>=0 && h1<NH1 && w1c>=0 && w1c<NW1);
    msl[r][c] = ok ? m1[(b*NH1+h1)*NW1+w1c] : 0;
    float4 v0=make_float4(0,0,0,0), v1=v0;
    if (ok){
      const float4* pp = (const float4*)(yin + (((size_t)b*NH1+h1)*NW1+w1c)*8);
      v0=pp[0]; v1=pp[1];
    }
    ys[0][r][c]=v0.x; ys[1][r][c]=v0.y; ys[2][r][c]=v0.z; ys[3][r][c]=v0.w;
    ys[4][r][c]=v1.x; ys[5][r][c]=v1.y; ys[6][r][c]=v1.z; ys[7][r][c]=v1.w;
  }
  __syncthreads();
  if (tid < 160){
    int lh = tid>>4, lw = tid&15;
    int h2 = th*10+lh, w2c = tw*16+lw;
    float best[16];
    #pragma unroll
    for (int co=0;co<16;co++) best[co]=-1e30f;
    bool many=false;
    for (int i=0;i<5;i++)
    for (int j=0;j<2;j++){
      int r = lh*5+i+1, c = lw*2+j+1;
      if (!msl[r][c]) continue;
      many=true;
      float a[16];
      #pragma unroll
      for (int co=0;co<16;co++) a[co]=b2s[co];
      for (int kh=0;kh<3;kh++)
      for (int kw=0;kw<3;kw++){
        #pragma unroll
        for (int ci=0;ci<8;ci++){
          float v = ys[ci][r-1+kh][c-1+kw];
          const float* wr = w2s[(kh*3+kw)*8+ci];
          #pragma unroll
          for (int co=0;co<16;co++) a[co]=fmaf(v,wr[co],a[co]);
        }
      }
      #pragma unroll
      for (int co=0;co<16;co++) best[co]=fmaxf(best[co], lrelu(a[co]));
    }
    float4 o0,o1,o2,o3;
    if (many){
      o0=make_float4(best[0],best[1],best[2],best[3]);
      o1=make_float4(best[4],best[5],best[6],best[7]);
      o2=make_float4(best[8],best[9],best[10],best[11]);
      o3=make_float4(best[12],best[13],best[14],best[15]);
    } else { o0=make_float4(0,0,0,0); o1=o0; o2=o0; o3=o0; }
    float4* op = (float4*)(yout + (((size_t)b*NH2+h2)*NW2+w2c)*16);
    op[0]=o0; op[1]=o1; op[2]=o2; op[3]=o3;
    m2[(b*NH2+h2)*NW2+w2c] = many?1:0;
  }
}

// ============ conv3 (3x3,16->32) + lrelu + pool 5x2, per-batch LDS-tiled, rolled ============
__global__ __launch_bounds__(256) void k_conv3pool(
    const float* __restrict__ yin, const unsigned char* __restrict__ m2,
    const float* __restrict__ w3, const float* __restrict__ b3,
    float* __restrict__ yout, unsigned char* __restrict__ m3){
  __shared__ float ys[16][20][33];
  __shared__ unsigned char msl[20][32];
  __shared__ float w3s[144][32];
  __shared__ float b3s[32];
  int b = blockIdx.x;
  int tid = threadIdx.x;
  for (int i=tid;i<4608;i+=256) w3s[i>>5][i&31] = w3[i];
  if (tid<32) b3s[tid]=b3[tid];
  for (int p=tid;p<640;p+=256){
    int r=p>>5, c=p&31;
    msl[r][c] = m2[(b*NH2+r)*NW2+c];
    const float4* pp = (const float4*)(yin + (((size_t)b*NH2+r)*NW2+c)*16);
    float4 q0=pp[0],q1=pp[1],q2=pp[2],q3=pp[3];
    ys[0][r][c]=q0.x; ys[1][r][c]=q0.y; ys[2][r][c]=q0.z; ys[3][r][c]=q0.w;
    ys[4][r][c]=q1.x; ys[5][r][c]=q1.y; ys[6][r][c]=q1.z; ys[7][r][c]=q1.w;
    ys[8][r][c]=q2.x; ys[9][r][c]=q2.y; ys[10][r][c]=q2.z; ys[11][r][c]=q2.w;
    ys[12][r][c]=q3.x; ys[13][r][c]=q3.y; ys[14][r][c]=q3.z; ys[15][r][c]=q3.w;
  }
  __syncthreads();
  int p = tid>>2, coq = tid&3;
  int co0 = coq*8;
  int hp = p>>4, wp = p&15;
  float best[8];
  #pragma unroll
  for (int co=0;co<8;co++) best[co]=-1e30f;
  bool many=false;
  for (int i=0;i<5;i++)
  for (int j=0;j<2;j++){
    int h2 = hp*5+i, w2c = wp*2+j;
    if (!msl[h2][w2c]) continue;
    many=true;
    float a[8];
    #pragma unroll
    for (int co=0;co<8;co++) a[co]=b3s[co0+co];
    for (int kh=0;kh<3;kh++){
      int hh=h2+kh-1;
      if (hh<0||hh>=NH2) continue;
      for (int kw=0;kw<3;kw++){
        int ww=w2c+kw-1;
        if (ww<0||ww>=NW2) continue;
        #pragma unroll
        for (int ci=0;ci<16;ci++){
          float v = ys[ci][hh][ww];
          const float* wr = w3s[(kh*3+kw)*16+ci];
          #pragma unroll
          for (int co=0;co<8;co++) a[co]=fmaf(v,wr[co0+co],a[co]);
        }
      }
    }
    #pragma unroll
    for (int co=0;co<8;co++) best[co]=fmaxf(best[co], lrelu(a[co]));
  }
  float4 o0,o1;
  if (many){
    o0=make_float4(best[0],best[1],best[2],best[3]);
    o1=make_float4(best[4],best[5],best[6],best[7]);
  } else { o0=make_float4(0,0,0,0); o1=o0; }
  float4* op = (float4*)(yout + ((size_t)(b*64+p))*32 + co0);
  op[0]=o0; op[1]=o1;
  if (coq==0) m3[b*64+p] = many?1:0;
}

// ============ latent head + NSF flow + kld + dec ============
__global__ __launch_bounds__(64) void k_latent(
    const float* __restrict__ y3p, const unsigned char* __restrict__ m3,
    const float* __restrict__ eps,
    const float* __restrict__ wmu, const float* __restrict__ bmu,
    const float* __restrict__ wlv, const float* __restrict__ blv,
    const float* __restrict__ wlin, const float* __restrict__ blin,
    const float* __restrict__ fW1, const float* __restrict__ fb1,
    const float* __restrict__ fW2, const float* __restrict__ fb2,
    const float* __restrict__ fW3, const float* __restrict__ fb3,
    float* __restrict__ out_mu, float* __restrict__ out_lv,
    float* __restrict__ out_kld, float* __restrict__ out_zf,
    float* __restrict__ dec)
{
  __shared__ __align__(16) float sW1[NT*HID*LAT];
  __shared__ float sb1[NT*HID];
  __shared__ __align__(16) float sW2[NT*HID*HID];
  __shared__ float sb2[NT*HID];
  __shared__ __align__(16) float sW3[NT*LAT*NPp*HID];
  __shared__ float sb3[NT*LAT*NPp];
  __shared__ float red[64];
  int tid = threadIdx.x;
  for (int i=tid;i<NT*HID*LAT;i+=64){ int j=i&3; int r=(i>>2)%HID; sW1[i]=fW1[i]*(((r%3+1)>=(j+1))?1.f:0.f); }
  for (int i=tid;i<NT*HID;i+=64){ sb1[i]=fb1[i]; sb2[i]=fb2[i]; }
  for (int i=tid;i<NT*HID*HID;i+=64){ int j=i&15; int r=(i>>4)%HID; sW2[i]=fW2[i]*(((r%3+1)>=(j%3+1))?1.f:0.f); }
  for (int i=tid;i<NT*LAT*NPp*HID;i+=64){ int j=i&15; int r=(i>>4)%(LAT*NPp); sW3[i]=fW3[i]*(((r/NPp+1)>(j%3+1))?1.f:0.f); }
  for (int i=tid;i<NT*LAT*NPp;i+=64) sb3[i]=fb3[i];
  __syncthreads();

  int b = blockIdx.x;
  int gpos = b*64 + tid;
  bool msk = m3[gpos]!=0;
  float kld_pc=0.f;
  if (msk){
    float yv[NC3];
    const float* yp = y3p + (size_t)gpos*NC3;
    #pragma unroll
    for (int c=0;c<NC3;c++) yv[c]=yp[c];
    float muv[LAT], lvv[LAT], stdv[LAT], evv[LAT], z0[LAT], z[LAT];
    #pragma unroll
    for (int l=0;l<LAT;l++){
      float a=bmu[l], g=blv[l];
      #pragma unroll
      for (int c=0;c<NC3;c++){ a=fmaf(yv[c],wmu[l*NC3+c],a); g=fmaf(yv[c],wlv[l*NC3+c],g); }
      muv[l]=a; lvv[l]=g;
      stdv[l]=fexpf(0.5f*g);
      evv[l]=eps[(size_t)gpos*LAT+l];
      z0[l]=fmaf(evv[l], stdv[l], a);
      z[l]=z0[l];
    }
    float ld_tot=0.f;
    for (int t=0;t<NT;t++){
      float h1[HID], h2[HID];
      const float* W1t = sW1 + t*HID*LAT;
      const float* b1t = sb1 + t*HID;
      float4 zv = make_float4(z[0],z[1],z[2],z[3]);
      #pragma unroll
      for (int i2=0;i2<HID;i2++){
        float4 wr = *(const float4*)(W1t + i2*4);
        float a = b1t[i2];
        a = fmaf(zv.x,wr.x, fmaf(zv.y,wr.y, fmaf(zv.z,wr.z, fmaf(zv.w,wr.w, a))));
        h1[i2]=fmaxf(a,0.f);
      }
      const float* W2t = sW2 + t*HID*HID;
      const float* b2t = sb2 + t*HID;
      #pragma unroll
      for (int i2=0;i2<HID;i2++){
        float a=b2t[i2];
        const float4* wr = (const float4*)(W2t + i2*HID);
        #pragma unroll
        for (int q=0;q<4;q++){
          float4 w4 = wr[q];
          a = fmaf(h1[q*4+0],w4.x, fmaf(h1[q*4+1],w4.y, fmaf(h1[q*4+2],w4.z, fmaf(h1[q*4+3],w4.w, a))));
        }
        h2[i2]=fmaxf(a,0.f);
      }
      const float* W3t = sW3 + t*LAT*NPp*HID;
      const float* b3t = sb3 + t*LAT*NPp;
      float zn[LAT];
      #pragma unroll
      for (int l=0;l<LAT;l++){
        float p[NPp];
        #pragma unroll
        for (int r=0;r<NPp;r++){
          int rr=l*NPp+r;
          float a=b3t[rr];
          const float4* wr = (const float4*)(W3t + rr*HID);
          #pragma unroll
          for (int q=0;q<4;q++){
            float4 w4 = wr[q];
            a = fmaf(h2[q*4+0],w4.x, fmaf(h2[q*4+1],w4.y, fmaf(h2[q*4+2],w4.z, fmaf(h2[q*4+3],w4.w, a))));
          }
          p[r]=a;
        }
        float mw=fmaxf(fmaxf(p[0],p[1]),fmaxf(p[2],p[3]));
        float e0=fexpf(p[0]-mw), e1=fexpf(p[1]-mw), e2=fexpf(p[2]-mw), e3=fexpf(p[3]-mw);
        float wsc=10.f/(e0+e1+e2+e3);
        float xk1=fmaf(e0,wsc,-BOUNDf), xk2=fmaf(e1,wsc,xk1), xk3=fmaf(e2,wsc,xk2), xk4=fmaf(e3,wsc,xk3);
        float mh=fmaxf(fmaxf(p[4],p[5]),fmaxf(p[6],p[7]));
        float f0=fexpf(p[4]-mh), f1=fexpf(p[5]-mh), f2=fexpf(p[6]-mh), f3=fexpf(p[7]-mh);
        float hsc=10.f/(f0+f1+f2+f3);
        float yk1=fmaf(f0,hsc,-BOUNDf), yk2=fmaf(f1,hsc,yk1), yk3=fmaf(f2,hsc,yk2), yk4=fmaf(f3,hsc,yk3);
        float dk1=softplusf(p[8]), dk2=softplusf(p[9]), dk3=softplusf(p[10]);
        float xv=z[l];
        bool inside = (xv>=-BOUNDf)&&(xv<=BOUNDf);
        float xc=fminf(fmaxf(xv,-BOUNDf),BOUNDf);
        float x0=-BOUNDf, x1=xk1, y0=-BOUNDf, y1=yk1, d0=1.f, d1=dk1;
        if (xc>=xk1){x0=xk1;x1=xk2;y0=yk1;y1=yk2;d0=dk1;d1=dk2;}
        if (xc>=xk2){x0=xk2;x1=xk3;y0=yk2;y1=yk3;d0=dk2;d1=dk3;}
        if (xc>=xk3){x0=xk3;x1=xk4;y0=yk3;y1=yk4;d0=dk3;d1=1.f;}
        float dxv=x1-x0, dyv=y1-y0;
        float sl=dyv/dxv, ttv=(xc-x0)/dxv, omt=1.f-ttv;
        float den=sl + (d1+d0-2.f*sl)*ttv*omt;
        float yo=y0 + dyv*(sl*ttv*ttv + d0*ttv*omt)/den;
        float ldv=flogf(sl*sl*(d1*ttv*ttv + 2.f*sl*ttv*omt + d0*omt*omt)) - 2.f*flogf(den);
        zn[l] = inside ? yo : xv;
        ld_tot += inside ? ldv : 0.f;
      }
      if (t<NT-1){ z[0]=zn[3]; z[1]=zn[2]; z[2]=zn[1]; z[3]=zn[0]; }
      else       { z[0]=zn[0]; z[1]=zn[1]; z[2]=zn[2]; z[3]=zn[3]; }
    }
    float lq=0.f, lp=0.f;
    #pragma unroll
    for (int l=0;l<LAT;l++){
      lq += -0.5f*evv[l]*evv[l] - 0.5f*lvv[l] - 0.5f*LOG2PI;
      lp += -0.5f*z[l]*z[l] - 0.5f*LOG2PI;
    }
    kld_pc = lq - ld_tot - lp;
    #pragma unroll
    for (int l=0;l<LAT;l++){
      out_mu[(size_t)gpos*LAT+l]=muv[l];
      out_lv[(size_t)gpos*LAT+l]=lvv[l];
      out_zf[(size_t)gpos*LAT+l]=z[l];
    }
    #pragma unroll
    for (int k2=0;k2<NC3;k2++){
      float a=blin[k2];
      #pragma unroll
      for (int l=0;l<LAT;l++) a=fmaf(z[l],wlin[k2*LAT+l],a);
      dec[(size_t)gpos*NC3+k2]=a;
    }
  } else {
    #pragma unroll
    for (int l=0;l<LAT;l++){
      out_mu[(size_t)gpos*LAT+l]=0.f;
      out_lv[(size_t)gpos*LAT+l]=0.f;
      out_zf[(size_t)gpos*LAT+l]=0.f;
    }
    for (int k2=0;k2<NC3;k2++) dec[(size_t)gpos*NC3+k2]=0.f;
  }
  red[tid]=kld_pc;
  __syncthreads();
  for (int s=32;s>0;s>>=1){ if (tid<s) red[tid]+=red[tid+s]; __syncthreads(); }
  if (tid==0) out_kld[b]=red[0];
}

// ============ fused invconv1(5,2,32,32) + conv4(3x3,32->16) -> t2, mask m2 ============
__global__ __launch_bounds__(256) void k_ic4(
    const float* __restrict__ dec, const unsigned char* __restrict__ m2,
    const float* __restrict__ u1, const float* __restrict__ bu1,
    const float* __restrict__ w4, const float* __restrict__ b4,
    float* __restrict__ t2){
  __shared__ __align__(16) float vs[12][18][32];
  __shared__ __align__(16) float w4s[288][16];
  __shared__ unsigned char msl[12][18];
  int blk = blockIdx.x;
  int b  = blk >> 2;
  int t  = blk & 3;
  int th = t >> 1, tw = t & 1;
  int h0 = th*10, w0 = tw*16;
  int tid = threadIdx.x;
  for (int i=tid;i<288*16;i+=256) w4s[i>>4][i&15] = w4[i];
  if (tid < 216){
    int lr = tid/18, lc = tid%18;
    int h2 = h0-1+lr, w2 = w0-1+lc;
    bool mk = (h2>=0 && h2<NH2 && w2>=0 && w2<NW2) && m2[(b*NH2+h2)*NW2+w2];
    msl[lr][lc] = mk?1:0;
    float acc[32];
    if (mk){
      const float* dp = dec + (((size_t)b*NH3 + h2/5)*NW3 + w2/2)*NC3;
      const float* up = u1 + ((h2%5)*2 + (w2&1))*1024;
      #pragma unroll
      for (int co=0;co<32;co++) acc[co]=bu1[co];
      for (int ci=0;ci<32;ci++){
        float dv = dp[ci];
        const float* ur = up + ci*32;
        #pragma unroll
        for (int co=0;co<32;co++) acc[co]=fmaf(dv,ur[co],acc[co]);
      }
    } else {
      #pragma unroll
      for (int co=0;co<32;co++) acc[co]=0.f;
    }
    #pragma unroll
    for (int co=0;co<32;co++) vs[lr][lc][co]=acc[co];
  }
  __syncthreads();
  if (tid < 160){
    int lh = tid/16, lw = tid%16;
    int h2 = h0+lh, w2 = w0+lw;
    float a[16];
    if (msl[lh+1][lw+1]){
      #pragma unroll
      for (int co=0;co<16;co++) a[co]=b4[co];
      for (int kh=0;kh<3;kh++)
      for (int kw=0;kw<3;kw++){
        const float* vp = vs[lh+kh][lw+kw];
        #pragma unroll
        for (int ci=0;ci<32;ci++){
          float v = vp[ci];
          const float* wr = w4s[(kh*3+kw)*32+ci];
          #pragma unroll
          for (int co=0;co<16;co++) a[co]=fmaf(v,wr[co],a[co]);
        }
      }
    } else {
      #pragma unroll
      for (int co=0;co<16;co++) a[co]=0.f;
    }
    float* op = t2 + (((size_t)b*NH2+h2)*NW2+w2)*NC2;
    #pragma unroll
    for (int co=0;co<16;co++) op[co]=a[co];
  }
}

// ============ fused invconv2(5,2,16,16) + conv5(3x3,16->8) -> t4, mask m1 ============
__global__ __launch_bounds__(256) void k_ic5(
    const float* __restrict__ t2, const unsigned char* __restrict__ m1,
    const float* __restrict__ u2, const float* __restrict__ bu2,
    const float* __restrict__ w5, const float* __restrict__ b5,
    float* __restrict__ t4){
  __shared__ __align__(16) float vs[12][18][16];
  __shared__ __align__(16) float w5s[144][8];
  __shared__ unsigned char msl[12][18];
  int blk = blockIdx.x;
  int b  = blk / 40;
  int t  = blk % 40;
  int th = t >> 2, tw = t & 3;
  int h0 = th*10, w0 = tw*16;
  int tid = threadIdx.x;
  for (int i=tid;i<144*8;i+=256) w5s[i>>3][i&7] = w5[i];
  if (tid < 216){
    int lr = tid/18, lc = tid%18;
    int h1 = h0-1+lr, w1c = w0-1+lc;
    bool mk = (h1>=0 && h1<NH1 && w1c>=0 && w1c<NW1) && m1[(b*NH1+h1)*NW1+w1c];
    msl[lr][lc] = mk?1:0;
    float acc[16];
    if (mk){
      const float* dp = t2 + (((size_t)b*NH2 + h1/5)*NW2 + w1c/2)*NC2;
      const float* up = u2 + ((h1%5)*2 + (w1c&1))*256;
      #pragma unroll
      for (int co=0;co<16;co++) acc[co]=bu2[co];
      for (int ci=0;ci<16;ci++){
        float dv = dp[ci];
        const float* ur = up + ci*16;
        #pragma unroll
        for (int co=0;co<16;co++) acc[co]=fmaf(dv,ur[co],acc[co]);
      }
    } else {
      #pragma unroll
      for (int co=0;co<16;co++) acc[co]=0.f;
    }
    #pragma unroll
    for (int co=0;co<16;co++) vs[lr][lc][co]=acc[co];
  }
  __syncthreads();
  if (tid < 160){
    int lh = tid/16, lw = tid%16;
    int h1 = h0+lh, w1c = w0+lw;
    float a[8];
    if (msl[lh+1][lw+1]){
      #pragma unroll
      for (int co=0;co<8;co++) a[co]=b5[co];
      for (int kh=0;kh<3;kh++)
      for (int kw=0;kw<3;kw++){
        const float* vp = vs[lh+kh][lw+kw];
        #pragma unroll
        for (int ci=0;ci<16;ci++){
          float v = vp[ci];
          const float* wr = w5s[(kh*3+kw)*16+ci];
          #pragma unroll
          for (int co=0;co<8;co++) a[co]=fmaf(v,wr[co],a[co]);
        }
      }
    } else {
      #pragma unroll
      for (int co=0;co<8;co++) a[co]=0.f;
    }
    float* op = t4 + (((size_t)b*NH1+h1)*NW1+w1c)*NC1;
    #pragma unroll
    for (int co=0;co<8;co++) op[co]=a[co];
  }
}

// ============ fused invconv3 (2,2,8,8) + conv6 (3x3,8->6), LDS-tiled, rolled ============
__global__ __launch_bounds__(256) void k_inv3conv6(
    const float* __restrict__ t4, const unsigned char* __restrict__ m0,
    const float* __restrict__ u3, const float* __restrict__ bu3,
    const float* __restrict__ w6, const float* __restrict__ b6,
    float* __restrict__ out){
  __shared__ float ts[8][10][36];
  __shared__ unsigned char msl[18][66];
  __shared__ float u3s[4][8][8];
  __shared__ float w6s[9][8][6];
  __shared__ float bu3s[8];
  __shared__ float b6s[6];
  int blk = blockIdx.x;
  int b  = blk / 26;
  int t  = blk % 26;
  int th = t >> 1, tw = t & 1;
  int h0 = th*16, w0 = tw*64;
  int base_r = 8*th - 1, base_c = 32*tw - 1;
  int tid = threadIdx.x;
  for (int i=tid;i<256;i+=256){ int pos=i>>6; int rem=i&63; u3s[pos][rem>>3][rem&7]=u3[i]; }
  for (int i=tid;i<432;i+=256){ int tap=i/48; int rem=i%48; w6s[tap][rem/6][rem%6]=w6[i]; }
  if (tid<8) bu3s[tid]=bu3[tid];
  if (tid<6) b6s[tid]=b6[tid];
  for (int p=tid;p<340;p+=256){
    int r=p/34, c=p-(p/34)*34;
    int h1=base_r+r, w1c=base_c+c;
    float4 v0=make_float4(0,0,0,0), v1=v0;
    if (h1>=0 && h1<NH1 && w1c>=0 && w1c<NW1){
      const float4* pp = (const float4*)(t4 + (((size_t)b*NH1+h1)*NW1+w1c)*8);
      v0=pp[0]; v1=pp[1];
    }
    ts[0][r][c]=v0.x; ts[1][r][c]=v0.y; ts[2][r][c]=v0.z; ts[3][r][c]=v0.w;
    ts[4][r][c]=v1.x; ts[5][r][c]=v1.y; ts[6][r][c]=v1.z; ts[7][r][c]=v1.w;
  }
  for (int p=tid;p<18*66;p+=256){
    int r=p/66, c=p-(p/66)*66;
    int h=h0-1+r, w=w0-1+c;
    msl[r][c] = (h>=0 && h<NH0 && w>=0 && w<NW0) ? m0[(b*NH0+h)*NW0+w] : 0;
  }
  __syncthreads();
  for (int k=0;k<4;k++){
    int p = tid + k*256;
    int lh = p>>6, lw = p&63;
    int h = h0+lh, w = w0+lw;
    if (h >= NH0) continue;
    float acc[6];
    if (msl[lh+1][lw+1]){
      #pragma unroll
      for (int co=0;co<6;co++) acc[co]=b6s[co];
      for (int kh=0;kh<3;kh++)
      for (int kw=0;kw<3;kw++){
        if (!msl[lh+kh][lw+kw]) continue;
        int hh = h+kh-1, ww = w+kw-1;
        int tr = (hh>>1) - base_r, tc = (ww>>1) - base_c;
        int pos = (hh&1)*2 + (ww&1);
        float v8[8];
        #pragma unroll
        for (int c8=0;c8<8;c8++) v8[c8]=bu3s[c8];
        #pragma unroll
        for (int ci=0;ci<8;ci++){
          float v = ts[ci][tr][tc];
          #pragma unroll
          for (int c8=0;c8<8;c8++) v8[c8]=fmaf(v, u3s[pos][ci][c8], v8[c8]);
        }
        const float (*wt)[6] = w6s[kh*3+kw];
        #pragma unroll
        for (int ci=0;ci<8;ci++)
          #pragma unroll
          for (int co=0;co<6;co++) acc[co]=fmaf(v8[ci], wt[ci][co], acc[co]);
      }
    } else {
      #pragma unroll
      for (int co=0;co<6;co++) acc[co]=0.f;
    }
    size_t base = (size_t)b*6*NH0*NW0 + (size_t)h*NW0 + w;
    #pragma unroll
    for (int co=0;co<6;co++) out[base + (size_t)co*NH0*NW0] = acc[co];
  }
}

extern "C" void kernel_launch(void* const* d_in, const int* in_sizes, int n_in,
                              void* d_out, int out_size, void* d_ws, size_t ws_size,
                              hipStream_t stream){
  (void)in_sizes; (void)n_in; (void)out_size; (void)ws_size;
  const float* x    = (const float*)d_in[0];
  const float* eps  = (const float*)d_in[1];
  const float* w1   = (const float*)d_in[2];
  const float* b1   = (const float*)d_in[3];
  const float* w2   = (const float*)d_in[4];
  const float* b2   = (const float*)d_in[5];
  const float* w3   = (const float*)d_in[6];
  const float* b3   = (const float*)d_in[7];
  const float* wmu  = (const float*)d_in[8];
  const float* bmu  = (const float*)d_in[9];
  const float* wlv  = (const float*)d_in[10];
  const float* blv  = (const float*)d_in[11];
  const float* wlin = (const float*)d_in[12];
  const float* blin = (const float*)d_in[13];
  const float* u1   = (const float*)d_in[14];
  const float* bu1  = (const float*)d_in[15];
  const float* w4   = (const float*)d_in[16];
  const float* b4   = (const float*)d_in[17];
  const float* u2   = (const float*)d_in[18];
  const float* bu2  = (const float*)d_in[19];
  const float* w5   = (const float*)d_in[20];
  const float* b5   = (const float*)d_in[21];
  const float* u3   = (const float*)d_in[22];
  const float* bu3  = (const float*)d_in[23];
  const float* w6   = (const float*)d_in[24];
  const float* b6   = (const float*)d_in[25];
  const float* fW1  = (const float*)d_in[26];
  const float* fb1  = (const float*)d_in[27];
  const float* fW2  = (const float*)d_in[28];
  const float* fb2  = (const float*)d_in[29];
  const float* fW3  = (const float*)d_in[30];
  const float* fb3  = (const float*)d_in[31];

  char* ws = (char*)d_ws;
  unsigned char* m0 = (unsigned char*)(ws);
  unsigned char* m1 = (unsigned char*)(ws + 3276800);
  unsigned char* m2 = (unsigned char*)(ws + 4096000);
  unsigned char* m3 = (unsigned char*)(ws + 4177920);
  float* y1p = (float*)(ws + 4194304);    // [B][100][64][8]
  float* y2p = (float*)(ws + 30408704);   // [B][20][32][16]
  float* y3p = (float*)(ws + 35651584);   // [B][4][16][32]
  float* dec = (float*)(ws + 36700160);   // [B][4][16][32]
  float* t2  = y2p;  // reuse
  float* t4  = y1p;  // reuse

  float* out   = (float*)d_out;
  float* o_mu  = out + 19660800;
  float* o_lv  = out + 19693568;
  float* o_kld = out + 19726336;
  float* o_zf  = out + 19726464;

  k_conv1pool<<< 3584,256,0,stream>>>(x, w1, b1, y1p, m0, m1);
  k_conv2pool<<<  512,256,0,stream>>>(y1p, m1, w2, b2, y2p, m2);
  k_conv3pool<<<  128,256,0,stream>>>(y2p, m2, w3, b3, y3p, m3);
  k_latent   <<<  128, 64,0,stream>>>(y3p, m3, eps, wmu,bmu,wlv,blv,wlin,blin,
                                      fW1,fb1,fW2,fb2,fW3,fb3, o_mu,o_lv,o_kld,o_zf, dec);
  k_ic4      <<<  512,256,0,stream>>>(dec, m2, u1, bu1, w4, b4, t2);
  k_ic5      <<< 5120,256,0,stream>>>(t2, m1, u2, bu2, w5, b5, t4);
  k_inv3conv6<<< 3328,256,0,stream>>>(t4, m0, u3, bu3, w6, b6, out);
}

// Round 5
// 521.638 us; speedup vs baseline: 2.9409x; 2.8973x over previous
//
#include <hip/hip_runtime.h>
#include <math.h>

constexpr int NB=128;
constexpr int NH0=200, NW0=128, NC0=6;
constexpr int NH1=100, NW1=64,  NC1=8;
constexpr int NH2=20,  NW2=32,  NC2=16;
constexpr int NH3=4,   NW3=16,  NC3=32;
constexpr int LAT=4, NPp=11, HID=16, NT=10;
constexpr float BOUNDf=5.0f;
constexpr float LOG2PI=1.8378770664093453f;

__device__ __forceinline__ float fexpf(float v){ return __expf(v); }
__device__ __forceinline__ float flogf(float v){ return __logf(v); }
__device__ __forceinline__ float softplusf(float v){ return v>20.f ? v : __logf(1.f+__expf(v)); }
__device__ __forceinline__ float lrelu(float v){ return v>0.f ? v : 0.01f*v; }

// ============ conv1 (3x3,6->8) + lrelu + pool2x2, LDS-tiled, computes m0,m1 ============
__global__ __launch_bounds__(256) void k_conv1pool(
    const float* __restrict__ x, const float* __restrict__ w1, const float* __restrict__ b1,
    float* __restrict__ y1p, unsigned char* __restrict__ m0, unsigned char* __restrict__ m1){
  __shared__ float xs[6][34][34];
  __shared__ float ws1[54][8];
  __shared__ unsigned char ms[34][34];
  int blk = blockIdx.x;
  int b  = blk / 28;
  int t  = blk % 28;
  int th = t / 4, tw = t % 4;
  int hp0 = th*16, wp0 = tw*16;
  int h0 = hp0*2 - 1, w0 = wp0*2 - 1;
  int tid = threadIdx.x;
  for (int i=tid;i<432;i+=256) ws1[i>>3][i&7] = w1[i];
  for (int i=tid;i<6*34*34;i+=256){
    int ci=i/1156; int rem=i-ci*1156; int r=rem/34, c=rem-r*34;
    int h=h0+r, w=w0+c;
    float v=0.f;
    if (h>=0 && h<NH0 && w>=0 && w<NW0) v = x[((size_t)(b*NC0+ci)*NH0+h)*NW0+w];
    xs[ci][r][c]=v;
  }
  __syncthreads();
  for (int i=tid;i<1156;i+=256){
    int r=i/34, c=i-r*34;
    bool any=false;
    #pragma unroll
    for (int ci=0;ci<6;ci++) any |= (xs[ci][r][c]!=0.f);
    ms[r][c] = any?1:0;
  }
  __syncthreads();
  for (int i=tid;i<1024;i+=256){
    int r=(i>>5)+1, c=(i&31)+1;
    int h=h0+r, w=w0+c;
    if (h<NH0) m0[(b*NH0+h)*NW0+w] = ms[r][c];
  }
  int lhp = tid>>4, lwp = tid&15;
  int hp = hp0+lhp, wp = wp0+lwp;
  if (hp < NH1){
    float best[8];
    #pragma unroll
    for (int co=0;co<8;co++) best[co]=-1e30f;
    bool many=false;
    #pragma unroll 1
    for (int i=0;i<2;i++)
    #pragma unroll 1
    for (int j=0;j<2;j++){
      int r = lhp*2+i+1, c = lwp*2+j+1;
      if (!ms[r][c]) continue;
      many=true;
      float a[8];
      #pragma unroll
      for (int co=0;co<8;co++) a[co]=b1[co];
      #pragma unroll 1
      for (int kh=0;kh<3;kh++)
      #pragma unroll 1
      for (int kw=0;kw<3;kw++){
        #pragma unroll
        for (int ci=0;ci<6;ci++){
          float v = xs[ci][r-1+kh][c-1+kw];
          const float* wv = ws1[(kh*3+kw)*6+ci];
          #pragma unroll
          for (int co=0;co<8;co++) a[co]=fmaf(v,wv[co],a[co]);
        }
      }
      #pragma unroll
      for (int co=0;co<8;co++) best[co]=fmaxf(best[co], lrelu(a[co]));
    }
    float* yp = y1p + (((size_t)b*NH1+hp)*NW1+wp)*8;
    #pragma unroll
    for (int co=0;co<8;co++) yp[co] = many?best[co]:0.f;
    m1[(b*NH1+hp)*NW1+wp] = many?1:0;
  }
}

// ============ conv2 (3x3,8->16) + lrelu + pool 5x2, small-tile LDS, co-split ============
// out tile 5x16 pool outputs; input halo 27x34 (SoA pad 35); 160 threads x 8co
__global__ __launch_bounds__(256) void k_conv2pool(
    const float* __restrict__ yin, const unsigned char* __restrict__ m1,
    const float* __restrict__ w2, const float* __restrict__ b2,
    float* __restrict__ yout, unsigned char* __restrict__ m2){
  __shared__ float ys[8][27][35];
  __shared__ unsigned char msl[27][35];
  __shared__ float w2s[72][16];
  __shared__ float b2s[16];
  int blk = blockIdx.x;
  int b  = blk >> 3;
  int t  = blk & 7;
  int th = t >> 1, tw = t & 1;       // th 0..3 (5 pool rows each), tw 0..1 (16 pool cols)
  int r0 = th*25 - 1, c0 = tw*32 - 1;
  int tid = threadIdx.x;
  for (int i=tid;i<1152;i+=256) w2s[i>>4][i&15] = w2[i];
  if (tid<16) b2s[tid]=b2[tid];
  for (int p=tid;p<27*34;p+=256){
    int r=p/34, c=p-(p/34)*34;
    int h1=r0+r, w1c=c0+c;
    bool ok = (h1>=0 && h1<NH1 && w1c>=0 && w1c<NW1);
    msl[r][c] = ok ? m1[(b*NH1+h1)*NW1+w1c] : 0;
    float4 v0=make_float4(0,0,0,0), v1=v0;
    if (ok){
      const float4* pp = (const float4*)(yin + (((size_t)b*NH1+h1)*NW1+w1c)*8);
      v0=pp[0]; v1=pp[1];
    }
    ys[0][r][c]=v0.x; ys[1][r][c]=v0.y; ys[2][r][c]=v0.z; ys[3][r][c]=v0.w;
    ys[4][r][c]=v1.x; ys[5][r][c]=v1.y; ys[6][r][c]=v1.z; ys[7][r][c]=v1.w;
  }
  __syncthreads();
  if (tid < 160){
    int oid = tid >> 1, coq = tid & 1;
    int co0 = coq*8;
    int lh = oid >> 4, lw = oid & 15;
    int h2 = th*5+lh, w2c = tw*16+lw;
    float best[8];
    #pragma unroll
    for (int co=0;co<8;co++) best[co]=-1e30f;
    bool many=false;
    #pragma unroll 1
    for (int i=0;i<5;i++)
    #pragma unroll 1
    for (int j=0;j<2;j++){
      int r = lh*5+i+1, c = lw*2+j+1;
      if (!msl[r][c]) continue;
      many=true;
      float a[8];
      #pragma unroll
      for (int co=0;co<8;co++) a[co]=b2s[co0+co];
      #pragma unroll 1
      for (int kh=0;kh<3;kh++)
      #pragma unroll 1
      for (int kw=0;kw<3;kw++){
        #pragma unroll
        for (int ci=0;ci<8;ci++){
          float v = ys[ci][r-1+kh][c-1+kw];
          const float* wr = w2s[(kh*3+kw)*8+ci];
          #pragma unroll
          for (int co=0;co<8;co++) a[co]=fmaf(v,wr[co0+co],a[co]);
        }
      }
      #pragma unroll
      for (int co=0;co<8;co++) best[co]=fmaxf(best[co], lrelu(a[co]));
    }
    float4 o0,o1;
    if (many){
      o0=make_float4(best[0],best[1],best[2],best[3]);
      o1=make_float4(best[4],best[5],best[6],best[7]);
    } else { o0=make_float4(0,0,0,0); o1=o0; }
    float4* op = (float4*)(yout + (((size_t)b*NH2+h2)*NW2+w2c)*16 + co0);
    op[0]=o0; op[1]=o1;
    if (coq==0) m2[(b*NH2+h2)*NW2+w2c] = many?1:0;
  }
}

// ============ conv3 (3x3,16->32) + lrelu + pool 5x2, per-batch LDS-tiled ============
__global__ __launch_bounds__(256) void k_conv3pool(
    const float* __restrict__ yin, const unsigned char* __restrict__ m2,
    const float* __restrict__ w3, const float* __restrict__ b3,
    float* __restrict__ yout, unsigned char* __restrict__ m3){
  __shared__ float ys[16][20][33];
  __shared__ unsigned char msl[20][32];
  __shared__ float w3s[144][32];
  __shared__ float b3s[32];
  int b = blockIdx.x;
  int tid = threadIdx.x;
  for (int i=tid;i<4608;i+=256) w3s[i>>5][i&31] = w3[i];
  if (tid<32) b3s[tid]=b3[tid];
  for (int p=tid;p<640;p+=256){
    int r=p>>5, c=p&31;
    msl[r][c] = m2[(b*NH2+r)*NW2+c];
    const float4* pp = (const float4*)(yin + (((size_t)b*NH2+r)*NW2+c)*16);
    float4 q0=pp[0],q1=pp[1],q2=pp[2],q3=pp[3];
    ys[0][r][c]=q0.x; ys[1][r][c]=q0.y; ys[2][r][c]=q0.z; ys[3][r][c]=q0.w;
    ys[4][r][c]=q1.x; ys[5][r][c]=q1.y; ys[6][r][c]=q1.z; ys[7][r][c]=q1.w;
    ys[8][r][c]=q2.x; ys[9][r][c]=q2.y; ys[10][r][c]=q2.z; ys[11][r][c]=q2.w;
    ys[12][r][c]=q3.x; ys[13][r][c]=q3.y; ys[14][r][c]=q3.z; ys[15][r][c]=q3.w;
  }
  __syncthreads();
  int p = tid>>2, coq = tid&3;
  int co0 = coq*8;
  int hp = p>>4, wp = p&15;
  float best[8];
  #pragma unroll
  for (int co=0;co<8;co++) best[co]=-1e30f;
  bool many=false;
  #pragma unroll 1
  for (int i=0;i<5;i++)
  #pragma unroll 1
  for (int j=0;j<2;j++){
    int h2 = hp*5+i, w2c = wp*2+j;
    if (!msl[h2][w2c]) continue;
    many=true;
    float a[8];
    #pragma unroll
    for (int co=0;co<8;co++) a[co]=b3s[co0+co];
    #pragma unroll 1
    for (int kh=0;kh<3;kh++){
      int hh=h2+kh-1;
      if (hh<0||hh>=NH2) continue;
      #pragma unroll 1
      for (int kw=0;kw<3;kw++){
        int ww=w2c+kw-1;
        if (ww<0||ww>=NW2) continue;
        #pragma unroll
        for (int ci=0;ci<16;ci++){
          float v = ys[ci][hh][ww];
          const float* wr = w3s[(kh*3+kw)*16+ci];
          #pragma unroll
          for (int co=0;co<8;co++) a[co]=fmaf(v,wr[co0+co],a[co]);
        }
      }
    }
    #pragma unroll
    for (int co=0;co<8;co++) best[co]=fmaxf(best[co], lrelu(a[co]));
  }
  float4 o0,o1;
  if (many){
    o0=make_float4(best[0],best[1],best[2],best[3]);
    o1=make_float4(best[4],best[5],best[6],best[7]);
  } else { o0=make_float4(0,0,0,0); o1=o0; }
  float4* op = (float4*)(yout + ((size_t)(b*64+p))*32 + co0);
  op[0]=o0; op[1]=o1;
  if (coq==0) m3[b*64+p] = many?1:0;
}

// ============ latent head + NSF flow + kld + dec ============
__global__ __launch_bounds__(64) void k_latent(
    const float* __restrict__ y3p, const unsigned char* __restrict__ m3,
    const float* __restrict__ eps,
    const float* __restrict__ wmu, const float* __restrict__ bmu,
    const float* __restrict__ wlv, const float* __restrict__ blv,
    const float* __restrict__ wlin, const float* __restrict__ blin,
    const float* __restrict__ fW1, const float* __restrict__ fb1,
    const float* __restrict__ fW2, const float* __restrict__ fb2,
    const float* __restrict__ fW3, const float* __restrict__ fb3,
    float* __restrict__ out_mu, float* __restrict__ out_lv,
    float* __restrict__ out_kld, float* __restrict__ out_zf,
    float* __restrict__ dec)
{
  __shared__ __align__(16) float sW1[NT*HID*LAT];
  __shared__ float sb1[NT*HID];
  __shared__ __align__(16) float sW2[NT*HID*HID];
  __shared__ float sb2[NT*HID];
  __shared__ __align__(16) float sW3[NT*LAT*NPp*HID];
  __shared__ float sb3[NT*LAT*NPp];
  __shared__ float red[64];
  int tid = threadIdx.x;
  for (int i=tid;i<NT*HID*LAT;i+=64){ int j=i&3; int r=(i>>2)%HID; sW1[i]=fW1[i]*(((r%3+1)>=(j+1))?1.f:0.f); }
  for (int i=tid;i<NT*HID;i+=64){ sb1[i]=fb1[i]; sb2[i]=fb2[i]; }
  for (int i=tid;i<NT*HID*HID;i+=64){ int j=i&15; int r=(i>>4)%HID; sW2[i]=fW2[i]*(((r%3+1)>=(j%3+1))?1.f:0.f); }
  for (int i=tid;i<NT*LAT*NPp*HID;i+=64){ int j=i&15; int r=(i>>4)%(LAT*NPp); sW3[i]=fW3[i]*(((r/NPp+1)>(j%3+1))?1.f:0.f); }
  for (int i=tid;i<NT*LAT*NPp;i+=64) sb3[i]=fb3[i];
  __syncthreads();

  int b = blockIdx.x;
  int gpos = b*64 + tid;
  bool msk = m3[gpos]!=0;
  float kld_pc=0.f;
  if (msk){
    float yv[NC3];
    const float* yp = y3p + (size_t)gpos*NC3;
    #pragma unroll
    for (int c=0;c<NC3;c++) yv[c]=yp[c];
    float muv[LAT], lvv[LAT], stdv[LAT], evv[LAT], z0[LAT], z[LAT];
    #pragma unroll
    for (int l=0;l<LAT;l++){
      float a=bmu[l], g=blv[l];
      #pragma unroll
      for (int c=0;c<NC3;c++){ a=fmaf(yv[c],wmu[l*NC3+c],a); g=fmaf(yv[c],wlv[l*NC3+c],g); }
      muv[l]=a; lvv[l]=g;
      stdv[l]=fexpf(0.5f*g);
      evv[l]=eps[(size_t)gpos*LAT+l];
      z0[l]=fmaf(evv[l], stdv[l], a);
      z[l]=z0[l];
    }
    float ld_tot=0.f;
    for (int t=0;t<NT;t++){
      float h1[HID], h2[HID];
      const float* W1t = sW1 + t*HID*LAT;
      const float* b1t = sb1 + t*HID;
      float4 zv = make_float4(z[0],z[1],z[2],z[3]);
      #pragma unroll
      for (int i2=0;i2<HID;i2++){
        float4 wr = *(const float4*)(W1t + i2*4);
        float a = b1t[i2];
        a = fmaf(zv.x,wr.x, fmaf(zv.y,wr.y, fmaf(zv.z,wr.z, fmaf(zv.w,wr.w, a))));
        h1[i2]=fmaxf(a,0.f);
      }
      const float* W2t = sW2 + t*HID*HID;
      const float* b2t = sb2 + t*HID;
      #pragma unroll
      for (int i2=0;i2<HID;i2++){
        float a=b2t[i2];
        const float4* wr = (const float4*)(W2t + i2*HID);
        #pragma unroll
        for (int q=0;q<4;q++){
          float4 w4 = wr[q];
          a = fmaf(h1[q*4+0],w4.x, fmaf(h1[q*4+1],w4.y, fmaf(h1[q*4+2],w4.z, fmaf(h1[q*4+3],w4.w, a))));
        }
        h2[i2]=fmaxf(a,0.f);
      }
      const float* W3t = sW3 + t*LAT*NPp*HID;
      const float* b3t = sb3 + t*LAT*NPp;
      float zn[LAT];
      #pragma unroll
      for (int l=0;l<LAT;l++){
        float p[NPp];
        #pragma unroll
        for (int r=0;r<NPp;r++){
          int rr=l*NPp+r;
          float a=b3t[rr];
          const float4* wr = (const float4*)(W3t + rr*HID);
          #pragma unroll
          for (int q=0;q<4;q++){
            float4 w4 = wr[q];
            a = fmaf(h2[q*4+0],w4.x, fmaf(h2[q*4+1],w4.y, fmaf(h2[q*4+2],w4.z, fmaf(h2[q*4+3],w4.w, a))));
          }
          p[r]=a;
        }
        float mw=fmaxf(fmaxf(p[0],p[1]),fmaxf(p[2],p[3]));
        float e0=fexpf(p[0]-mw), e1=fexpf(p[1]-mw), e2=fexpf(p[2]-mw), e3=fexpf(p[3]-mw);
        float wsc=10.f/(e0+e1+e2+e3);
        float xk1=fmaf(e0,wsc,-BOUNDf), xk2=fmaf(e1,wsc,xk1), xk3=fmaf(e2,wsc,xk2), xk4=fmaf(e3,wsc,xk3);
        float mh=fmaxf(fmaxf(p[4],p[5]),fmaxf(p[6],p[7]));
        float f0=fexpf(p[4]-mh), f1=fexpf(p[5]-mh), f2=fexpf(p[6]-mh), f3=fexpf(p[7]-mh);
        float hsc=10.f/(f0+f1+f2+f3);
        float yk1=fmaf(f0,hsc,-BOUNDf), yk2=fmaf(f1,hsc,yk1), yk3=fmaf(f2,hsc,yk2), yk4=fmaf(f3,hsc,yk3);
        float dk1=softplusf(p[8]), dk2=softplusf(p[9]), dk3=softplusf(p[10]);
        float xv=z[l];
        bool inside = (xv>=-BOUNDf)&&(xv<=BOUNDf);
        float xc=fminf(fmaxf(xv,-BOUNDf),BOUNDf);
        float x0=-BOUNDf, x1=xk1, y0=-BOUNDf, y1=yk1, d0=1.f, d1=dk1;
        if (xc>=xk1){x0=xk1;x1=xk2;y0=yk1;y1=yk2;d0=dk1;d1=dk2;}
        if (xc>=xk2){x0=xk2;x1=xk3;y0=yk2;y1=yk3;d0=dk2;d1=dk3;}
        if (xc>=xk3){x0=xk3;x1=xk4;y0=yk3;y1=yk4;d0=dk3;d1=1.f;}
        float dxv=x1-x0, dyv=y1-y0;
        float sl=dyv/dxv, ttv=(xc-x0)/dxv, omt=1.f-ttv;
        float den=sl + (d1+d0-2.f*sl)*ttv*omt;
        float yo=y0 + dyv*(sl*ttv*ttv + d0*ttv*omt)/den;
        float ldv=flogf(sl*sl*(d1*ttv*ttv + 2.f*sl*ttv*omt + d0*omt*omt)) - 2.f*flogf(den);
        zn[l] = inside ? yo : xv;
        ld_tot += inside ? ldv : 0.f;
      }
      if (t<NT-1){ z[0]=zn[3]; z[1]=zn[2]; z[2]=zn[1]; z[3]=zn[0]; }
      else       { z[0]=zn[0]; z[1]=zn[1]; z[2]=zn[2]; z[3]=zn[3]; }
    }
    float lq=0.f, lp=0.f;
    #pragma unroll
    for (int l=0;l<LAT;l++){
      lq += -0.5f*evv[l]*evv[l] - 0.5f*lvv[l] - 0.5f*LOG2PI;
      lp += -0.5f*z[l]*z[l] - 0.5f*LOG2PI;
    }
    kld_pc = lq - ld_tot - lp;
    #pragma unroll
    for (int l=0;l<LAT;l++){
      out_mu[(size_t)gpos*LAT+l]=muv[l];
      out_lv[(size_t)gpos*LAT+l]=lvv[l];
      out_zf[(size_t)gpos*LAT+l]=z[l];
    }
    #pragma unroll
    for (int k2=0;k2<NC3;k2++){
      float a=blin[k2];
      #pragma unroll
      for (int l=0;l<LAT;l++) a=fmaf(z[l],wlin[k2*LAT+l],a);
      dec[(size_t)gpos*NC3+k2]=a;
    }
  } else {
    #pragma unroll
    for (int l=0;l<LAT;l++){
      out_mu[(size_t)gpos*LAT+l]=0.f;
      out_lv[(size_t)gpos*LAT+l]=0.f;
      out_zf[(size_t)gpos*LAT+l]=0.f;
    }
    for (int k2=0;k2<NC3;k2++) dec[(size_t)gpos*NC3+k2]=0.f;
  }
  red[tid]=kld_pc;
  __syncthreads();
  for (int s=32;s>0;s>>=1){ if (tid<s) red[tid]+=red[tid+s]; __syncthreads(); }
  if (tid==0) out_kld[b]=red[0];
}

// ============ fused invconv1(5,2,32,32) + conv4(3x3,32->16) -> t2, mask m2 ============
__global__ __launch_bounds__(256) void k_ic4(
    const float* __restrict__ dec, const unsigned char* __restrict__ m2,
    const float* __restrict__ u1, const float* __restrict__ bu1,
    const float* __restrict__ w4, const float* __restrict__ b4,
    float* __restrict__ t2){
  __shared__ __align__(16) float vs[12][18][32];
  __shared__ __align__(16) float w4s[288][16];
  __shared__ unsigned char msl[12][18];
  int blk = blockIdx.x;
  int b  = blk >> 2;
  int t  = blk & 3;
  int th = t >> 1, tw = t & 1;
  int h0 = th*10, w0 = tw*16;
  int tid = threadIdx.x;
  for (int i=tid;i<288*16;i+=256) w4s[i>>4][i&15] = w4[i];
  if (tid < 216){
    int lr = tid/18, lc = tid%18;
    int h2 = h0-1+lr, w2 = w0-1+lc;
    bool mk = (h2>=0 && h2<NH2 && w2>=0 && w2<NW2) && m2[(b*NH2+h2)*NW2+w2];
    msl[lr][lc] = mk?1:0;
    float acc[32];
    if (mk){
      const float* dp = dec + (((size_t)b*NH3 + h2/5)*NW3 + w2/2)*NC3;
      const float* up = u1 + ((h2%5)*2 + (w2&1))*1024;
      #pragma unroll
      for (int co=0;co<32;co++) acc[co]=bu1[co];
      #pragma unroll 1
      for (int ci=0;ci<32;ci++){
        float dv = dp[ci];
        const float* ur = up + ci*32;
        #pragma unroll
        for (int co=0;co<32;co++) acc[co]=fmaf(dv,ur[co],acc[co]);
      }
    } else {
      #pragma unroll
      for (int co=0;co<32;co++) acc[co]=0.f;
    }
    #pragma unroll
    for (int co=0;co<32;co++) vs[lr][lc][co]=acc[co];
  }
  __syncthreads();
  if (tid < 160){
    int lh = tid/16, lw = tid%16;
    int h2 = h0+lh, w2 = w0+lw;
    float a[16];
    if (msl[lh+1][lw+1]){
      #pragma unroll
      for (int co=0;co<16;co++) a[co]=b4[co];
      #pragma unroll 1
      for (int kh=0;kh<3;kh++)
      #pragma unroll 1
      for (int kw=0;kw<3;kw++){
        const float* vp = vs[lh+kh][lw+kw];
        #pragma unroll
        for (int ci=0;ci<32;ci++){
          float v = vp[ci];
          const float* wr = w4s[(kh*3+kw)*32+ci];
          #pragma unroll
          for (int co=0;co<16;co++) a[co]=fmaf(v,wr[co],a[co]);
        }
      }
    } else {
      #pragma unroll
      for (int co=0;co<16;co++) a[co]=0.f;
    }
    float* op = t2 + (((size_t)b*NH2+h2)*NW2+w2)*NC2;
    #pragma unroll
    for (int co=0;co<16;co++) op[co]=a[co];
  }
}

// ============ fused invconv2(5,2,16,16) + conv5(3x3,16->8) -> t4, mask m1 ============
__global__ __launch_bounds__(256) void k_ic5(
    const float* __restrict__ t2, const unsigned char* __restrict__ m1,
    const float* __restrict__ u2, const float* __restrict__ bu2,
    const float* __restrict__ w5, const float* __restrict__ b5,
    float* __restrict__ t4){
  __shared__ __align__(16) float vs[12][18][16];
  __shared__ __align__(16) float w5s[144][8];
  __shared__ unsigned char msl[12][18];
  int blk = blockIdx.x;
  int b  = blk / 40;
  int t  = blk % 40;
  int th = t >> 2, tw = t & 3;
  int h0 = th*10, w0 = tw*16;
  int tid = threadIdx.x;
  for (int i=tid;i<144*8;i+=256) w5s[i>>3][i&7] = w5[i];
  if (tid < 216){
    int lr = tid/18, lc = tid%18;
    int h1 = h0-1+lr, w1c = w0-1+lc;
    bool mk = (h1>=0 && h1<NH1 && w1c>=0 && w1c<NW1) && m1[(b*NH1+h1)*NW1+w1c];
    msl[lr][lc] = mk?1:0;
    float acc[16];
    if (mk){
      const float* dp = t2 + (((size_t)b*NH2 + h1/5)*NW2 + w1c/2)*NC2;
      const float* up = u2 + ((h1%5)*2 + (w1c&1))*256;
      #pragma unroll
      for (int co=0;co<16;co++) acc[co]=bu2[co];
      #pragma unroll 1
      for (int ci=0;ci<16;ci++){
        float dv = dp[ci];
        const float* ur = up + ci*16;
        #pragma unroll
        for (int co=0;co<16;co++) acc[co]=fmaf(dv,ur[co],acc[co]);
      }
    } else {
      #pragma unroll
      for (int co=0;co<16;co++) acc[co]=0.f;
    }
    #pragma unroll
    for (int co=0;co<16;co++) vs[lr][lc][co]=acc[co];
  }
  __syncthreads();
  if (tid < 160){
    int lh = tid/16, lw = tid%16;
    int h1 = h0+lh, w1c = w0+lw;
    float a[8];
    if (msl[lh+1][lw+1]){
      #pragma unroll
      for (int co=0;co<8;co++) a[co]=b5[co];
      #pragma unroll 1
      for (int kh=0;kh<3;kh++)
      #pragma unroll 1
      for (int kw=0;kw<3;kw++){
        const float* vp = vs[lh+kh][lw+kw];
        #pragma unroll
        for (int ci=0;ci<16;ci++){
          float v = vp[ci];
          const float* wr = w5s[(kh*3+kw)*16+ci];
          #pragma unroll
          for (int co=0;co<8;co++) a[co]=fmaf(v,wr[co],a[co]);
        }
      }
    } else {
      #pragma unroll
      for (int co=0;co<8;co++) a[co]=0.f;
    }
    float* op = t4 + (((size_t)b*NH1+h1)*NW1+w1c)*NC1;
    #pragma unroll
    for (int co=0;co<8;co++) op[co]=a[co];
  }
}

// ============ fused invconv3 (2,2,8,8) + conv6 (3x3,8->6), LDS-tiled ============
__global__ __launch_bounds__(256) void k_inv3conv6(
    const float* __restrict__ t4, const unsigned char* __restrict__ m0,
    const float* __restrict__ u3, const float* __restrict__ bu3,
    const float* __restrict__ w6, const float* __restrict__ b6,
    float* __restrict__ out){
  __shared__ float ts[8][10][36];
  __shared__ unsigned char msl[18][66];
  __shared__ float u3s[4][8][8];
  __shared__ float w6s[9][8][6];
  __shared__ float bu3s[8];
  __shared__ float b6s[6];
  int blk = blockIdx.x;
  int b  = blk / 26;
  int t  = blk % 26;
  int th = t >> 1, tw = t & 1;
  int h0 = th*16, w0 = tw*64;
  int base_r = 8*th - 1, base_c = 32*tw - 1;
  int tid = threadIdx.x;
  for (int i=tid;i<256;i+=256){ int pos=i>>6; int rem=i&63; u3s[pos][rem>>3][rem&7]=u3[i]; }
  for (int i=tid;i<432;i+=256){ int tap=i/48; int rem=i%48; w6s[tap][rem/6][rem%6]=w6[i]; }
  if (tid<8) bu3s[tid]=bu3[tid];
  if (tid<6) b6s[tid]=b6[tid];
  for (int p=tid;p<340;p+=256){
    int r=p/34, c=p-(p/34)*34;
    int h1=base_r+r, w1c=base_c+c;
    float4 v0=make_float4(0,0,0,0), v1=v0;
    if (h1>=0 && h1<NH1 && w1c>=0 && w1c<NW1){
      const float4* pp = (const float4*)(t4 + (((size_t)b*NH1+h1)*NW1+w1c)*8);
      v0=pp[0]; v1=pp[1];
    }
    ts[0][r][c]=v0.x; ts[1][r][c]=v0.y; ts[2][r][c]=v0.z; ts[3][r][c]=v0.w;
    ts[4][r][c]=v1.x; ts[5][r][c]=v1.y; ts[6][r][c]=v1.z; ts[7][r][c]=v1.w;
  }
  for (int p=tid;p<18*66;p+=256){
    int r=p/66, c=p-(p/66)*66;
    int h=h0-1+r, w=w0-1+c;
    msl[r][c] = (h>=0 && h<NH0 && w>=0 && w<NW0) ? m0[(b*NH0+h)*NW0+w] : 0;
  }
  __syncthreads();
  #pragma unroll 1
  for (int k=0;k<4;k++){
    int p = tid + k*256;
    int lh = p>>6, lw = p&63;
    int h = h0+lh, w = w0+lw;
    if (h >= NH0) continue;
    float acc[6];
    if (msl[lh+1][lw+1]){
      #pragma unroll
      for (int co=0;co<6;co++) acc[co]=b6s[co];
      #pragma unroll 1
      for (int kh=0;kh<3;kh++)
      #pragma unroll 1
      for (int kw=0;kw<3;kw++){
        if (!msl[lh+kh][lw+kw]) continue;
        int hh = h+kh-1, ww = w+kw-1;
        int tr = (hh>>1) - base_r, tc = (ww>>1) - base_c;
        int pos = (hh&1)*2 + (ww&1);
        float v8[8];
        #pragma unroll
        for (int c8=0;c8<8;c8++) v8[c8]=bu3s[c8];
        #pragma unroll
        for (int ci=0;ci<8;ci++){
          float v = ts[ci][tr][tc];
          #pragma unroll
          for (int c8=0;c8<8;c8++) v8[c8]=fmaf(v, u3s[pos][ci][c8], v8[c8]);
        }
        const float (*wt)[6] = w6s[kh*3+kw];
        #pragma unroll
        for (int ci=0;ci<8;ci++)
          #pragma unroll
          for (int co=0;co<6;co++) acc[co]=fmaf(v8[ci], wt[ci][co], acc[co]);
      }
    } else {
      #pragma unroll
      for (int co=0;co<6;co++) acc[co]=0.f;
    }
    size_t base = (size_t)b*6*NH0*NW0 + (size_t)h*NW0 + w;
    #pragma unroll
    for (int co=0;co<6;co++) out[base + (size_t)co*NH0*NW0] = acc[co];
  }
}

extern "C" void kernel_launch(void* const* d_in, const int* in_sizes, int n_in,
                              void* d_out, int out_size, void* d_ws, size_t ws_size,
                              hipStream_t stream){
  (void)in_sizes; (void)n_in; (void)out_size; (void)ws_size;
  const float* x    = (const float*)d_in[0];
  const float* eps  = (const float*)d_in[1];
  const float* w1   = (const float*)d_in[2];
  const float* b1   = (const float*)d_in[3];
  const float* w2   = (const float*)d_in[4];
  const float* b2   = (const float*)d_in[5];
  const float* w3   = (const float*)d_in[6];
  const float* b3   = (const float*)d_in[7];
  const float* wmu  = (const float*)d_in[8];
  const float* bmu  = (const float*)d_in[9];
  const float* wlv  = (const float*)d_in[10];
  const float* blv  = (const float*)d_in[11];
  const float* wlin = (const float*)d_in[12];
  const float* blin = (const float*)d_in[13];
  const float* u1   = (const float*)d_in[14];
  const float* bu1  = (const float*)d_in[15];
  const float* w4   = (const float*)d_in[16];
  const float* b4   = (const float*)d_in[17];
  const float* u2   = (const float*)d_in[18];
  const float* bu2  = (const float*)d_in[19];
  const float* w5   = (const float*)d_in[20];
  const float* b5   = (const float*)d_in[21];
  const float* u3   = (const float*)d_in[22];
  const float* bu3  = (const float*)d_in[23];
  const float* w6   = (const float*)d_in[24];
  const float* b6   = (const float*)d_in[25];
  const float* fW1  = (const float*)d_in[26];
  const float* fb1  = (const float*)d_in[27];
  const float* fW2  = (const float*)d_in[28];
  const float* fb2  = (const float*)d_in[29];
  const float* fW3  = (const float*)d_in[30];
  const float* fb3  = (const float*)d_in[31];

  char* ws = (char*)d_ws;
  unsigned char* m0 = (unsigned char*)(ws);
  unsigned char* m1 = (unsigned char*)(ws + 3276800);
  unsigned char* m2 = (unsigned char*)(ws + 4096000);
  unsigned char* m3 = (unsigned char*)(ws + 4177920);
  float* y1p = (float*)(ws + 4194304);    // [B][100][64][8]
  float* y2p = (float*)(ws + 30408704);   // [B][20][32][16]
  float* y3p = (float*)(ws + 35651584);   // [B][4][16][32]
  float* dec = (float*)(ws + 36700160);   // [B][4][16][32]
  float* t2  = y2p;  // reuse
  float* t4  = y1p;  // reuse

  float* out   = (float*)d_out;
  float* o_mu  = out + 19660800;
  float* o_lv  = out + 19693568;
  float* o_kld = out + 19726336;
  float* o_zf  = out + 19726464;

  k_conv1pool<<< 3584,256,0,stream>>>(x, w1, b1, y1p, m0, m1);
  k_conv2pool<<< 1024,256,0,stream>>>(y1p, m1, w2, b2, y2p, m2);
  k_conv3pool<<<  128,256,0,stream>>>(y2p, m2, w3, b3, y3p, m3);
  k_latent   <<<  128, 64,0,stream>>>(y3p, m3, eps, wmu,bmu,wlv,blv,wlin,blin,
                                      fW1,fb1,fW2,fb2,fW3,fb3, o_mu,o_lv,o_kld,o_zf, dec);
  k_ic4      <<<  512,256,0,stream>>>(dec, m2, u1, bu1, w4, b4, t2);
  k_ic5      <<< 5120,256,0,stream>>>(t2, m1, u2, bu2, w5, b5, t4);
  k_inv3conv6<<< 3328,256,0,stream>>>(t4, m0, u3, bu3, w6, b6, out);
}

// Round 6
// 481.976 us; speedup vs baseline: 3.1829x; 1.0823x over previous
//
#include <hip/hip_runtime.h>
#include <math.h>

constexpr int NB=128;
constexpr int NH0=200, NW0=128, NC0=6;
constexpr int NH1=100, NW1=64,  NC1=8;
constexpr int NH2=20,  NW2=32,  NC2=16;
constexpr int NH3=4,   NW3=16,  NC3=32;
constexpr int LAT=4, NPp=11, HID=16, NT=10;
constexpr float BOUNDf=5.0f;
constexpr float LOG2PI=1.8378770664093453f;

__device__ __forceinline__ float fexpf(float v){ return __expf(v); }
__device__ __forceinline__ float flogf(float v){ return __logf(v); }
__device__ __forceinline__ float softplusf(float v){ return v>20.f ? v : __logf(1.f+__expf(v)); }
__device__ __forceinline__ float lrelu(float v){ return v>0.f ? v : 0.01f*v; }

// ============ conv1 (3x3,6->8) + lrelu + pool2x2, LDS-tiled, computes m0,m1 ============
__global__ __launch_bounds__(256) void k_conv1pool(
    const float* __restrict__ x, const float* __restrict__ w1, const float* __restrict__ b1,
    float* __restrict__ y1p, unsigned char* __restrict__ m0, unsigned char* __restrict__ m1){
  __shared__ float xs[6][34][34];
  __shared__ float ws1[54][8];
  __shared__ unsigned char ms[34][34];
  int blk = blockIdx.x;
  int b  = blk / 28;
  int t  = blk % 28;
  int th = t / 4, tw = t % 4;
  int hp0 = th*16, wp0 = tw*16;
  int h0 = hp0*2 - 1, w0 = wp0*2 - 1;
  int tid = threadIdx.x;
  for (int i=tid;i<432;i+=256) ws1[i>>3][i&7] = w1[i];
  for (int i=tid;i<6*34*34;i+=256){
    int ci=i/1156; int rem=i-ci*1156; int r=rem/34, c=rem-r*34;
    int h=h0+r, w=w0+c;
    float v=0.f;
    if (h>=0 && h<NH0 && w>=0 && w<NW0) v = x[((size_t)(b*NC0+ci)*NH0+h)*NW0+w];
    xs[ci][r][c]=v;
  }
  __syncthreads();
  for (int i=tid;i<1156;i+=256){
    int r=i/34, c=i-r*34;
    bool any=false;
    #pragma unroll
    for (int ci=0;ci<6;ci++) any |= (xs[ci][r][c]!=0.f);
    ms[r][c] = any?1:0;
  }
  __syncthreads();
  for (int i=tid;i<1024;i+=256){
    int r=(i>>5)+1, c=(i&31)+1;
    int h=h0+r, w=w0+c;
    if (h<NH0) m0[(b*NH0+h)*NW0+w] = ms[r][c];
  }
  int lhp = tid>>4, lwp = tid&15;
  int hp = hp0+lhp, wp = wp0+lwp;
  if (hp < NH1){
    float best[8];
    #pragma unroll
    for (int co=0;co<8;co++) best[co]=-1e30f;
    bool many=false;
    #pragma unroll 1
    for (int i=0;i<2;i++)
    #pragma unroll 1
    for (int j=0;j<2;j++){
      int r = lhp*2+i+1, c = lwp*2+j+1;
      if (!ms[r][c]) continue;
      many=true;
      float a[8];
      #pragma unroll
      for (int co=0;co<8;co++) a[co]=b1[co];
      #pragma unroll 1
      for (int kh=0;kh<3;kh++)
      #pragma unroll 1
      for (int kw=0;kw<3;kw++){
        #pragma unroll
        for (int ci=0;ci<6;ci++){
          float v = xs[ci][r-1+kh][c-1+kw];
          const float* wv = ws1[(kh*3+kw)*6+ci];
          #pragma unroll
          for (int co=0;co<8;co++) a[co]=fmaf(v,wv[co],a[co]);
        }
      }
      #pragma unroll
      for (int co=0;co<8;co++) best[co]=fmaxf(best[co], lrelu(a[co]));
    }
    float* yp = y1p + (((size_t)b*NH1+hp)*NW1+wp)*8;
    #pragma unroll
    for (int co=0;co<8;co++) yp[co] = many?best[co]:0.f;
    m1[(b*NH1+hp)*NW1+wp] = many?1:0;
  }
}

// ============ conv2 (3x3,8->16) + lrelu + pool 5x2, small-tile LDS, co-split ============
__global__ __launch_bounds__(256) void k_conv2pool(
    const float* __restrict__ yin, const unsigned char* __restrict__ m1,
    const float* __restrict__ w2, const float* __restrict__ b2,
    float* __restrict__ yout, unsigned char* __restrict__ m2){
  __shared__ float ys[8][27][35];
  __shared__ unsigned char msl[27][35];
  __shared__ float w2s[72][16];
  __shared__ float b2s[16];
  int blk = blockIdx.x;
  int b  = blk >> 3;
  int t  = blk & 7;
  int th = t >> 1, tw = t & 1;
  int r0 = th*25 - 1, c0 = tw*32 - 1;
  int tid = threadIdx.x;
  for (int i=tid;i<1152;i+=256) w2s[i>>4][i&15] = w2[i];
  if (tid<16) b2s[tid]=b2[tid];
  for (int p=tid;p<27*34;p+=256){
    int r=p/34, c=p-(p/34)*34;
    int h1=r0+r, w1c=c0+c;
    bool ok = (h1>=0 && h1<NH1 && w1c>=0 && w1c<NW1);
    msl[r][c] = ok ? m1[(b*NH1+h1)*NW1+w1c] : 0;
    float4 v0=make_float4(0,0,0,0), v1=v0;
    if (ok){
      const float4* pp = (const float4*)(yin + (((size_t)b*NH1+h1)*NW1+w1c)*8);
      v0=pp[0]; v1=pp[1];
    }
    ys[0][r][c]=v0.x; ys[1][r][c]=v0.y; ys[2][r][c]=v0.z; ys[3][r][c]=v0.w;
    ys[4][r][c]=v1.x; ys[5][r][c]=v1.y; ys[6][r][c]=v1.z; ys[7][r][c]=v1.w;
  }
  __syncthreads();
  if (tid < 160){
    int oid = tid >> 1, coq = tid & 1;
    int co0 = coq*8;
    int lh = oid >> 4, lw = oid & 15;
    int h2 = th*5+lh, w2c = tw*16+lw;
    float best[8];
    #pragma unroll
    for (int co=0;co<8;co++) best[co]=-1e30f;
    bool many=false;
    #pragma unroll 1
    for (int i=0;i<5;i++)
    #pragma unroll 1
    for (int j=0;j<2;j++){
      int r = lh*5+i+1, c = lw*2+j+1;
      if (!msl[r][c]) continue;
      many=true;
      float a[8];
      #pragma unroll
      for (int co=0;co<8;co++) a[co]=b2s[co0+co];
      #pragma unroll 1
      for (int kh=0;kh<3;kh++)
      #pragma unroll 1
      for (int kw=0;kw<3;kw++){
        #pragma unroll
        for (int ci=0;ci<8;ci++){
          float v = ys[ci][r-1+kh][c-1+kw];
          const float* wr = w2s[(kh*3+kw)*8+ci];
          #pragma unroll
          for (int co=0;co<8;co++) a[co]=fmaf(v,wr[co0+co],a[co]);
        }
      }
      #pragma unroll
      for (int co=0;co<8;co++) best[co]=fmaxf(best[co], lrelu(a[co]));
    }
    float4 o0,o1;
    if (many){
      o0=make_float4(best[0],best[1],best[2],best[3]);
      o1=make_float4(best[4],best[5],best[6],best[7]);
    } else { o0=make_float4(0,0,0,0); o1=o0; }
    float4* op = (float4*)(yout + (((size_t)b*NH2+h2)*NW2+w2c)*16 + co0);
    op[0]=o0; op[1]=o1;
    if (coq==0) m2[(b*NH2+h2)*NW2+w2c] = many?1:0;
  }
}

// ============ conv3 (3x3,16->32) + lrelu + pool 5x2, per-batch LDS-tiled ============
__global__ __launch_bounds__(256) void k_conv3pool(
    const float* __restrict__ yin, const unsigned char* __restrict__ m2,
    const float* __restrict__ w3, const float* __restrict__ b3,
    float* __restrict__ yout, unsigned char* __restrict__ m3,
    float* __restrict__ out_kld){
  __shared__ float ys[16][20][33];
  __shared__ unsigned char msl[20][32];
  __shared__ float w3s[144][32];
  __shared__ float b3s[32];
  int b = blockIdx.x;
  int tid = threadIdx.x;
  if (tid==0) out_kld[b]=0.f;
  for (int i=tid;i<4608;i+=256) w3s[i>>5][i&31] = w3[i];
  if (tid<32) b3s[tid]=b3[tid];
  for (int p=tid;p<640;p+=256){
    int r=p>>5, c=p&31;
    msl[r][c] = m2[(b*NH2+r)*NW2+c];
    const float4* pp = (const float4*)(yin + (((size_t)b*NH2+r)*NW2+c)*16);
    float4 q0=pp[0],q1=pp[1],q2=pp[2],q3=pp[3];
    ys[0][r][c]=q0.x; ys[1][r][c]=q0.y; ys[2][r][c]=q0.z; ys[3][r][c]=q0.w;
    ys[4][r][c]=q1.x; ys[5][r][c]=q1.y; ys[6][r][c]=q1.z; ys[7][r][c]=q1.w;
    ys[8][r][c]=q2.x; ys[9][r][c]=q2.y; ys[10][r][c]=q2.z; ys[11][r][c]=q2.w;
    ys[12][r][c]=q3.x; ys[13][r][c]=q3.y; ys[14][r][c]=q3.z; ys[15][r][c]=q3.w;
  }
  __syncthreads();
  int p = tid>>2, coq = tid&3;
  int co0 = coq*8;
  int hp = p>>4, wp = p&15;
  float best[8];
  #pragma unroll
  for (int co=0;co<8;co++) best[co]=-1e30f;
  bool many=false;
  #pragma unroll 1
  for (int i=0;i<5;i++)
  #pragma unroll 1
  for (int j=0;j<2;j++){
    int h2 = hp*5+i, w2c = wp*2+j;
    if (!msl[h2][w2c]) continue;
    many=true;
    float a[8];
    #pragma unroll
    for (int co=0;co<8;co++) a[co]=b3s[co0+co];
    #pragma unroll 1
    for (int kh=0;kh<3;kh++){
      int hh=h2+kh-1;
      if (hh<0||hh>=NH2) continue;
      #pragma unroll 1
      for (int kw=0;kw<3;kw++){
        int ww=w2c+kw-1;
        if (ww<0||ww>=NW2) continue;
        #pragma unroll
        for (int ci=0;ci<16;ci++){
          float v = ys[ci][hh][ww];
          const float* wr = w3s[(kh*3+kw)*16+ci];
          #pragma unroll
          for (int co=0;co<8;co++) a[co]=fmaf(v,wr[co0+co],a[co]);
        }
      }
    }
    #pragma unroll
    for (int co=0;co<8;co++) best[co]=fmaxf(best[co], lrelu(a[co]));
  }
  float4 o0,o1;
  if (many){
    o0=make_float4(best[0],best[1],best[2],best[3]);
    o1=make_float4(best[4],best[5],best[6],best[7]);
  } else { o0=make_float4(0,0,0,0); o1=o0; }
  float4* op = (float4*)(yout + ((size_t)(b*64+p))*32 + co0);
  op[0]=o0; op[1]=o1;
  if (coq==0) m3[b*64+p] = many?1:0;
}

// ============ latent head + NSF flow + kld + dec; 4 lanes per position ============
// grid: 512 blocks x 64 threads. block k: batch b=k/4, positions (k%4)*16..+16
__global__ __launch_bounds__(64) void k_latent(
    const float* __restrict__ y3p, const unsigned char* __restrict__ m3,
    const float* __restrict__ eps,
    const float* __restrict__ wmu, const float* __restrict__ bmu,
    const float* __restrict__ wlv, const float* __restrict__ blv,
    const float* __restrict__ wlin, const float* __restrict__ blin,
    const float* __restrict__ fW1, const float* __restrict__ fb1,
    const float* __restrict__ fW2, const float* __restrict__ fb2,
    const float* __restrict__ fW3, const float* __restrict__ fb3,
    float* __restrict__ out_mu, float* __restrict__ out_lv,
    float* __restrict__ out_kld, float* __restrict__ out_zf,
    float* __restrict__ dec)
{
  __shared__ __align__(16) float sW1[NT*HID*LAT];
  __shared__ float sb1[NT*HID];
  __shared__ __align__(16) float sW2[NT*HID*HID];
  __shared__ float sb2[NT*HID];
  __shared__ __align__(16) float sW3[NT*LAT*NPp*HID];
  __shared__ float sb3[NT*LAT*NPp];
  __shared__ __align__(16) float swmu[LAT*NC3];
  __shared__ __align__(16) float swlv[LAT*NC3];
  __shared__ __align__(16) float slin[NC3*LAT];
  __shared__ float sbmu[LAT], sblv[LAT], sblin[NC3];
  int tid = threadIdx.x;
  for (int i=tid;i<NT*HID*LAT;i+=64){ int j=i&3; int r=(i>>2)%HID; sW1[i]=fW1[i]*(((r%3+1)>=(j+1))?1.f:0.f); }
  for (int i=tid;i<NT*HID;i+=64){ sb1[i]=fb1[i]; sb2[i]=fb2[i]; }
  for (int i=tid;i<NT*HID*HID;i+=64){ int j=i&15; int r=(i>>4)%HID; sW2[i]=fW2[i]*(((r%3+1)>=(j%3+1))?1.f:0.f); }
  for (int i=tid;i<NT*LAT*NPp*HID;i+=64){ int j=i&15; int r=(i>>4)%(LAT*NPp); sW3[i]=fW3[i]*(((r/NPp+1)>(j%3+1))?1.f:0.f); }
  for (int i=tid;i<NT*LAT*NPp;i+=64) sb3[i]=fb3[i];
  for (int i=tid;i<LAT*NC3;i+=64){ swmu[i]=wmu[i]; swlv[i]=wlv[i]; slin[i]=wlin[i]; }
  if (tid<LAT){ sbmu[tid]=bmu[tid]; sblv[tid]=blv[tid]; }
  for (int i=tid;i<NC3;i+=64) sblin[i]=blin[i];
  __syncthreads();

  int blk = blockIdx.x;
  int b   = blk >> 2;
  int gpos = b*64 + (blk&3)*16 + (tid>>2);
  int g = tid & 3;
  bool msk = m3[gpos]!=0;
  float kld_part = 0.f;
  if (msk){
    // head: lane g computes mu/lv for latent g
    const float4* yp = (const float4*)(y3p + (size_t)gpos*NC3);
    const float4* wm = (const float4*)(swmu + g*NC3);
    const float4* wl = (const float4*)(swlv + g*NC3);
    float mu_g = sbmu[g], lv_g = sblv[g];
    #pragma unroll
    for (int q=0;q<8;q++){
      float4 yq = yp[q], a = wm[q], c = wl[q];
      mu_g = fmaf(yq.x,a.x, fmaf(yq.y,a.y, fmaf(yq.z,a.z, fmaf(yq.w,a.w, mu_g))));
      lv_g = fmaf(yq.x,c.x, fmaf(yq.y,c.y, fmaf(yq.z,c.z, fmaf(yq.w,c.w, lv_g))));
    }
    float std_g = fexpf(0.5f*lv_g);
    float ev_g  = eps[(size_t)gpos*LAT+g];
    float z0_g  = fmaf(ev_g, std_g, mu_g);
    float zg = z0_g;
    float z[4];
    z[g]=zg; z[g^1]=__shfl_xor(zg,1); z[g^2]=__shfl_xor(zg,2); z[g^3]=__shfl_xor(zg,3);
    float ld_g = 0.f;
    for (int t=0;t<NT;t++){
      // h1 full (16 units x 4)
      float h1[16];
      const float4* W1t = (const float4*)(sW1 + t*HID*LAT);
      const float*  b1t = sb1 + t*HID;
      #pragma unroll
      for (int i2=0;i2<16;i2++){
        float4 w = W1t[i2];
        float a = b1t[i2];
        a = fmaf(z[0],w.x, fmaf(z[1],w.y, fmaf(z[2],w.z, fmaf(z[3],w.w, a))));
        h1[i2]=fmaxf(a,0.f);
      }
      // h2 own rows g*4..g*4+3
      float h2o[4];
      const float* W2t = sW2 + t*HID*HID;
      const float* b2t = sb2 + t*HID;
      #pragma unroll
      for (int k=0;k<4;k++){
        int row = g*4+k;
        const float4* wr = (const float4*)(W2t + row*HID);
        float a = b2t[row];
        #pragma unroll
        for (int q=0;q<4;q++){
          float4 w = wr[q];
          a = fmaf(h1[q*4+0],w.x, fmaf(h1[q*4+1],w.y, fmaf(h1[q*4+2],w.z, fmaf(h1[q*4+3],w.w, a))));
        }
        h2o[k]=fmaxf(a,0.f);
      }
      // exchange h2 -> full
      float h2[16];
      #pragma unroll
      for (int k=0;k<4;k++) h2[g*4+k]=h2o[k];
      #pragma unroll
      for (int mski=1;mski<4;mski++){
        int og = g^mski;
        #pragma unroll
        for (int k=0;k<4;k++) h2[og*4+k]=__shfl_xor(h2o[k],mski);
      }
      // p rows g*11..g*11+10  (latent g's params)
      float p[NPp];
      const float* W3t = sW3 + t*LAT*NPp*HID;
      const float* b3t = sb3 + t*LAT*NPp;
      #pragma unroll
      for (int r=0;r<NPp;r++){
        int row = g*NPp+r;
        const float4* wr = (const float4*)(W3t + row*HID);
        float a = b3t[row];
        #pragma unroll
        for (int q=0;q<4;q++){
          float4 w = wr[q];
          a = fmaf(h2[q*4+0],w.x, fmaf(h2[q*4+1],w.y, fmaf(h2[q*4+2],w.z, fmaf(h2[q*4+3],w.w, a))));
        }
        p[r]=a;
      }
      // RQS on latent g
      float mw=fmaxf(fmaxf(p[0],p[1]),fmaxf(p[2],p[3]));
      float e0=fexpf(p[0]-mw), e1=fexpf(p[1]-mw), e2=fexpf(p[2]-mw), e3=fexpf(p[3]-mw);
      float wsc=10.f/(e0+e1+e2+e3);
      float xk1=fmaf(e0,wsc,-BOUNDf), xk2=fmaf(e1,wsc,xk1), xk3=fmaf(e2,wsc,xk2), xk4=fmaf(e3,wsc,xk3);
      float mh=fmaxf(fmaxf(p[4],p[5]),fmaxf(p[6],p[7]));
      float f0=fexpf(p[4]-mh), f1=fexpf(p[5]-mh), f2=fexpf(p[6]-mh), f3=fexpf(p[7]-mh);
      float hsc=10.f/(f0+f1+f2+f3);
      float yk1=fmaf(f0,hsc,-BOUNDf), yk2=fmaf(f1,hsc,yk1), yk3=fmaf(f2,hsc,yk2), yk4=fmaf(f3,hsc,yk3);
      float dk1=softplusf(p[8]), dk2=softplusf(p[9]), dk3=softplusf(p[10]);
      float xv=z[g];
      bool inside = (xv>=-BOUNDf)&&(xv<=BOUNDf);
      float xc=fminf(fmaxf(xv,-BOUNDf),BOUNDf);
      float x0=-BOUNDf, x1=xk1, y0=-BOUNDf, y1=yk1, d0=1.f, d1=dk1;
      if (xc>=xk1){x0=xk1;x1=xk2;y0=yk1;y1=yk2;d0=dk1;d1=dk2;}
      if (xc>=xk2){x0=xk2;x1=xk3;y0=yk2;y1=yk3;d0=dk2;d1=dk3;}
      if (xc>=xk3){x0=xk3;x1=xk4;y0=yk3;y1=yk4;d0=dk3;d1=1.f;}
      float dxv=x1-x0, dyv=y1-y0;
      float sl=dyv/dxv, ttv=(xc-x0)/dxv, omt=1.f-ttv;
      float den=sl + (d1+d0-2.f*sl)*ttv*omt;
      float yo=y0 + dyv*(sl*ttv*ttv + d0*ttv*omt)/den;
      float ldv=flogf(sl*sl*(d1*ttv*ttv + 2.f*sl*ttv*omt + d0*omt*omt)) - 2.f*flogf(den);
      float zn_g = inside ? yo : xv;
      ld_g += inside ? ldv : 0.f;
      // gather new z
      float znf[4];
      znf[g]=zn_g; znf[g^1]=__shfl_xor(zn_g,1); znf[g^2]=__shfl_xor(zn_g,2); znf[g^3]=__shfl_xor(zn_g,3);
      if (t<NT-1){ z[0]=znf[3]; z[1]=znf[2]; z[2]=znf[1]; z[3]=znf[0]; }
      else       { z[0]=znf[0]; z[1]=znf[1]; z[2]=znf[2]; z[3]=znf[3]; }
    }
    float lq_g = -0.5f*ev_g*ev_g - 0.5f*lv_g - 0.5f*LOG2PI;
    float lp_g = -0.5f*z[g]*z[g] - 0.5f*LOG2PI;
    kld_part = lq_g - ld_g - lp_g;
    out_mu[(size_t)gpos*LAT+g]=mu_g;
    out_lv[(size_t)gpos*LAT+g]=lv_g;
    out_zf[(size_t)gpos*LAT+g]=z[g];
    // dec: lane g computes channels g*8..g*8+7
    float4 d0v, d1v;
    {
      float dv[8];
      #pragma unroll
      for (int k=0;k<8;k++){
        int c = g*8+k;
        const float4 w = ((const float4*)slin)[c];
        dv[k] = fmaf(z[0],w.x, fmaf(z[1],w.y, fmaf(z[2],w.z, fmaf(z[3],w.w, sblin[c]))));
      }
      d0v=make_float4(dv[0],dv[1],dv[2],dv[3]);
      d1v=make_float4(dv[4],dv[5],dv[6],dv[7]);
    }
    float4* dp = (float4*)(dec + (size_t)gpos*NC3 + g*8);
    dp[0]=d0v; dp[1]=d1v;
  } else {
    out_mu[(size_t)gpos*LAT+g]=0.f;
    out_lv[(size_t)gpos*LAT+g]=0.f;
    out_zf[(size_t)gpos*LAT+g]=0.f;
    float4 zv = make_float4(0,0,0,0);
    float4* dp = (float4*)(dec + (size_t)gpos*NC3 + g*8);
    dp[0]=zv; dp[1]=zv;
  }
  // wave-level kld reduction (block = 1 wave of 64)
  float s = kld_part;
  s += __shfl_xor(s,1);  s += __shfl_xor(s,2);
  s += __shfl_xor(s,4);  s += __shfl_xor(s,8);
  s += __shfl_xor(s,16); s += __shfl_xor(s,32);
  if (tid==0) atomicAdd(&out_kld[b], s);
}

// ============ fused invconv1(5,2,32,32) + conv4(3x3,32->16) -> t2, mask m2 ============
__global__ __launch_bounds__(256) void k_ic4(
    const float* __restrict__ dec, const unsigned char* __restrict__ m2,
    const float* __restrict__ u1, const float* __restrict__ bu1,
    const float* __restrict__ w4, const float* __restrict__ b4,
    float* __restrict__ t2){
  __shared__ __align__(16) float vs[12][18][32];
  __shared__ __align__(16) float w4s[288][16];
  __shared__ unsigned char msl[12][18];
  int blk = blockIdx.x;
  int b  = blk >> 2;
  int t  = blk & 3;
  int th = t >> 1, tw = t & 1;
  int h0 = th*10, w0 = tw*16;
  int tid = threadIdx.x;
  for (int i=tid;i<288*16;i+=256) w4s[i>>4][i&15] = w4[i];
  if (tid < 216){
    int lr = tid/18, lc = tid%18;
    int h2 = h0-1+lr, w2 = w0-1+lc;
    bool mk = (h2>=0 && h2<NH2 && w2>=0 && w2<NW2) && m2[(b*NH2+h2)*NW2+w2];
    msl[lr][lc] = mk?1:0;
    float acc[32];
    if (mk){
      const float* dp = dec + (((size_t)b*NH3 + h2/5)*NW3 + w2/2)*NC3;
      const float* up = u1 + ((h2%5)*2 + (w2&1))*1024;
      #pragma unroll
      for (int co=0;co<32;co++) acc[co]=bu1[co];
      #pragma unroll 1
      for (int ci=0;ci<32;ci++){
        float dv = dp[ci];
        const float* ur = up + ci*32;
        #pragma unroll
        for (int co=0;co<32;co++) acc[co]=fmaf(dv,ur[co],acc[co]);
      }
    } else {
      #pragma unroll
      for (int co=0;co<32;co++) acc[co]=0.f;
    }
    #pragma unroll
    for (int co=0;co<32;co++) vs[lr][lc][co]=acc[co];
  }
  __syncthreads();
  if (tid < 160){
    int lh = tid/16, lw = tid%16;
    int h2 = h0+lh, w2 = w0+lw;
    float a[16];
    if (msl[lh+1][lw+1]){
      #pragma unroll
      for (int co=0;co<16;co++) a[co]=b4[co];
      #pragma unroll 1
      for (int kh=0;kh<3;kh++)
      #pragma unroll 1
      for (int kw=0;kw<3;kw++){
        const float* vp = vs[lh+kh][lw+kw];
        #pragma unroll
        for (int ci=0;ci<32;ci++){
          float v = vp[ci];
          const float* wr = w4s[(kh*3+kw)*32+ci];
          #pragma unroll
          for (int co=0;co<16;co++) a[co]=fmaf(v,wr[co],a[co]);
        }
      }
    } else {
      #pragma unroll
      for (int co=0;co<16;co++) a[co]=0.f;
    }
    float* op = t2 + (((size_t)b*NH2+h2)*NW2+w2)*NC2;
    #pragma unroll
    for (int co=0;co<16;co++) op[co]=a[co];
  }
}

// ============ fused invconv2(5,2,16,16) + conv5(3x3,16->8) -> t4, mask m1 ============
__global__ __launch_bounds__(256) void k_ic5(
    const float* __restrict__ t2, const unsigned char* __restrict__ m1,
    const float* __restrict__ u2, const float* __restrict__ bu2,
    const float* __restrict__ w5, const float* __restrict__ b5,
    float* __restrict__ t4){
  __shared__ __align__(16) float vs[12][18][16];
  __shared__ __align__(16) float w5s[144][8];
  __shared__ unsigned char msl[12][18];
  int blk = blockIdx.x;
  int b  = blk / 40;
  int t  = blk % 40;
  int th = t >> 2, tw = t & 3;
  int h0 = th*10, w0 = tw*16;
  int tid = threadIdx.x;
  for (int i=tid;i<144*8;i+=256) w5s[i>>3][i&7] = w5[i];
  if (tid < 216){
    int lr = tid/18, lc = tid%18;
    int h1 = h0-1+lr, w1c = w0-1+lc;
    bool mk = (h1>=0 && h1<NH1 && w1c>=0 && w1c<NW1) && m1[(b*NH1+h1)*NW1+w1c];
    msl[lr][lc] = mk?1:0;
    float acc[16];
    if (mk){
      const float* dp = t2 + (((size_t)b*NH2 + h1/5)*NW2 + w1c/2)*NC2;
      const float* up = u2 + ((h1%5)*2 + (w1c&1))*256;
      #pragma unroll
      for (int co=0;co<16;co++) acc[co]=bu2[co];
      #pragma unroll 1
      for (int ci=0;ci<16;ci++){
        float dv = dp[ci];
        const float* ur = up + ci*16;
        #pragma unroll
        for (int co=0;co<16;co++) acc[co]=fmaf(dv,ur[co],acc[co]);
      }
    } else {
      #pragma unroll
      for (int co=0;co<16;co++) acc[co]=0.f;
    }
    #pragma unroll
    for (int co=0;co<16;co++) vs[lr][lc][co]=acc[co];
  }
  __syncthreads();
  if (tid < 160){
    int lh = tid/16, lw = tid%16;
    int h1 = h0+lh, w1c = w0+lw;
    float a[8];
    if (msl[lh+1][lw+1]){
      #pragma unroll
      for (int co=0;co<8;co++) a[co]=b5[co];
      #pragma unroll 1
      for (int kh=0;kh<3;kh++)
      #pragma unroll 1
      for (int kw=0;kw<3;kw++){
        const float* vp = vs[lh+kh][lw+kw];
        #pragma unroll
        for (int ci=0;ci<16;ci++){
          float v = vp[ci];
          const float* wr = w5s[(kh*3+kw)*16+ci];
          #pragma unroll
          for (int co=0;co<8;co++) a[co]=fmaf(v,wr[co],a[co]);
        }
      }
    } else {
      #pragma unroll
      for (int co=0;co<8;co++) a[co]=0.f;
    }
    float* op = t4 + (((size_t)b*NH1+h1)*NW1+w1c)*NC1;
    #pragma unroll
    for (int co=0;co<8;co++) op[co]=a[co];
  }
}

// ============ fused invconv3 (2,2,8,8) + conv6 (3x3,8->6), LDS-tiled ============
__global__ __launch_bounds__(256) void k_inv3conv6(
    const float* __restrict__ t4, const unsigned char* __restrict__ m0,
    const float* __restrict__ u3, const float* __restrict__ bu3,
    const float* __restrict__ w6, const float* __restrict__ b6,
    float* __restrict__ out){
  __shared__ float ts[8][10][36];
  __shared__ unsigned char msl[18][66];
  __shared__ float u3s[4][8][8];
  __shared__ float w6s[9][8][6];
  __shared__ float bu3s[8];
  __shared__ float b6s[6];
  int blk = blockIdx.x;
  int b  = blk / 26;
  int t  = blk % 26;
  int th = t >> 1, tw = t & 1;
  int h0 = th*16, w0 = tw*64;
  int base_r = 8*th - 1, base_c = 32*tw - 1;
  int tid = threadIdx.x;
  for (int i=tid;i<256;i+=256){ int pos=i>>6; int rem=i&63; u3s[pos][rem>>3][rem&7]=u3[i]; }
  for (int i=tid;i<432;i+=256){ int tap=i/48; int rem=i%48; w6s[tap][rem/6][rem%6]=w6[i]; }
  if (tid<8) bu3s[tid]=bu3[tid];
  if (tid<6) b6s[tid]=b6[tid];
  for (int p=tid;p<340;p+=256){
    int r=p/34, c=p-(p/34)*34;
    int h1=base_r+r, w1c=base_c+c;
    float4 v0=make_float4(0,0,0,0), v1=v0;
    if (h1>=0 && h1<NH1 && w1c>=0 && w1c<NW1){
      const float4* pp = (const float4*)(t4 + (((size_t)b*NH1+h1)*NW1+w1c)*8);
      v0=pp[0]; v1=pp[1];
    }
    ts[0][r][c]=v0.x; ts[1][r][c]=v0.y; ts[2][r][c]=v0.z; ts[3][r][c]=v0.w;
    ts[4][r][c]=v1.x; ts[5][r][c]=v1.y; ts[6][r][c]=v1.z; ts[7][r][c]=v1.w;
  }
  for (int p=tid;p<18*66;p+=256){
    int r=p/66, c=p-(p/66)*66;
    int h=h0-1+r, w=w0-1+c;
    msl[r][c] = (h>=0 && h<NH0 && w>=0 && w<NW0) ? m0[(b*NH0+h)*NW0+w] : 0;
  }
  __syncthreads();
  #pragma unroll 1
  for (int k=0;k<4;k++){
    int p = tid + k*256;
    int lh = p>>6, lw = p&63;
    int h = h0+lh, w = w0+lw;
    if (h >= NH0) continue;
    float acc[6];
    if (msl[lh+1][lw+1]){
      #pragma unroll
      for (int co=0;co<6;co++) acc[co]=b6s[co];
      #pragma unroll 1
      for (int kh=0;kh<3;kh++)
      #pragma unroll 1
      for (int kw=0;kw<3;kw++){
        if (!msl[lh+kh][lw+kw]) continue;
        int hh = h+kh-1, ww = w+kw-1;
        int tr = (hh>>1) - base_r, tc = (ww>>1) - base_c;
        int pos = (hh&1)*2 + (ww&1);
        float v8[8];
        #pragma unroll
        for (int c8=0;c8<8;c8++) v8[c8]=bu3s[c8];
        #pragma unroll
        for (int ci=0;ci<8;ci++){
          float v = ts[ci][tr][tc];
          #pragma unroll
          for (int c8=0;c8<8;c8++) v8[c8]=fmaf(v, u3s[pos][ci][c8], v8[c8]);
        }
        const float (*wt)[6] = w6s[kh*3+kw];
        #pragma unroll
        for (int ci=0;ci<8;ci++)
          #pragma unroll
          for (int co=0;co<6;co++) acc[co]=fmaf(v8[ci], wt[ci][co], acc[co]);
      }
    } else {
      #pragma unroll
      for (int co=0;co<6;co++) acc[co]=0.f;
    }
    size_t base = (size_t)b*6*NH0*NW0 + (size_t)h*NW0 + w;
    #pragma unroll
    for (int co=0;co<6;co++) out[base + (size_t)co*NH0*NW0] = acc[co];
  }
}

extern "C" void kernel_launch(void* const* d_in, const int* in_sizes, int n_in,
                              void* d_out, int out_size, void* d_ws, size_t ws_size,
                              hipStream_t stream){
  (void)in_sizes; (void)n_in; (void)out_size; (void)ws_size;
  const float* x    = (const float*)d_in[0];
  const float* eps  = (const float*)d_in[1];
  const float* w1   = (const float*)d_in[2];
  const float* b1   = (const float*)d_in[3];
  const float* w2   = (const float*)d_in[4];
  const float* b2   = (const float*)d_in[5];
  const float* w3   = (const float*)d_in[6];
  const float* b3   = (const float*)d_in[7];
  const float* wmu  = (const float*)d_in[8];
  const float* bmu  = (const float*)d_in[9];
  const float* wlv  = (const float*)d_in[10];
  const float* blv  = (const float*)d_in[11];
  const float* wlin = (const float*)d_in[12];
  const float* blin = (const float*)d_in[13];
  const float* u1   = (const float*)d_in[14];
  const float* bu1  = (const float*)d_in[15];
  const float* w4   = (const float*)d_in[16];
  const float* b4   = (const float*)d_in[17];
  const float* u2   = (const float*)d_in[18];
  const float* bu2  = (const float*)d_in[19];
  const float* w5   = (const float*)d_in[20];
  const float* b5   = (const float*)d_in[21];
  const float* u3   = (const float*)d_in[22];
  const float* bu3  = (const float*)d_in[23];
  const float* w6   = (const float*)d_in[24];
  const float* b6   = (const float*)d_in[25];
  const float* fW1  = (const float*)d_in[26];
  const float* fb1  = (const float*)d_in[27];
  const float* fW2  = (const float*)d_in[28];
  const float* fb2  = (const float*)d_in[29];
  const float* fW3  = (const float*)d_in[30];
  const float* fb3  = (const float*)d_in[31];

  char* ws = (char*)d_ws;
  unsigned char* m0 = (unsigned char*)(ws);
  unsigned char* m1 = (unsigned char*)(ws + 3276800);
  unsigned char* m2 = (unsigned char*)(ws + 4096000);
  unsigned char* m3 = (unsigned char*)(ws + 4177920);
  float* y1p = (float*)(ws + 4194304);    // [B][100][64][8]
  float* y2p = (float*)(ws + 30408704);   // [B][20][32][16]
  float* y3p = (float*)(ws + 35651584);   // [B][4][16][32]
  float* dec = (float*)(ws + 36700160);   // [B][4][16][32]
  float* t2  = y2p;  // reuse
  float* t4  = y1p;  // reuse

  float* out   = (float*)d_out;
  float* o_mu  = out + 19660800;
  float* o_lv  = out + 19693568;
  float* o_kld = out + 19726336;
  float* o_zf  = out + 19726464;

  k_conv1pool<<< 3584,256,0,stream>>>(x, w1, b1, y1p, m0, m1);
  k_conv2pool<<< 1024,256,0,stream>>>(y1p, m1, w2, b2, y2p, m2);
  k_conv3pool<<<  128,256,0,stream>>>(y2p, m2, w3, b3, y3p, m3, o_kld);
  k_latent   <<<  512, 64,0,stream>>>(y3p, m3, eps, wmu,bmu,wlv,blv,wlin,blin,
                                      fW1,fb1,fW2,fb2,fW3,fb3, o_mu,o_lv,o_kld,o_zf, dec);
  k_ic4      <<<  512,256,0,stream>>>(dec, m2, u1, bu1, w4, b4, t2);
  k_ic5      <<< 5120,256,0,stream>>>(t2, m1, u2, bu2, w5, b5, t4);
  k_inv3conv6<<< 3328,256,0,stream>>>(t4, m0, u3, bu3, w6, b6, out);
}

// Round 7
// 454.438 us; speedup vs baseline: 3.3758x; 1.0606x over previous
//
#include <hip/hip_runtime.h>
#include <math.h>

constexpr int NB=128;
constexpr int NH0=200, NW0=128, NC0=6;
constexpr int NH1=100, NW1=64,  NC1=8;
constexpr int NH2=20,  NW2=32,  NC2=16;
constexpr int NH3=4,   NW3=16,  NC3=32;
constexpr int LAT=4, NPp=11, HID=16, NT=10;
constexpr float BOUNDf=5.0f;
constexpr float LOG2PI=1.8378770664093453f;

__device__ __forceinline__ float fexpf(float v){ return __expf(v); }
__device__ __forceinline__ float flogf(float v){ return __logf(v); }
__device__ __forceinline__ float softplusf(float v){ return v>20.f ? v : __logf(1.f+__expf(v)); }
__device__ __forceinline__ float lrelu(float v){ return v>0.f ? v : 0.01f*v; }

// ============ conv1 (3x3,6->8) + lrelu + pool2x2, LDS-tiled, computes m0,m1 ============
__global__ __launch_bounds__(256) void k_conv1pool(
    const float* __restrict__ x, const float* __restrict__ w1, const float* __restrict__ b1,
    float* __restrict__ y1p, unsigned char* __restrict__ m0, unsigned char* __restrict__ m1){
  __shared__ float xs[6][34][34];
  __shared__ float ws1[54][8];
  __shared__ unsigned char ms[34][34];
  int blk = blockIdx.x;
  int b  = blk / 28;
  int t  = blk % 28;
  int th = t / 4, tw = t % 4;
  int hp0 = th*16, wp0 = tw*16;
  int h0 = hp0*2 - 1, w0 = wp0*2 - 1;
  int tid = threadIdx.x;
  for (int i=tid;i<432;i+=256) ws1[i>>3][i&7] = w1[i];
  for (int i=tid;i<6*34*34;i+=256){
    int ci=i/1156; int rem=i-ci*1156; int r=rem/34, c=rem-r*34;
    int h=h0+r, w=w0+c;
    float v=0.f;
    if (h>=0 && h<NH0 && w>=0 && w<NW0) v = x[((size_t)(b*NC0+ci)*NH0+h)*NW0+w];
    xs[ci][r][c]=v;
  }
  __syncthreads();
  for (int i=tid;i<1156;i+=256){
    int r=i/34, c=i-r*34;
    bool any=false;
    #pragma unroll
    for (int ci=0;ci<6;ci++) any |= (xs[ci][r][c]!=0.f);
    ms[r][c] = any?1:0;
  }
  __syncthreads();
  for (int i=tid;i<1024;i+=256){
    int r=(i>>5)+1, c=(i&31)+1;
    int h=h0+r, w=w0+c;
    if (h<NH0) m0[(b*NH0+h)*NW0+w] = ms[r][c];
  }
  int lhp = tid>>4, lwp = tid&15;
  int hp = hp0+lhp, wp = wp0+lwp;
  if (hp < NH1){
    float best[8];
    #pragma unroll
    for (int co=0;co<8;co++) best[co]=-1e30f;
    bool many=false;
    #pragma unroll 1
    for (int i=0;i<2;i++)
    #pragma unroll 1
    for (int j=0;j<2;j++){
      int r = lhp*2+i+1, c = lwp*2+j+1;
      if (!ms[r][c]) continue;
      many=true;
      float a[8];
      #pragma unroll
      for (int co=0;co<8;co++) a[co]=b1[co];
      #pragma unroll 1
      for (int kh=0;kh<3;kh++)
      #pragma unroll 1
      for (int kw=0;kw<3;kw++){
        #pragma unroll
        for (int ci=0;ci<6;ci++){
          float v = xs[ci][r-1+kh][c-1+kw];
          const float* wv = ws1[(kh*3+kw)*6+ci];
          #pragma unroll
          for (int co=0;co<8;co++) a[co]=fmaf(v,wv[co],a[co]);
        }
      }
      #pragma unroll
      for (int co=0;co<8;co++) best[co]=fmaxf(best[co], lrelu(a[co]));
    }
    float* yp = y1p + (((size_t)b*NH1+hp)*NW1+wp)*8;
    #pragma unroll
    for (int co=0;co<8;co++) yp[co] = many?best[co]:0.f;
    m1[(b*NH1+hp)*NW1+wp] = many?1:0;
  }
}

// ============ conv2 (3x3,8->16) + lrelu + pool 5x2, small-tile LDS, co-split ============
__global__ __launch_bounds__(256) void k_conv2pool(
    const float* __restrict__ yin, const unsigned char* __restrict__ m1,
    const float* __restrict__ w2, const float* __restrict__ b2,
    float* __restrict__ yout, unsigned char* __restrict__ m2){
  __shared__ float ys[8][27][35];
  __shared__ unsigned char msl[27][35];
  __shared__ float w2s[72][16];
  __shared__ float b2s[16];
  int blk = blockIdx.x;
  int b  = blk >> 3;
  int t  = blk & 7;
  int th = t >> 1, tw = t & 1;
  int r0 = th*25 - 1, c0 = tw*32 - 1;
  int tid = threadIdx.x;
  for (int i=tid;i<1152;i+=256) w2s[i>>4][i&15] = w2[i];
  if (tid<16) b2s[tid]=b2[tid];
  for (int p=tid;p<27*34;p+=256){
    int r=p/34, c=p-(p/34)*34;
    int h1=r0+r, w1c=c0+c;
    bool ok = (h1>=0 && h1<NH1 && w1c>=0 && w1c<NW1);
    msl[r][c] = ok ? m1[(b*NH1+h1)*NW1+w1c] : 0;
    float4 v0=make_float4(0,0,0,0), v1=v0;
    if (ok){
      const float4* pp = (const float4*)(yin + (((size_t)b*NH1+h1)*NW1+w1c)*8);
      v0=pp[0]; v1=pp[1];
    }
    ys[0][r][c]=v0.x; ys[1][r][c]=v0.y; ys[2][r][c]=v0.z; ys[3][r][c]=v0.w;
    ys[4][r][c]=v1.x; ys[5][r][c]=v1.y; ys[6][r][c]=v1.z; ys[7][r][c]=v1.w;
  }
  __syncthreads();
  if (tid < 160){
    int oid = tid >> 1, coq = tid & 1;
    int co0 = coq*8;
    int lh = oid >> 4, lw = oid & 15;
    int h2 = th*5+lh, w2c = tw*16+lw;
    float best[8];
    #pragma unroll
    for (int co=0;co<8;co++) best[co]=-1e30f;
    bool many=false;
    #pragma unroll 1
    for (int i=0;i<5;i++)
    #pragma unroll 1
    for (int j=0;j<2;j++){
      int r = lh*5+i+1, c = lw*2+j+1;
      if (!msl[r][c]) continue;
      many=true;
      float a[8];
      #pragma unroll
      for (int co=0;co<8;co++) a[co]=b2s[co0+co];
      #pragma unroll 1
      for (int kh=0;kh<3;kh++)
      #pragma unroll 1
      for (int kw=0;kw<3;kw++){
        #pragma unroll
        for (int ci=0;ci<8;ci++){
          float v = ys[ci][r-1+kh][c-1+kw];
          const float* wr = w2s[(kh*3+kw)*8+ci];
          #pragma unroll
          for (int co=0;co<8;co++) a[co]=fmaf(v,wr[co0+co],a[co]);
        }
      }
      #pragma unroll
      for (int co=0;co<8;co++) best[co]=fmaxf(best[co], lrelu(a[co]));
    }
    float4 o0,o1;
    if (many){
      o0=make_float4(best[0],best[1],best[2],best[3]);
      o1=make_float4(best[4],best[5],best[6],best[7]);
    } else { o0=make_float4(0,0,0,0); o1=o0; }
    float4* op = (float4*)(yout + (((size_t)b*NH2+h2)*NW2+w2c)*16 + co0);
    op[0]=o0; op[1]=o1;
    if (coq==0) m2[(b*NH2+h2)*NW2+w2c] = many?1:0;
  }
}

// ============ conv3 (3x3,16->32) + lrelu + pool 5x2, per-batch LDS-tiled ============
__global__ __launch_bounds__(256) void k_conv3pool(
    const float* __restrict__ yin, const unsigned char* __restrict__ m2,
    const float* __restrict__ w3, const float* __restrict__ b3,
    float* __restrict__ yout, unsigned char* __restrict__ m3,
    float* __restrict__ out_kld){
  __shared__ float ys[16][20][33];
  __shared__ unsigned char msl[20][32];
  __shared__ float w3s[144][32];
  __shared__ float b3s[32];
  int b = blockIdx.x;
  int tid = threadIdx.x;
  if (tid==0) out_kld[b]=0.f;
  for (int i=tid;i<4608;i+=256) w3s[i>>5][i&31] = w3[i];
  if (tid<32) b3s[tid]=b3[tid];
  for (int p=tid;p<640;p+=256){
    int r=p>>5, c=p&31;
    msl[r][c] = m2[(b*NH2+r)*NW2+c];
    const float4* pp = (const float4*)(yin + (((size_t)b*NH2+r)*NW2+c)*16);
    float4 q0=pp[0],q1=pp[1],q2=pp[2],q3=pp[3];
    ys[0][r][c]=q0.x; ys[1][r][c]=q0.y; ys[2][r][c]=q0.z; ys[3][r][c]=q0.w;
    ys[4][r][c]=q1.x; ys[5][r][c]=q1.y; ys[6][r][c]=q1.z; ys[7][r][c]=q1.w;
    ys[8][r][c]=q2.x; ys[9][r][c]=q2.y; ys[10][r][c]=q2.z; ys[11][r][c]=q2.w;
    ys[12][r][c]=q3.x; ys[13][r][c]=q3.y; ys[14][r][c]=q3.z; ys[15][r][c]=q3.w;
  }
  __syncthreads();
  int p = tid>>2, coq = tid&3;
  int co0 = coq*8;
  int hp = p>>4, wp = p&15;
  float best[8];
  #pragma unroll
  for (int co=0;co<8;co++) best[co]=-1e30f;
  bool many=false;
  #pragma unroll 1
  for (int i=0;i<5;i++)
  #pragma unroll 1
  for (int j=0;j<2;j++){
    int h2 = hp*5+i, w2c = wp*2+j;
    if (!msl[h2][w2c]) continue;
    many=true;
    float a[8];
    #pragma unroll
    for (int co=0;co<8;co++) a[co]=b3s[co0+co];
    #pragma unroll 1
    for (int kh=0;kh<3;kh++){
      int hh=h2+kh-1;
      if (hh<0||hh>=NH2) continue;
      #pragma unroll 1
      for (int kw=0;kw<3;kw++){
        int ww=w2c+kw-1;
        if (ww<0||ww>=NW2) continue;
        #pragma unroll
        for (int ci=0;ci<16;ci++){
          float v = ys[ci][hh][ww];
          const float* wr = w3s[(kh*3+kw)*16+ci];
          #pragma unroll
          for (int co=0;co<8;co++) a[co]=fmaf(v,wr[co0+co],a[co]);
        }
      }
    }
    #pragma unroll
    for (int co=0;co<8;co++) best[co]=fmaxf(best[co], lrelu(a[co]));
  }
  float4 o0,o1;
  if (many){
    o0=make_float4(best[0],best[1],best[2],best[3]);
    o1=make_float4(best[4],best[5],best[6],best[7]);
  } else { o0=make_float4(0,0,0,0); o1=o0; }
  float4* op = (float4*)(yout + ((size_t)(b*64+p))*32 + co0);
  op[0]=o0; op[1]=o1;
  if (coq==0) m3[b*64+p] = many?1:0;
}

// ============ latent head + NSF flow + kld + dec; 4 lanes per position ============
__global__ __launch_bounds__(64) void k_latent(
    const float* __restrict__ y3p, const unsigned char* __restrict__ m3,
    const float* __restrict__ eps,
    const float* __restrict__ wmu, const float* __restrict__ bmu,
    const float* __restrict__ wlv, const float* __restrict__ blv,
    const float* __restrict__ wlin, const float* __restrict__ blin,
    const float* __restrict__ fW1, const float* __restrict__ fb1,
    const float* __restrict__ fW2, const float* __restrict__ fb2,
    const float* __restrict__ fW3, const float* __restrict__ fb3,
    float* __restrict__ out_mu, float* __restrict__ out_lv,
    float* __restrict__ out_kld, float* __restrict__ out_zf,
    float* __restrict__ dec)
{
  __shared__ __align__(16) float sW1[NT*HID*LAT];
  __shared__ float sb1[NT*HID];
  __shared__ __align__(16) float sW2[NT*HID*HID];
  __shared__ float sb2[NT*HID];
  __shared__ __align__(16) float sW3[NT*LAT*NPp*HID];
  __shared__ float sb3[NT*LAT*NPp];
  __shared__ __align__(16) float swmu[LAT*NC3];
  __shared__ __align__(16) float swlv[LAT*NC3];
  __shared__ __align__(16) float slin[NC3*LAT];
  __shared__ float sbmu[LAT], sblv[LAT], sblin[NC3];
  int tid = threadIdx.x;
  for (int i=tid;i<NT*HID*LAT;i+=64){ int j=i&3; int r=(i>>2)%HID; sW1[i]=fW1[i]*(((r%3+1)>=(j+1))?1.f:0.f); }
  for (int i=tid;i<NT*HID;i+=64){ sb1[i]=fb1[i]; sb2[i]=fb2[i]; }
  for (int i=tid;i<NT*HID*HID;i+=64){ int j=i&15; int r=(i>>4)%HID; sW2[i]=fW2[i]*(((r%3+1)>=(j%3+1))?1.f:0.f); }
  for (int i=tid;i<NT*LAT*NPp*HID;i+=64){ int j=i&15; int r=(i>>4)%(LAT*NPp); sW3[i]=fW3[i]*(((r/NPp+1)>(j%3+1))?1.f:0.f); }
  for (int i=tid;i<NT*LAT*NPp;i+=64) sb3[i]=fb3[i];
  for (int i=tid;i<LAT*NC3;i+=64){ swmu[i]=wmu[i]; swlv[i]=wlv[i]; slin[i]=wlin[i]; }
  if (tid<LAT){ sbmu[tid]=bmu[tid]; sblv[tid]=blv[tid]; }
  for (int i=tid;i<NC3;i+=64) sblin[i]=blin[i];
  __syncthreads();

  int blk = blockIdx.x;
  int b   = blk >> 2;
  int gpos = b*64 + (blk&3)*16 + (tid>>2);
  int g = tid & 3;
  bool msk = m3[gpos]!=0;
  float kld_part = 0.f;
  if (msk){
    const float4* yp = (const float4*)(y3p + (size_t)gpos*NC3);
    const float4* wm = (const float4*)(swmu + g*NC3);
    const float4* wl = (const float4*)(swlv + g*NC3);
    float mu_g = sbmu[g], lv_g = sblv[g];
    #pragma unroll
    for (int q=0;q<8;q++){
      float4 yq = yp[q], a = wm[q], c = wl[q];
      mu_g = fmaf(yq.x,a.x, fmaf(yq.y,a.y, fmaf(yq.z,a.z, fmaf(yq.w,a.w, mu_g))));
      lv_g = fmaf(yq.x,c.x, fmaf(yq.y,c.y, fmaf(yq.z,c.z, fmaf(yq.w,c.w, lv_g))));
    }
    float std_g = fexpf(0.5f*lv_g);
    float ev_g  = eps[(size_t)gpos*LAT+g];
    float z0_g  = fmaf(ev_g, std_g, mu_g);
    float zg = z0_g;
    float z[4];
    z[g]=zg; z[g^1]=__shfl_xor(zg,1); z[g^2]=__shfl_xor(zg,2); z[g^3]=__shfl_xor(zg,3);
    float ld_g = 0.f;
    for (int t=0;t<NT;t++){
      float h1[16];
      const float4* W1t = (const float4*)(sW1 + t*HID*LAT);
      const float*  b1t = sb1 + t*HID;
      #pragma unroll
      for (int i2=0;i2<16;i2++){
        float4 w = W1t[i2];
        float a = b1t[i2];
        a = fmaf(z[0],w.x, fmaf(z[1],w.y, fmaf(z[2],w.z, fmaf(z[3],w.w, a))));
        h1[i2]=fmaxf(a,0.f);
      }
      float h2o[4];
      const float* W2t = sW2 + t*HID*HID;
      const float* b2t = sb2 + t*HID;
      #pragma unroll
      for (int k=0;k<4;k++){
        int row = g*4+k;
        const float4* wr = (const float4*)(W2t + row*HID);
        float a = b2t[row];
        #pragma unroll
        for (int q=0;q<4;q++){
          float4 w = wr[q];
          a = fmaf(h1[q*4+0],w.x, fmaf(h1[q*4+1],w.y, fmaf(h1[q*4+2],w.z, fmaf(h1[q*4+3],w.w, a))));
        }
        h2o[k]=fmaxf(a,0.f);
      }
      float h2[16];
      #pragma unroll
      for (int k=0;k<4;k++) h2[g*4+k]=h2o[k];
      #pragma unroll
      for (int mski=1;mski<4;mski++){
        int og = g^mski;
        #pragma unroll
        for (int k=0;k<4;k++) h2[og*4+k]=__shfl_xor(h2o[k],mski);
      }
      float p[NPp];
      const float* W3t = sW3 + t*LAT*NPp*HID;
      const float* b3t = sb3 + t*LAT*NPp;
      #pragma unroll
      for (int r=0;r<NPp;r++){
        int row = g*NPp+r;
        const float4* wr = (const float4*)(W3t + row*HID);
        float a = b3t[row];
        #pragma unroll
        for (int q=0;q<4;q++){
          float4 w = wr[q];
          a = fmaf(h2[q*4+0],w.x, fmaf(h2[q*4+1],w.y, fmaf(h2[q*4+2],w.z, fmaf(h2[q*4+3],w.w, a))));
        }
        p[r]=a;
      }
      float mw=fmaxf(fmaxf(p[0],p[1]),fmaxf(p[2],p[3]));
      float e0=fexpf(p[0]-mw), e1=fexpf(p[1]-mw), e2=fexpf(p[2]-mw), e3=fexpf(p[3]-mw);
      float wsc=10.f/(e0+e1+e2+e3);
      float xk1=fmaf(e0,wsc,-BOUNDf), xk2=fmaf(e1,wsc,xk1), xk3=fmaf(e2,wsc,xk2), xk4=fmaf(e3,wsc,xk3);
      float mh=fmaxf(fmaxf(p[4],p[5]),fmaxf(p[6],p[7]));
      float f0=fexpf(p[4]-mh), f1=fexpf(p[5]-mh), f2=fexpf(p[6]-mh), f3=fexpf(p[7]-mh);
      float hsc=10.f/(f0+f1+f2+f3);
      float yk1=fmaf(f0,hsc,-BOUNDf), yk2=fmaf(f1,hsc,yk1), yk3=fmaf(f2,hsc,yk2), yk4=fmaf(f3,hsc,yk3);
      float dk1=softplusf(p[8]), dk2=softplusf(p[9]), dk3=softplusf(p[10]);
      float xv=z[g];
      bool inside = (xv>=-BOUNDf)&&(xv<=BOUNDf);
      float xc=fminf(fmaxf(xv,-BOUNDf),BOUNDf);
      float x0=-BOUNDf, x1=xk1, y0=-BOUNDf, y1=yk1, d0=1.f, d1=dk1;
      if (xc>=xk1){x0=xk1;x1=xk2;y0=yk1;y1=yk2;d0=dk1;d1=dk2;}
      if (xc>=xk2){x0=xk2;x1=xk3;y0=yk2;y1=yk3;d0=dk2;d1=dk3;}
      if (xc>=xk3){x0=xk3;x1=xk4;y0=yk3;y1=yk4;d0=dk3;d1=1.f;}
      float dxv=x1-x0, dyv=y1-y0;
      float sl=dyv/dxv, ttv=(xc-x0)/dxv, omt=1.f-ttv;
      float den=sl + (d1+d0-2.f*sl)*ttv*omt;
      float yo=y0 + dyv*(sl*ttv*ttv + d0*ttv*omt)/den;
      float ldv=flogf(sl*sl*(d1*ttv*ttv + 2.f*sl*ttv*omt + d0*omt*omt)) - 2.f*flogf(den);
      float zn_g = inside ? yo : xv;
      ld_g += inside ? ldv : 0.f;
      float znf[4];
      znf[g]=zn_g; znf[g^1]=__shfl_xor(zn_g,1); znf[g^2]=__shfl_xor(zn_g,2); znf[g^3]=__shfl_xor(zn_g,3);
      if (t<NT-1){ z[0]=znf[3]; z[1]=znf[2]; z[2]=znf[1]; z[3]=znf[0]; }
      else       { z[0]=znf[0]; z[1]=znf[1]; z[2]=znf[2]; z[3]=znf[3]; }
    }
    float lq_g = -0.5f*ev_g*ev_g - 0.5f*lv_g - 0.5f*LOG2PI;
    float lp_g = -0.5f*z[g]*z[g] - 0.5f*LOG2PI;
    kld_part = lq_g - ld_g - lp_g;
    out_mu[(size_t)gpos*LAT+g]=mu_g;
    out_lv[(size_t)gpos*LAT+g]=lv_g;
    out_zf[(size_t)gpos*LAT+g]=z[g];
    float4 d0v, d1v;
    {
      float dv[8];
      #pragma unroll
      for (int k=0;k<8;k++){
        int c = g*8+k;
        const float4 w = ((const float4*)slin)[c];
        dv[k] = fmaf(z[0],w.x, fmaf(z[1],w.y, fmaf(z[2],w.z, fmaf(z[3],w.w, sblin[c]))));
      }
      d0v=make_float4(dv[0],dv[1],dv[2],dv[3]);
      d1v=make_float4(dv[4],dv[5],dv[6],dv[7]);
    }
    float4* dp = (float4*)(dec + (size_t)gpos*NC3 + g*8);
    dp[0]=d0v; dp[1]=d1v;
  } else {
    out_mu[(size_t)gpos*LAT+g]=0.f;
    out_lv[(size_t)gpos*LAT+g]=0.f;
    out_zf[(size_t)gpos*LAT+g]=0.f;
    float4 zv = make_float4(0,0,0,0);
    float4* dp = (float4*)(dec + (size_t)gpos*NC3 + g*8);
    dp[0]=zv; dp[1]=zv;
  }
  float s = kld_part;
  s += __shfl_xor(s,1);  s += __shfl_xor(s,2);
  s += __shfl_xor(s,4);  s += __shfl_xor(s,8);
  s += __shfl_xor(s,16); s += __shfl_xor(s,32);
  if (tid==0) atomicAdd(&out_kld[b], s);
}

// ============ fused invconv1(5,2,32,32) + conv4(3x3,32->16) -> t2, mask m2 ============
__global__ __launch_bounds__(256) void k_ic4(
    const float* __restrict__ dec, const unsigned char* __restrict__ m2,
    const float* __restrict__ u1, const float* __restrict__ bu1,
    const float* __restrict__ w4, const float* __restrict__ b4,
    float* __restrict__ t2){
  __shared__ __align__(16) float vs[12][18][32];
  __shared__ __align__(16) float w4s[288][16];
  __shared__ unsigned char msl[12][18];
  int blk = blockIdx.x;
  int b  = blk >> 2;
  int t  = blk & 3;
  int th = t >> 1, tw = t & 1;
  int h0 = th*10, w0 = tw*16;
  int tid = threadIdx.x;
  for (int i=tid;i<288*16;i+=256) w4s[i>>4][i&15] = w4[i];
  if (tid < 216){
    int lr = tid/18, lc = tid%18;
    int h2 = h0-1+lr, w2 = w0-1+lc;
    bool mk = (h2>=0 && h2<NH2 && w2>=0 && w2<NW2) && m2[(b*NH2+h2)*NW2+w2];
    msl[lr][lc] = mk?1:0;
    float acc[32];
    if (mk){
      const float* dp = dec + (((size_t)b*NH3 + h2/5)*NW3 + w2/2)*NC3;
      const float* up = u1 + ((h2%5)*2 + (w2&1))*1024;
      #pragma unroll
      for (int co=0;co<32;co++) acc[co]=bu1[co];
      #pragma unroll 1
      for (int ci=0;ci<32;ci++){
        float dv = dp[ci];
        const float* ur = up + ci*32;
        #pragma unroll
        for (int co=0;co<32;co++) acc[co]=fmaf(dv,ur[co],acc[co]);
      }
    } else {
      #pragma unroll
      for (int co=0;co<32;co++) acc[co]=0.f;
    }
    #pragma unroll
    for (int co=0;co<32;co++) vs[lr][lc][co]=acc[co];
  }
  __syncthreads();
  if (tid < 160){
    int lh = tid/16, lw = tid%16;
    int h2 = h0+lh, w2 = w0+lw;
    float a[16];
    if (msl[lh+1][lw+1]){
      #pragma unroll
      for (int co=0;co<16;co++) a[co]=b4[co];
      #pragma unroll 1
      for (int kh=0;kh<3;kh++)
      #pragma unroll 1
      for (int kw=0;kw<3;kw++){
        const float* vp = vs[lh+kh][lw+kw];
        #pragma unroll
        for (int ci=0;ci<32;ci++){
          float v = vp[ci];
          const float* wr = w4s[(kh*3+kw)*32+ci];
          #pragma unroll
          for (int co=0;co<16;co++) a[co]=fmaf(v,wr[co],a[co]);
        }
      }
    } else {
      #pragma unroll
      for (int co=0;co<16;co++) a[co]=0.f;
    }
    float* op = t2 + (((size_t)b*NH2+h2)*NW2+w2)*NC2;
    #pragma unroll
    for (int co=0;co<16;co++) op[co]=a[co];
  }
}

// ============ fused invconv2(5,2,16,16) + conv5(3x3,16->8) -> t4, mask m1 ============
__global__ __launch_bounds__(256) void k_ic5(
    const float* __restrict__ t2, const unsigned char* __restrict__ m1,
    const float* __restrict__ u2, const float* __restrict__ bu2,
    const float* __restrict__ w5, const float* __restrict__ b5,
    float* __restrict__ t4){
  __shared__ __align__(16) float vs[12][18][16];
  __shared__ __align__(16) float w5s[144][8];
  __shared__ unsigned char msl[12][18];
  int blk = blockIdx.x;
  int b  = blk / 40;
  int t  = blk % 40;
  int th = t >> 2, tw = t & 3;
  int h0 = th*10, w0 = tw*16;
  int tid = threadIdx.x;
  for (int i=tid;i<144*8;i+=256) w5s[i>>3][i&7] = w5[i];
  if (tid < 216){
    int lr = tid/18, lc = tid%18;
    int h1 = h0-1+lr, w1c = w0-1+lc;
    bool mk = (h1>=0 && h1<NH1 && w1c>=0 && w1c<NW1) && m1[(b*NH1+h1)*NW1+w1c];
    msl[lr][lc] = mk?1:0;
    float acc[16];
    if (mk){
      const float* dp = t2 + (((size_t)b*NH2 + h1/5)*NW2 + w1c/2)*NC2;
      const float* up = u2 + ((h1%5)*2 + (w1c&1))*256;
      #pragma unroll
      for (int co=0;co<16;co++) acc[co]=bu2[co];
      #pragma unroll 1
      for (int ci=0;ci<16;ci++){
        float dv = dp[ci];
        const float* ur = up + ci*16;
        #pragma unroll
        for (int co=0;co<16;co++) acc[co]=fmaf(dv,ur[co],acc[co]);
      }
    } else {
      #pragma unroll
      for (int co=0;co<16;co++) acc[co]=0.f;
    }
    #pragma unroll
    for (int co=0;co<16;co++) vs[lr][lc][co]=acc[co];
  }
  __syncthreads();
  if (tid < 160){
    int lh = tid/16, lw = tid%16;
    int h1 = h0+lh, w1c = w0+lw;
    float a[8];
    if (msl[lh+1][lw+1]){
      #pragma unroll
      for (int co=0;co<8;co++) a[co]=b5[co];
      #pragma unroll 1
      for (int kh=0;kh<3;kh++)
      #pragma unroll 1
      for (int kw=0;kw<3;kw++){
        const float* vp = vs[lh+kh][lw+kw];
        #pragma unroll
        for (int ci=0;ci<16;ci++){
          float v = vp[ci];
          const float* wr = w5s[(kh*3+kw)*16+ci];
          #pragma unroll
          for (int co=0;co<8;co++) a[co]=fmaf(v,wr[co],a[co]);
        }
      }
    } else {
      #pragma unroll
      for (int co=0;co<8;co++) a[co]=0.f;
    }
    float* op = t4 + (((size_t)b*NH1+h1)*NW1+w1c)*NC1;
    #pragma unroll
    for (int co=0;co<8;co++) op[co]=a[co];
  }
}

// ============ fused invconv3 (2,2,8,8) + conv6 (3x3,8->6), two-phase LDS ============
// Phase A: masked invconv3 -> vs[8][18][68] (SoA) for halo 18x66
// Phase B: dense 3x3 conv6 from vs (zeros where masked), no per-tap branching
__global__ __launch_bounds__(256) void k_inv3conv6(
    const float* __restrict__ t4, const unsigned char* __restrict__ m0,
    const float* __restrict__ u3, const float* __restrict__ bu3,
    const float* __restrict__ w6, const float* __restrict__ b6,
    float* __restrict__ out){
  __shared__ float vs[8][18][68];
  __shared__ unsigned char msl[18][66];
  __shared__ float u3s[4][8][8];
  __shared__ float w6s[9][8][6];
  __shared__ float bu3s[8];
  __shared__ float b6s[6];
  int blk = blockIdx.x;
  int b  = blk / 26;
  int t  = blk % 26;
  int th = t >> 1, tw = t & 1;
  int h0 = th*16, w0 = tw*64;
  int tid = threadIdx.x;
  for (int i=tid;i<256;i+=256){ u3s[i>>6][(i>>3)&7][i&7]=u3[i]; }
  for (int i=tid;i<432;i+=256){ int tap=i/48; int rem=i%48; w6s[tap][rem/6][rem%6]=w6[i]; }
  if (tid<8) bu3s[tid]=bu3[tid];
  if (tid<6) b6s[tid]=b6[tid];
  __syncthreads();
  // Phase A: halo rows h0-1..h0+16, cols w0-1..w0+64
  for (int p=tid;p<18*66;p+=256){
    int r=p/66, c=p-(p/66)*66;
    int h=h0-1+r, w=w0-1+c;
    bool act = (h>=0 && h<NH0 && w>=0 && w<NW0) && m0[(b*NH0+h)*NW0+w];
    msl[r][c] = act?1:0;
    float v8[8];
    if (act){
      const float4* tp = (const float4*)(t4 + (((size_t)b*NH1 + (h>>1))*NW1 + (w>>1))*8);
      float4 q0=tp[0], q1=tp[1];
      float tin[8]={q0.x,q0.y,q0.z,q0.w,q1.x,q1.y,q1.z,q1.w};
      const float (*up)[8] = u3s[(h&1)*2+(w&1)];
      #pragma unroll
      for (int c8=0;c8<8;c8++) v8[c8]=bu3s[c8];
      #pragma unroll
      for (int ci=0;ci<8;ci++){
        float v=tin[ci];
        #pragma unroll
        for (int c8=0;c8<8;c8++) v8[c8]=fmaf(v, up[ci][c8], v8[c8]);
      }
    } else {
      #pragma unroll
      for (int c8=0;c8<8;c8++) v8[c8]=0.f;
    }
    #pragma unroll
    for (int c8=0;c8<8;c8++) vs[c8][r][c]=v8[c8];
  }
  __syncthreads();
  // Phase B: dense conv6 over vs (zeros contribute nothing)
  #pragma unroll 1
  for (int k=0;k<4;k++){
    int p = tid + k*256;
    int lh = p>>6, lw = p&63;
    int h = h0+lh, w = w0+lw;
    if (h >= NH0) continue;
    float acc[6];
    if (msl[lh+1][lw+1]){
      #pragma unroll
      for (int co=0;co<6;co++) acc[co]=b6s[co];
      #pragma unroll 1
      for (int kh=0;kh<3;kh++)
      #pragma unroll 1
      for (int kw=0;kw<3;kw++){
        const float (*wt)[6] = w6s[kh*3+kw];
        #pragma unroll
        for (int ci=0;ci<8;ci++){
          float v = vs[ci][lh+kh][lw+kw];
          #pragma unroll
          for (int co=0;co<6;co++) acc[co]=fmaf(v, wt[ci][co], acc[co]);
        }
      }
    } else {
      #pragma unroll
      for (int co=0;co<6;co++) acc[co]=0.f;
    }
    size_t base = (size_t)b*6*NH0*NW0 + (size_t)h*NW0 + w;
    #pragma unroll
    for (int co=0;co<6;co++) out[base + (size_t)co*NH0*NW0] = acc[co];
  }
}

extern "C" void kernel_launch(void* const* d_in, const int* in_sizes, int n_in,
                              void* d_out, int out_size, void* d_ws, size_t ws_size,
                              hipStream_t stream){
  (void)in_sizes; (void)n_in; (void)out_size; (void)ws_size;
  const float* x    = (const float*)d_in[0];
  const float* eps  = (const float*)d_in[1];
  const float* w1   = (const float*)d_in[2];
  const float* b1   = (const float*)d_in[3];
  const float* w2   = (const float*)d_in[4];
  const float* b2   = (const float*)d_in[5];
  const float* w3   = (const float*)d_in[6];
  const float* b3   = (const float*)d_in[7];
  const float* wmu  = (const float*)d_in[8];
  const float* bmu  = (const float*)d_in[9];
  const float* wlv  = (const float*)d_in[10];
  const float* blv  = (const float*)d_in[11];
  const float* wlin = (const float*)d_in[12];
  const float* blin = (const float*)d_in[13];
  const float* u1   = (const float*)d_in[14];
  const float* bu1  = (const float*)d_in[15];
  const float* w4   = (const float*)d_in[16];
  const float* b4   = (const float*)d_in[17];
  const float* u2   = (const float*)d_in[18];
  const float* bu2  = (const float*)d_in[19];
  const float* w5   = (const float*)d_in[20];
  const float* b5   = (const float*)d_in[21];
  const float* u3   = (const float*)d_in[22];
  const float* bu3  = (const float*)d_in[23];
  const float* w6   = (const float*)d_in[24];
  const float* b6   = (const float*)d_in[25];
  const float* fW1  = (const float*)d_in[26];
  const float* fb1  = (const float*)d_in[27];
  const float* fW2  = (const float*)d_in[28];
  const float* fb2  = (const float*)d_in[29];
  const float* fW3  = (const float*)d_in[30];
  const float* fb3  = (const float*)d_in[31];

  char* ws = (char*)d_ws;
  unsigned char* m0 = (unsigned char*)(ws);
  unsigned char* m1 = (unsigned char*)(ws + 3276800);
  unsigned char* m2 = (unsigned char*)(ws + 4096000);
  unsigned char* m3 = (unsigned char*)(ws + 4177920);
  float* y1p = (float*)(ws + 4194304);    // [B][100][64][8]
  float* y2p = (float*)(ws + 30408704);   // [B][20][32][16]
  float* y3p = (float*)(ws + 35651584);   // [B][4][16][32]
  float* dec = (float*)(ws + 36700160);   // [B][4][16][32]
  float* t2  = y2p;  // reuse
  float* t4  = y1p;  // reuse

  float* out   = (float*)d_out;
  float* o_mu  = out + 19660800;
  float* o_lv  = out + 19693568;
  float* o_kld = out + 19726336;
  float* o_zf  = out + 19726464;

  k_conv1pool<<< 3584,256,0,stream>>>(x, w1, b1, y1p, m0, m1);
  k_conv2pool<<< 1024,256,0,stream>>>(y1p, m1, w2, b2, y2p, m2);
  k_conv3pool<<<  128,256,0,stream>>>(y2p, m2, w3, b3, y3p, m3, o_kld);
  k_latent   <<<  512, 64,0,stream>>>(y3p, m3, eps, wmu,bmu,wlv,blv,wlin,blin,
                                      fW1,fb1,fW2,fb2,fW3,fb3, o_mu,o_lv,o_kld,o_zf, dec);
  k_ic4      <<<  512,256,0,stream>>>(dec, m2, u1, bu1, w4, b4, t2);
  k_ic5      <<< 5120,256,0,stream>>>(t2, m1, u2, bu2, w5, b5, t4);
  k_inv3conv6<<< 3328,256,0,stream>>>(t4, m0, u3, bu3, w6, b6, out);
}

// Round 8
// 449.542 us; speedup vs baseline: 3.4126x; 1.0109x over previous
//
#include <hip/hip_runtime.h>
#include <math.h>

constexpr int NB=128;
constexpr int NH0=200, NW0=128, NC0=6;
constexpr int NH1=100, NW1=64,  NC1=8;
constexpr int NH2=20,  NW2=32,  NC2=16;
constexpr int NH3=4,   NW3=16,  NC3=32;
constexpr int LAT=4, NPp=11, HID=16, NT=10;
constexpr float BOUNDf=5.0f;
constexpr float LOG2PI=1.8378770664093453f;

__device__ __forceinline__ float fexpf(float v){ return __expf(v); }
__device__ __forceinline__ float flogf(float v){ return __logf(v); }
__device__ __forceinline__ float softplusf(float v){ return v>20.f ? v : __logf(1.f+__expf(v)); }
__device__ __forceinline__ float lrelu(float v){ return v>0.f ? v : 0.01f*v; }

// ============ conv1 (3x3,6->8) + lrelu + pool2x2 ============
// one pre-pool pixel per thread; 16x16 pre-pool tile; in-wave 2x2 pool via shfl
__global__ __launch_bounds__(256) void k_conv1pool(
    const float* __restrict__ x, const float* __restrict__ w1, const float* __restrict__ b1,
    float* __restrict__ y1p, unsigned char* __restrict__ m0, unsigned char* __restrict__ m1){
  __shared__ float xs[6][18][24];
  __shared__ float ws1[54][8];
  __shared__ float b1s[8];
  int blk = blockIdx.x;
  int b  = blk / 104;           // 13*8 tiles per batch
  int t  = blk % 104;
  int th = t >> 3, tw = t & 7;  // th 0..12, tw 0..7
  int h0 = th*16, w0 = tw*16;
  int tid = threadIdx.x;
  for (int i=tid;i<432;i+=256) ws1[i>>3][i&7] = w1[i];
  if (tid<8) b1s[tid]=b1[tid];
  for (int i=tid;i<6*18*18;i+=256){
    int ci=i/324; int rem=i-ci*324; int r=rem/18, c=rem-r*18;
    int h=h0-1+r, w=w0-1+c;
    float v=0.f;
    if (h>=0 && h<NH0 && w>=0 && w<NW0) v = x[((size_t)(b*NC0+ci)*NH0+h)*NW0+w];
    xs[ci][r][c]=v;
  }
  __syncthreads();
  int r = tid>>4, c = tid&15;
  int h = h0+r, w = w0+c;
  bool inb = (h < NH0);
  float c0v=xs[0][r+1][c+1], c1v=xs[1][r+1][c+1], c2v=xs[2][r+1][c+1];
  float c3v=xs[3][r+1][c+1], c4v=xs[4][r+1][c+1], c5v=xs[5][r+1][c+1];
  bool act = inb && ((c0v!=0.f)||(c1v!=0.f)||(c2v!=0.f)||(c3v!=0.f)||(c4v!=0.f)||(c5v!=0.f));
  if (inb) m0[(b*NH0+h)*NW0+w] = act?1:0;
  float a[8];
  #pragma unroll
  for (int co=0;co<8;co++) a[co]=b1s[co];
  #pragma unroll 1
  for (int kh=0;kh<3;kh++)
  #pragma unroll 1
  for (int kw=0;kw<3;kw++){
    #pragma unroll
    for (int ci=0;ci<6;ci++){
      float v = xs[ci][r+kh][c+kw];
      const float* wv = ws1[(kh*3+kw)*6+ci];
      #pragma unroll
      for (int co=0;co<8;co++) a[co]=fmaf(v,wv[co],a[co]);
    }
  }
  #pragma unroll
  for (int co=0;co<8;co++) a[co] = act ? lrelu(a[co]) : -1e30f;
  // in-wave 2x2 pool: col neighbor = lane^1, row neighbor = lane^16
  float best[8];
  #pragma unroll
  for (int co=0;co<8;co++){
    float v = a[co];
    v = fmaxf(v, __shfl_xor(v,1));
    v = fmaxf(v, __shfl_xor(v,16));
    best[co]=v;
  }
  float af = act?1.f:0.f;
  af = fmaxf(af, __shfl_xor(af,1));
  af = fmaxf(af, __shfl_xor(af,16));
  bool anyact = af>0.f;
  bool rep = ((r&1)==0) && ((c&1)==0);
  if (rep && inb){
    int hp=h>>1, wp=w>>1;
    float4 o0,o1;
    if (anyact){
      o0=make_float4(best[0],best[1],best[2],best[3]);
      o1=make_float4(best[4],best[5],best[6],best[7]);
    } else { o0=make_float4(0,0,0,0); o1=o0; }
    float4* yp = (float4*)(y1p + (((size_t)b*NH1+hp)*NW1+wp)*8);
    yp[0]=o0; yp[1]=o1;
    m1[(b*NH1+hp)*NW1+wp] = anyact?1:0;
  }
}

// ============ conv2 (3x3,8->16) + lrelu + pool 5x2, small-tile LDS, co-split ============
__global__ __launch_bounds__(256) void k_conv2pool(
    const float* __restrict__ yin, const unsigned char* __restrict__ m1,
    const float* __restrict__ w2, const float* __restrict__ b2,
    float* __restrict__ yout, unsigned char* __restrict__ m2){
  __shared__ float ys[8][27][35];
  __shared__ unsigned char msl[27][35];
  __shared__ float w2s[72][16];
  __shared__ float b2s[16];
  int blk = blockIdx.x;
  int b  = blk >> 3;
  int t  = blk & 7;
  int th = t >> 1, tw = t & 1;
  int r0 = th*25 - 1, c0 = tw*32 - 1;
  int tid = threadIdx.x;
  for (int i=tid;i<1152;i+=256) w2s[i>>4][i&15] = w2[i];
  if (tid<16) b2s[tid]=b2[tid];
  for (int p=tid;p<27*34;p+=256){
    int r=p/34, c=p-(p/34)*34;
    int h1=r0+r, w1c=c0+c;
    bool ok = (h1>=0 && h1<NH1 && w1c>=0 && w1c<NW1);
    msl[r][c] = ok ? m1[(b*NH1+h1)*NW1+w1c] : 0;
    float4 v0=make_float4(0,0,0,0), v1=v0;
    if (ok){
      const float4* pp = (const float4*)(yin + (((size_t)b*NH1+h1)*NW1+w1c)*8);
      v0=pp[0]; v1=pp[1];
    }
    ys[0][r][c]=v0.x; ys[1][r][c]=v0.y; ys[2][r][c]=v0.z; ys[3][r][c]=v0.w;
    ys[4][r][c]=v1.x; ys[5][r][c]=v1.y; ys[6][r][c]=v1.z; ys[7][r][c]=v1.w;
  }
  __syncthreads();
  if (tid < 160){
    int oid = tid >> 1, coq = tid & 1;
    int co0 = coq*8;
    int lh = oid >> 4, lw = oid & 15;
    int h2 = th*5+lh, w2c = tw*16+lw;
    float best[8];
    #pragma unroll
    for (int co=0;co<8;co++) best[co]=-1e30f;
    bool many=false;
    #pragma unroll 1
    for (int i=0;i<5;i++)
    #pragma unroll 1
    for (int j=0;j<2;j++){
      int r = lh*5+i+1, c = lw*2+j+1;
      if (!msl[r][c]) continue;
      many=true;
      float a[8];
      #pragma unroll
      for (int co=0;co<8;co++) a[co]=b2s[co0+co];
      #pragma unroll 1
      for (int kh=0;kh<3;kh++)
      #pragma unroll 1
      for (int kw=0;kw<3;kw++){
        #pragma unroll
        for (int ci=0;ci<8;ci++){
          float v = ys[ci][r-1+kh][c-1+kw];
          const float* wr = w2s[(kh*3+kw)*8+ci];
          #pragma unroll
          for (int co=0;co<8;co++) a[co]=fmaf(v,wr[co0+co],a[co]);
        }
      }
      #pragma unroll
      for (int co=0;co<8;co++) best[co]=fmaxf(best[co], lrelu(a[co]));
    }
    float4 o0,o1;
    if (many){
      o0=make_float4(best[0],best[1],best[2],best[3]);
      o1=make_float4(best[4],best[5],best[6],best[7]);
    } else { o0=make_float4(0,0,0,0); o1=o0; }
    float4* op = (float4*)(yout + (((size_t)b*NH2+h2)*NW2+w2c)*16 + co0);
    op[0]=o0; op[1]=o1;
    if (coq==0) m2[(b*NH2+h2)*NW2+w2c] = many?1:0;
  }
}

// ============ conv3 (3x3,16->32) + lrelu + pool 5x2, per-batch LDS-tiled ============
__global__ __launch_bounds__(256) void k_conv3pool(
    const float* __restrict__ yin, const unsigned char* __restrict__ m2,
    const float* __restrict__ w3, const float* __restrict__ b3,
    float* __restrict__ yout, unsigned char* __restrict__ m3,
    float* __restrict__ out_kld){
  __shared__ float ys[16][20][33];
  __shared__ unsigned char msl[20][32];
  __shared__ float w3s[144][32];
  __shared__ float b3s[32];
  int b = blockIdx.x;
  int tid = threadIdx.x;
  if (tid==0) out_kld[b]=0.f;
  for (int i=tid;i<4608;i+=256) w3s[i>>5][i&31] = w3[i];
  if (tid<32) b3s[tid]=b3[tid];
  for (int p=tid;p<640;p+=256){
    int r=p>>5, c=p&31;
    msl[r][c] = m2[(b*NH2+r)*NW2+c];
    const float4* pp = (const float4*)(yin + (((size_t)b*NH2+r)*NW2+c)*16);
    float4 q0=pp[0],q1=pp[1],q2=pp[2],q3=pp[3];
    ys[0][r][c]=q0.x; ys[1][r][c]=q0.y; ys[2][r][c]=q0.z; ys[3][r][c]=q0.w;
    ys[4][r][c]=q1.x; ys[5][r][c]=q1.y; ys[6][r][c]=q1.z; ys[7][r][c]=q1.w;
    ys[8][r][c]=q2.x; ys[9][r][c]=q2.y; ys[10][r][c]=q2.z; ys[11][r][c]=q2.w;
    ys[12][r][c]=q3.x; ys[13][r][c]=q3.y; ys[14][r][c]=q3.z; ys[15][r][c]=q3.w;
  }
  __syncthreads();
  int p = tid>>2, coq = tid&3;
  int co0 = coq*8;
  int hp = p>>4, wp = p&15;
  float best[8];
  #pragma unroll
  for (int co=0;co<8;co++) best[co]=-1e30f;
  bool many=false;
  #pragma unroll 1
  for (int i=0;i<5;i++)
  #pragma unroll 1
  for (int j=0;j<2;j++){
    int h2 = hp*5+i, w2c = wp*2+j;
    if (!msl[h2][w2c]) continue;
    many=true;
    float a[8];
    #pragma unroll
    for (int co=0;co<8;co++) a[co]=b3s[co0+co];
    #pragma unroll 1
    for (int kh=0;kh<3;kh++){
      int hh=h2+kh-1;
      if (hh<0||hh>=NH2) continue;
      #pragma unroll 1
      for (int kw=0;kw<3;kw++){
        int ww=w2c+kw-1;
        if (ww<0||ww>=NW2) continue;
        #pragma unroll
        for (int ci=0;ci<16;ci++){
          float v = ys[ci][hh][ww];
          const float* wr = w3s[(kh*3+kw)*16+ci];
          #pragma unroll
          for (int co=0;co<8;co++) a[co]=fmaf(v,wr[co0+co],a[co]);
        }
      }
    }
    #pragma unroll
    for (int co=0;co<8;co++) best[co]=fmaxf(best[co], lrelu(a[co]));
  }
  float4 o0,o1;
  if (many){
    o0=make_float4(best[0],best[1],best[2],best[3]);
    o1=make_float4(best[4],best[5],best[6],best[7]);
  } else { o0=make_float4(0,0,0,0); o1=o0; }
  float4* op = (float4*)(yout + ((size_t)(b*64+p))*32 + co0);
  op[0]=o0; op[1]=o1;
  if (coq==0) m3[b*64+p] = many?1:0;
}

// ============ latent head + NSF flow + kld + dec; 4 lanes per position ============
__global__ __launch_bounds__(64) void k_latent(
    const float* __restrict__ y3p, const unsigned char* __restrict__ m3,
    const float* __restrict__ eps,
    const float* __restrict__ wmu, const float* __restrict__ bmu,
    const float* __restrict__ wlv, const float* __restrict__ blv,
    const float* __restrict__ wlin, const float* __restrict__ blin,
    const float* __restrict__ fW1, const float* __restrict__ fb1,
    const float* __restrict__ fW2, const float* __restrict__ fb2,
    const float* __restrict__ fW3, const float* __restrict__ fb3,
    float* __restrict__ out_mu, float* __restrict__ out_lv,
    float* __restrict__ out_kld, float* __restrict__ out_zf,
    float* __restrict__ dec)
{
  __shared__ __align__(16) float sW1[NT*HID*LAT];
  __shared__ float sb1[NT*HID];
  __shared__ __align__(16) float sW2[NT*HID*HID];
  __shared__ float sb2[NT*HID];
  __shared__ __align__(16) float sW3[NT*LAT*NPp*HID];
  __shared__ float sb3[NT*LAT*NPp];
  __shared__ __align__(16) float swmu[LAT*NC3];
  __shared__ __align__(16) float swlv[LAT*NC3];
  __shared__ __align__(16) float slin[NC3*LAT];
  __shared__ float sbmu[LAT], sblv[LAT], sblin[NC3];
  int tid = threadIdx.x;
  for (int i=tid;i<NT*HID*LAT;i+=64){ int j=i&3; int r=(i>>2)%HID; sW1[i]=fW1[i]*(((r%3+1)>=(j+1))?1.f:0.f); }
  for (int i=tid;i<NT*HID;i+=64){ sb1[i]=fb1[i]; sb2[i]=fb2[i]; }
  for (int i=tid;i<NT*HID*HID;i+=64){ int j=i&15; int r=(i>>4)%HID; sW2[i]=fW2[i]*(((r%3+1)>=(j%3+1))?1.f:0.f); }
  for (int i=tid;i<NT*LAT*NPp*HID;i+=64){ int j=i&15; int r=(i>>4)%(LAT*NPp); sW3[i]=fW3[i]*(((r/NPp+1)>(j%3+1))?1.f:0.f); }
  for (int i=tid;i<NT*LAT*NPp;i+=64) sb3[i]=fb3[i];
  for (int i=tid;i<LAT*NC3;i+=64){ swmu[i]=wmu[i]; swlv[i]=wlv[i]; slin[i]=wlin[i]; }
  if (tid<LAT){ sbmu[tid]=bmu[tid]; sblv[tid]=blv[tid]; }
  for (int i=tid;i<NC3;i+=64) sblin[i]=blin[i];
  __syncthreads();

  int blk = blockIdx.x;
  int b   = blk >> 2;
  int gpos = b*64 + (blk&3)*16 + (tid>>2);
  int g = tid & 3;
  bool msk = m3[gpos]!=0;
  float kld_part = 0.f;
  if (msk){
    const float4* yp = (const float4*)(y3p + (size_t)gpos*NC3);
    const float4* wm = (const float4*)(swmu + g*NC3);
    const float4* wl = (const float4*)(swlv + g*NC3);
    float mu_g = sbmu[g], lv_g = sblv[g];
    #pragma unroll
    for (int q=0;q<8;q++){
      float4 yq = yp[q], a = wm[q], c = wl[q];
      mu_g = fmaf(yq.x,a.x, fmaf(yq.y,a.y, fmaf(yq.z,a.z, fmaf(yq.w,a.w, mu_g))));
      lv_g = fmaf(yq.x,c.x, fmaf(yq.y,c.y, fmaf(yq.z,c.z, fmaf(yq.w,c.w, lv_g))));
    }
    float std_g = fexpf(0.5f*lv_g);
    float ev_g  = eps[(size_t)gpos*LAT+g];
    float z0_g  = fmaf(ev_g, std_g, mu_g);
    float zg = z0_g;
    float z[4];
    z[g]=zg; z[g^1]=__shfl_xor(zg,1); z[g^2]=__shfl_xor(zg,2); z[g^3]=__shfl_xor(zg,3);
    float ld_g = 0.f;
    for (int t=0;t<NT;t++){
      float h1[16];
      const float4* W1t = (const float4*)(sW1 + t*HID*LAT);
      const float*  b1t = sb1 + t*HID;
      #pragma unroll
      for (int i2=0;i2<16;i2++){
        float4 w = W1t[i2];
        float a = b1t[i2];
        a = fmaf(z[0],w.x, fmaf(z[1],w.y, fmaf(z[2],w.z, fmaf(z[3],w.w, a))));
        h1[i2]=fmaxf(a,0.f);
      }
      float h2o[4];
      const float* W2t = sW2 + t*HID*HID;
      const float* b2t = sb2 + t*HID;
      #pragma unroll
      for (int k=0;k<4;k++){
        int row = g*4+k;
        const float4* wr = (const float4*)(W2t + row*HID);
        float a = b2t[row];
        #pragma unroll
        for (int q=0;q<4;q++){
          float4 w = wr[q];
          a = fmaf(h1[q*4+0],w.x, fmaf(h1[q*4+1],w.y, fmaf(h1[q*4+2],w.z, fmaf(h1[q*4+3],w.w, a))));
        }
        h2o[k]=fmaxf(a,0.f);
      }
      float h2[16];
      #pragma unroll
      for (int k=0;k<4;k++) h2[g*4+k]=h2o[k];
      #pragma unroll
      for (int mski=1;mski<4;mski++){
        int og = g^mski;
        #pragma unroll
        for (int k=0;k<4;k++) h2[og*4+k]=__shfl_xor(h2o[k],mski);
      }
      float p[NPp];
      const float* W3t = sW3 + t*LAT*NPp*HID;
      const float* b3t = sb3 + t*LAT*NPp;
      #pragma unroll
      for (int r=0;r<NPp;r++){
        int row = g*NPp+r;
        const float4* wr = (const float4*)(W3t + row*HID);
        float a = b3t[row];
        #pragma unroll
        for (int q=0;q<4;q++){
          float4 w = wr[q];
          a = fmaf(h2[q*4+0],w.x, fmaf(h2[q*4+1],w.y, fmaf(h2[q*4+2],w.z, fmaf(h2[q*4+3],w.w, a))));
        }
        p[r]=a;
      }
      float mw=fmaxf(fmaxf(p[0],p[1]),fmaxf(p[2],p[3]));
      float e0=fexpf(p[0]-mw), e1=fexpf(p[1]-mw), e2=fexpf(p[2]-mw), e3=fexpf(p[3]-mw);
      float wsc=10.f/(e0+e1+e2+e3);
      float xk1=fmaf(e0,wsc,-BOUNDf), xk2=fmaf(e1,wsc,xk1), xk3=fmaf(e2,wsc,xk2), xk4=fmaf(e3,wsc,xk3);
      float mh=fmaxf(fmaxf(p[4],p[5]),fmaxf(p[6],p[7]));
      float f0=fexpf(p[4]-mh), f1=fexpf(p[5]-mh), f2=fexpf(p[6]-mh), f3=fexpf(p[7]-mh);
      float hsc=10.f/(f0+f1+f2+f3);
      float yk1=fmaf(f0,hsc,-BOUNDf), yk2=fmaf(f1,hsc,yk1), yk3=fmaf(f2,hsc,yk2), yk4=fmaf(f3,hsc,yk3);
      float dk1=softplusf(p[8]), dk2=softplusf(p[9]), dk3=softplusf(p[10]);
      float xv=z[g];
      bool inside = (xv>=-BOUNDf)&&(xv<=BOUNDf);
      float xc=fminf(fmaxf(xv,-BOUNDf),BOUNDf);
      float x0=-BOUNDf, x1=xk1, y0=-BOUNDf, y1=yk1, d0=1.f, d1=dk1;
      if (xc>=xk1){x0=xk1;x1=xk2;y0=yk1;y1=yk2;d0=dk1;d1=dk2;}
      if (xc>=xk2){x0=xk2;x1=xk3;y0=yk2;y1=yk3;d0=dk2;d1=dk3;}
      if (xc>=xk3){x0=xk3;x1=xk4;y0=yk3;y1=yk4;d0=dk3;d1=1.f;}
      float dxv=x1-x0, dyv=y1-y0;
      float sl=dyv/dxv, ttv=(xc-x0)/dxv, omt=1.f-ttv;
      float den=sl + (d1+d0-2.f*sl)*ttv*omt;
      float yo=y0 + dyv*(sl*ttv*ttv + d0*ttv*omt)/den;
      float ldv=flogf(sl*sl*(d1*ttv*ttv + 2.f*sl*ttv*omt + d0*omt*omt)) - 2.f*flogf(den);
      float zn_g = inside ? yo : xv;
      ld_g += inside ? ldv : 0.f;
      float znf[4];
      znf[g]=zn_g; znf[g^1]=__shfl_xor(zn_g,1); znf[g^2]=__shfl_xor(zn_g,2); znf[g^3]=__shfl_xor(zn_g,3);
      if (t<NT-1){ z[0]=znf[3]; z[1]=znf[2]; z[2]=znf[1]; z[3]=znf[0]; }
      else       { z[0]=znf[0]; z[1]=znf[1]; z[2]=znf[2]; z[3]=znf[3]; }
    }
    float lq_g = -0.5f*ev_g*ev_g - 0.5f*lv_g - 0.5f*LOG2PI;
    float lp_g = -0.5f*z[g]*z[g] - 0.5f*LOG2PI;
    kld_part = lq_g - ld_g - lp_g;
    out_mu[(size_t)gpos*LAT+g]=mu_g;
    out_lv[(size_t)gpos*LAT+g]=lv_g;
    out_zf[(size_t)gpos*LAT+g]=z[g];
    float4 d0v, d1v;
    {
      float dv[8];
      #pragma unroll
      for (int k=0;k<8;k++){
        int c = g*8+k;
        const float4 w = ((const float4*)slin)[c];
        dv[k] = fmaf(z[0],w.x, fmaf(z[1],w.y, fmaf(z[2],w.z, fmaf(z[3],w.w, sblin[c]))));
      }
      d0v=make_float4(dv[0],dv[1],dv[2],dv[3]);
      d1v=make_float4(dv[4],dv[5],dv[6],dv[7]);
    }
    float4* dp = (float4*)(dec + (size_t)gpos*NC3 + g*8);
    dp[0]=d0v; dp[1]=d1v;
  } else {
    out_mu[(size_t)gpos*LAT+g]=0.f;
    out_lv[(size_t)gpos*LAT+g]=0.f;
    out_zf[(size_t)gpos*LAT+g]=0.f;
    float4 zv = make_float4(0,0,0,0);
    float4* dp = (float4*)(dec + (size_t)gpos*NC3 + g*8);
    dp[0]=zv; dp[1]=zv;
  }
  float s = kld_part;
  s += __shfl_xor(s,1);  s += __shfl_xor(s,2);
  s += __shfl_xor(s,4);  s += __shfl_xor(s,8);
  s += __shfl_xor(s,16); s += __shfl_xor(s,32);
  if (tid==0) atomicAdd(&out_kld[b], s);
}

// ============ fused invconv1(5,2,32,32) + conv4(3x3,32->16) -> t2, mask m2 ============
__global__ __launch_bounds__(256) void k_ic4(
    const float* __restrict__ dec, const unsigned char* __restrict__ m2,
    const float* __restrict__ u1, const float* __restrict__ bu1,
    const float* __restrict__ w4, const float* __restrict__ b4,
    float* __restrict__ t2){
  __shared__ __align__(16) float vs[12][18][32];
  __shared__ __align__(16) float w4s[288][16];
  __shared__ unsigned char msl[12][18];
  int blk = blockIdx.x;
  int b  = blk >> 2;
  int t  = blk & 3;
  int th = t >> 1, tw = t & 1;
  int h0 = th*10, w0 = tw*16;
  int tid = threadIdx.x;
  for (int i=tid;i<288*16;i+=256) w4s[i>>4][i&15] = w4[i];
  if (tid < 216){
    int lr = tid/18, lc = tid%18;
    int h2 = h0-1+lr, w2 = w0-1+lc;
    bool mk = (h2>=0 && h2<NH2 && w2>=0 && w2<NW2) && m2[(b*NH2+h2)*NW2+w2];
    msl[lr][lc] = mk?1:0;
    float acc[32];
    if (mk){
      const float* dp = dec + (((size_t)b*NH3 + h2/5)*NW3 + w2/2)*NC3;
      const float* up = u1 + ((h2%5)*2 + (w2&1))*1024;
      #pragma unroll
      for (int co=0;co<32;co++) acc[co]=bu1[co];
      #pragma unroll 1
      for (int ci=0;ci<32;ci++){
        float dv = dp[ci];
        const float* ur = up + ci*32;
        #pragma unroll
        for (int co=0;co<32;co++) acc[co]=fmaf(dv,ur[co],acc[co]);
      }
    } else {
      #pragma unroll
      for (int co=0;co<32;co++) acc[co]=0.f;
    }
    #pragma unroll
    for (int co=0;co<32;co++) vs[lr][lc][co]=acc[co];
  }
  __syncthreads();
  if (tid < 160){
    int lh = tid/16, lw = tid%16;
    int h2 = h0+lh, w2 = w0+lw;
    float a[16];
    if (msl[lh+1][lw+1]){
      #pragma unroll
      for (int co=0;co<16;co++) a[co]=b4[co];
      #pragma unroll 1
      for (int kh=0;kh<3;kh++)
      #pragma unroll 1
      for (int kw=0;kw<3;kw++){
        const float* vp = vs[lh+kh][lw+kw];
        #pragma unroll
        for (int ci=0;ci<32;ci++){
          float v = vp[ci];
          const float* wr = w4s[(kh*3+kw)*32+ci];
          #pragma unroll
          for (int co=0;co<16;co++) a[co]=fmaf(v,wr[co],a[co]);
        }
      }
    } else {
      #pragma unroll
      for (int co=0;co<16;co++) a[co]=0.f;
    }
    float* op = t2 + (((size_t)b*NH2+h2)*NW2+w2)*NC2;
    #pragma unroll
    for (int co=0;co<16;co++) op[co]=a[co];
  }
}

// ============ fused invconv2(5,2,16,16) + conv5(3x3,16->8) -> t4, mask m1 ============
__global__ __launch_bounds__(256) void k_ic5(
    const float* __restrict__ t2, const unsigned char* __restrict__ m1,
    const float* __restrict__ u2, const float* __restrict__ bu2,
    const float* __restrict__ w5, const float* __restrict__ b5,
    float* __restrict__ t4){
  __shared__ __align__(16) float vs[12][18][16];
  __shared__ __align__(16) float w5s[144][8];
  __shared__ unsigned char msl[12][18];
  int blk = blockIdx.x;
  int b  = blk / 40;
  int t  = blk % 40;
  int th = t >> 2, tw = t & 3;
  int h0 = th*10, w0 = tw*16;
  int tid = threadIdx.x;
  for (int i=tid;i<144*8;i+=256) w5s[i>>3][i&7] = w5[i];
  if (tid < 216){
    int lr = tid/18, lc = tid%18;
    int h1 = h0-1+lr, w1c = w0-1+lc;
    bool mk = (h1>=0 && h1<NH1 && w1c>=0 && w1c<NW1) && m1[(b*NH1+h1)*NW1+w1c];
    msl[lr][lc] = mk?1:0;
    float acc[16];
    if (mk){
      const float* dp = t2 + (((size_t)b*NH2 + h1/5)*NW2 + w1c/2)*NC2;
      const float* up = u2 + ((h1%5)*2 + (w1c&1))*256;
      #pragma unroll
      for (int co=0;co<16;co++) acc[co]=bu2[co];
      #pragma unroll 1
      for (int ci=0;ci<16;ci++){
        float dv = dp[ci];
        const float* ur = up + ci*16;
        #pragma unroll
        for (int co=0;co<16;co++) acc[co]=fmaf(dv,ur[co],acc[co]);
      }
    } else {
      #pragma unroll
      for (int co=0;co<16;co++) acc[co]=0.f;
    }
    #pragma unroll
    for (int co=0;co<16;co++) vs[lr][lc][co]=acc[co];
  }
  __syncthreads();
  if (tid < 160){
    int lh = tid/16, lw = tid%16;
    int h1 = h0+lh, w1c = w0+lw;
    float a[8];
    if (msl[lh+1][lw+1]){
      #pragma unroll
      for (int co=0;co<8;co++) a[co]=b5[co];
      #pragma unroll 1
      for (int kh=0;kh<3;kh++)
      #pragma unroll 1
      for (int kw=0;kw<3;kw++){
        const float* vp = vs[lh+kh][lw+kw];
        #pragma unroll
        for (int ci=0;ci<16;ci++){
          float v = vp[ci];
          const float* wr = w5s[(kh*3+kw)*16+ci];
          #pragma unroll
          for (int co=0;co<8;co++) a[co]=fmaf(v,wr[co],a[co]);
        }
      }
    } else {
      #pragma unroll
      for (int co=0;co<8;co++) a[co]=0.f;
    }
    float* op = t4 + (((size_t)b*NH1+h1)*NW1+w1c)*NC1;
    #pragma unroll
    for (int co=0;co<8;co++) op[co]=a[co];
  }
}

// ============ fused invconv3 (2,2,8,8) + conv6 (3x3,8->6), two-phase LDS ============
__global__ __launch_bounds__(256) void k_inv3conv6(
    const float* __restrict__ t4, const unsigned char* __restrict__ m0,
    const float* __restrict__ u3, const float* __restrict__ bu3,
    const float* __restrict__ w6, const float* __restrict__ b6,
    float* __restrict__ out){
  __shared__ float vs[8][18][68];
  __shared__ unsigned char msl[18][66];
  __shared__ float u3s[4][8][8];
  __shared__ float w6s[9][8][6];
  __shared__ float bu3s[8];
  __shared__ float b6s[6];
  int blk = blockIdx.x;
  int b  = blk / 26;
  int t  = blk % 26;
  int th = t >> 1, tw = t & 1;
  int h0 = th*16, w0 = tw*64;
  int tid = threadIdx.x;
  for (int i=tid;i<256;i+=256){ u3s[i>>6][(i>>3)&7][i&7]=u3[i]; }
  for (int i=tid;i<432;i+=256){ int tap=i/48; int rem=i%48; w6s[tap][rem/6][rem%6]=w6[i]; }
  if (tid<8) bu3s[tid]=bu3[tid];
  if (tid<6) b6s[tid]=b6[tid];
  __syncthreads();
  for (int p=tid;p<18*66;p+=256){
    int r=p/66, c=p-(p/66)*66;
    int h=h0-1+r, w=w0-1+c;
    bool act = (h>=0 && h<NH0 && w>=0 && w<NW0) && m0[(b*NH0+h)*NW0+w];
    msl[r][c] = act?1:0;
    float v8[8];
    if (act){
      const float4* tp = (const float4*)(t4 + (((size_t)b*NH1 + (h>>1))*NW1 + (w>>1))*8);
      float4 q0=tp[0], q1=tp[1];
      float tin[8]={q0.x,q0.y,q0.z,q0.w,q1.x,q1.y,q1.z,q1.w};
      const float (*up)[8] = u3s[(h&1)*2+(w&1)];
      #pragma unroll
      for (int c8=0;c8<8;c8++) v8[c8]=bu3s[c8];
      #pragma unroll
      for (int ci=0;ci<8;ci++){
        float v=tin[ci];
        #pragma unroll
        for (int c8=0;c8<8;c8++) v8[c8]=fmaf(v, up[ci][c8], v8[c8]);
      }
    } else {
      #pragma unroll
      for (int c8=0;c8<8;c8++) v8[c8]=0.f;
    }
    #pragma unroll
    for (int c8=0;c8<8;c8++) vs[c8][r][c]=v8[c8];
  }
  __syncthreads();
  #pragma unroll 1
  for (int k=0;k<4;k++){
    int p = tid + k*256;
    int lh = p>>6, lw = p&63;
    int h = h0+lh, w = w0+lw;
    if (h >= NH0) continue;
    float acc[6];
    if (msl[lh+1][lw+1]){
      #pragma unroll
      for (int co=0;co<6;co++) acc[co]=b6s[co];
      #pragma unroll 1
      for (int kh=0;kh<3;kh++)
      #pragma unroll 1
      for (int kw=0;kw<3;kw++){
        const float (*wt)[6] = w6s[kh*3+kw];
        #pragma unroll
        for (int ci=0;ci<8;ci++){
          float v = vs[ci][lh+kh][lw+kw];
          #pragma unroll
          for (int co=0;co<6;co++) acc[co]=fmaf(v, wt[ci][co], acc[co]);
        }
      }
    } else {
      #pragma unroll
      for (int co=0;co<6;co++) acc[co]=0.f;
    }
    size_t base = (size_t)b*6*NH0*NW0 + (size_t)h*NW0 + w;
    #pragma unroll
    for (int co=0;co<6;co++) out[base + (size_t)co*NH0*NW0] = acc[co];
  }
}

extern "C" void kernel_launch(void* const* d_in, const int* in_sizes, int n_in,
                              void* d_out, int out_size, void* d_ws, size_t ws_size,
                              hipStream_t stream){
  (void)in_sizes; (void)n_in; (void)out_size; (void)ws_size;
  const float* x    = (const float*)d_in[0];
  const float* eps  = (const float*)d_in[1];
  const float* w1   = (const float*)d_in[2];
  const float* b1   = (const float*)d_in[3];
  const float* w2   = (const float*)d_in[4];
  const float* b2   = (const float*)d_in[5];
  const float* w3   = (const float*)d_in[6];
  const float* b3   = (const float*)d_in[7];
  const float* wmu  = (const float*)d_in[8];
  const float* bmu  = (const float*)d_in[9];
  const float* wlv  = (const float*)d_in[10];
  const float* blv  = (const float*)d_in[11];
  const float* wlin = (const float*)d_in[12];
  const float* blin = (const float*)d_in[13];
  const float* u1   = (const float*)d_in[14];
  const float* bu1  = (const float*)d_in[15];
  const float* w4   = (const float*)d_in[16];
  const float* b4   = (const float*)d_in[17];
  const float* u2   = (const float*)d_in[18];
  const float* bu2  = (const float*)d_in[19];
  const float* w5   = (const float*)d_in[20];
  const float* b5   = (const float*)d_in[21];
  const float* u3   = (const float*)d_in[22];
  const float* bu3  = (const float*)d_in[23];
  const float* w6   = (const float*)d_in[24];
  const float* b6   = (const float*)d_in[25];
  const float* fW1  = (const float*)d_in[26];
  const float* fb1  = (const float*)d_in[27];
  const float* fW2  = (const float*)d_in[28];
  const float* fb2  = (const float*)d_in[29];
  const float* fW3  = (const float*)d_in[30];
  const float* fb3  = (const float*)d_in[31];

  char* ws = (char*)d_ws;
  unsigned char* m0 = (unsigned char*)(ws);
  unsigned char* m1 = (unsigned char*)(ws + 3276800);
  unsigned char* m2 = (unsigned char*)(ws + 4096000);
  unsigned char* m3 = (unsigned char*)(ws + 4177920);
  float* y1p = (float*)(ws + 4194304);    // [B][100][64][8]
  float* y2p = (float*)(ws + 30408704);   // [B][20][32][16]
  float* y3p = (float*)(ws + 35651584);   // [B][4][16][32]
  float* dec = (float*)(ws + 36700160);   // [B][4][16][32]
  float* t2  = y2p;  // reuse
  float* t4  = y1p;  // reuse

  float* out   = (float*)d_out;
  float* o_mu  = out + 19660800;
  float* o_lv  = out + 19693568;
  float* o_kld = out + 19726336;
  float* o_zf  = out + 19726464;

  k_conv1pool<<<13312,256,0,stream>>>(x, w1, b1, y1p, m0, m1);
  k_conv2pool<<< 1024,256,0,stream>>>(y1p, m1, w2, b2, y2p, m2);
  k_conv3pool<<<  128,256,0,stream>>>(y2p, m2, w3, b3, y3p, m3, o_kld);
  k_latent   <<<  512, 64,0,stream>>>(y3p, m3, eps, wmu,bmu,wlv,blv,wlin,blin,
                                      fW1,fb1,fW2,fb2,fW3,fb3, o_mu,o_lv,o_kld,o_zf, dec);
  k_ic4      <<<  512,256,0,stream>>>(dec, m2, u1, bu1, w4, b4, t2);
  k_ic5      <<< 5120,256,0,stream>>>(t2, m1, u2, bu2, w5, b5, t4);
  k_inv3conv6<<< 3328,256,0,stream>>>(t4, m0, u3, bu3, w6, b6, out);
}

// Round 9
// 440.534 us; speedup vs baseline: 3.4823x; 1.0204x over previous
//
#include <hip/hip_runtime.h>
#include <math.h>

constexpr int NB=128;
constexpr int NH0=200, NW0=128, NC0=6;
constexpr int NH1=100, NW1=64,  NC1=8;
constexpr int NH2=20,  NW2=32,  NC2=16;
constexpr int NH3=4,   NW3=16,  NC3=32;
constexpr int LAT=4, NPp=11, HID=16, NT=10;
constexpr float BOUNDf=5.0f;
constexpr float LOG2PI=1.8378770664093453f;

__device__ __forceinline__ float fexpf(float v){ return __expf(v); }
__device__ __forceinline__ float flogf(float v){ return __logf(v); }
__device__ __forceinline__ float softplusf(float v){ return v>20.f ? v : __logf(1.f+__expf(v)); }
__device__ __forceinline__ float lrelu(float v){ return v>0.f ? v : 0.01f*v; }

// ============ conv1 (3x3,6->8) + lrelu + pool2x2 ============
// vertical pool-pair per thread; 16x8 pool tile (32x16 pre-pool); halo 34x18 in LDS
// full unroll -> immediate-offset LDS reads; weights amortized over 2 px
__global__ __launch_bounds__(256) void k_conv1pool(
    const float* __restrict__ x, const float* __restrict__ w1, const float* __restrict__ b1,
    float* __restrict__ y1p, unsigned char* __restrict__ m0, unsigned char* __restrict__ m1){
  __shared__ float xs[6][34][19];
  __shared__ float ws1[54][8];
  __shared__ float b1s[8];
  int blk = blockIdx.x;
  int b  = blk / 56;
  int t  = blk % 56;
  int th = t >> 3, tw = t & 7;   // th 0..6 (16 pool rows), tw 0..7 (8 pool cols)
  int h0 = th*32, w0 = tw*16;    // pre-pool tile origin
  int tid = threadIdx.x;
  for (int i=tid;i<432;i+=256) ws1[i>>3][i&7] = w1[i];
  if (tid<8) b1s[tid]=b1[tid];
  for (int i=tid;i<6*34*18;i+=256){
    int ci=i/612; int rem=i-ci*612; int r=rem/18, c=rem-r*18;
    int h=h0-1+r, w=w0-1+c;
    float v=0.f;
    if (h>=0 && h<NH0 && w>=0 && w<NW0) v = x[((size_t)(b*NC0+ci)*NH0+h)*NW0+w];
    xs[ci][r][c]=v;
  }
  __syncthreads();
  int pp = tid>>4, pj = tid&15;     // pp: pool-row within tile (0..15), pj: pre-col (0..15)
  int hA = h0 + 2*pp;               // pre-pool rows hA, hA+1
  int w  = w0 + pj;
  bool inbA = (hA   < NH0);
  bool inbB = (hA+1 < NH0);
  // activity from center taps (xs row = 2pp+1 / 2pp+2, col = pj+1)
  bool actA=false, actB=false;
  #pragma unroll
  for (int ci=0;ci<6;ci++){
    actA |= (xs[ci][2*pp+1][pj+1]!=0.f);
    actB |= (xs[ci][2*pp+2][pj+1]!=0.f);
  }
  actA = actA && inbA;
  actB = actB && inbB;
  if (inbA) m0[(b*NH0+hA  )*NW0+w] = actA?1:0;
  if (inbB) m0[(b*NH0+hA+1)*NW0+w] = actB?1:0;
  float aA[8], aB[8];
  #pragma unroll
  for (int co=0;co<8;co++){ aA[co]=b1s[co]; aB[co]=b1s[co]; }
  #pragma unroll
  for (int ci=0;ci<6;ci++){
    #pragma unroll
    for (int kh=0;kh<3;kh++){
      #pragma unroll
      for (int kw=0;kw<3;kw++){
        float vA = xs[ci][2*pp+kh  ][pj+kw];
        float vB = xs[ci][2*pp+kh+1][pj+kw];
        const float* wv = ws1[(kh*3+kw)*6+ci];
        #pragma unroll
        for (int co=0;co<8;co++){
          float wc = wv[co];
          aA[co]=fmaf(vA,wc,aA[co]);
          aB[co]=fmaf(vB,wc,aB[co]);
        }
      }
    }
  }
  float best[8];
  #pragma unroll
  for (int co=0;co<8;co++){
    float va = actA ? lrelu(aA[co]) : -1e30f;
    float vb = actB ? lrelu(aB[co]) : -1e30f;
    float v  = fmaxf(va,vb);
    best[co] = fmaxf(v, __shfl_xor(v,1));
  }
  float af = (actA||actB) ? 1.f : 0.f;
  af = fmaxf(af, __shfl_xor(af,1));
  bool anyact = af>0.f;
  int hp = th*16 + pp;
  if (((pj&1)==0) && hp < NH1){
    int wp = tw*8 + (pj>>1);
    float4 o0,o1;
    if (anyact){
      o0=make_float4(best[0],best[1],best[2],best[3]);
      o1=make_float4(best[4],best[5],best[6],best[7]);
    } else { o0=make_float4(0,0,0,0); o1=o0; }
    float4* yp = (float4*)(y1p + (((size_t)b*NH1+hp)*NW1+wp)*8);
    yp[0]=o0; yp[1]=o1;
    m1[(b*NH1+hp)*NW1+wp] = anyact?1:0;
  }
}

// ============ conv2 (3x3,8->16) + lrelu + pool 5x2, small-tile LDS, co-split ============
__global__ __launch_bounds__(256) void k_conv2pool(
    const float* __restrict__ yin, const unsigned char* __restrict__ m1,
    const float* __restrict__ w2, const float* __restrict__ b2,
    float* __restrict__ yout, unsigned char* __restrict__ m2){
  __shared__ float ys[8][27][35];
  __shared__ unsigned char msl[27][35];
  __shared__ float w2s[72][16];
  __shared__ float b2s[16];
  int blk = blockIdx.x;
  int b  = blk >> 3;
  int t  = blk & 7;
  int th = t >> 1, tw = t & 1;
  int r0 = th*25 - 1, c0 = tw*32 - 1;
  int tid = threadIdx.x;
  for (int i=tid;i<1152;i+=256) w2s[i>>4][i&15] = w2[i];
  if (tid<16) b2s[tid]=b2[tid];
  for (int p=tid;p<27*34;p+=256){
    int r=p/34, c=p-(p/34)*34;
    int h1=r0+r, w1c=c0+c;
    bool ok = (h1>=0 && h1<NH1 && w1c>=0 && w1c<NW1);
    msl[r][c] = ok ? m1[(b*NH1+h1)*NW1+w1c] : 0;
    float4 v0=make_float4(0,0,0,0), v1=v0;
    if (ok){
      const float4* pp = (const float4*)(yin + (((size_t)b*NH1+h1)*NW1+w1c)*8);
      v0=pp[0]; v1=pp[1];
    }
    ys[0][r][c]=v0.x; ys[1][r][c]=v0.y; ys[2][r][c]=v0.z; ys[3][r][c]=v0.w;
    ys[4][r][c]=v1.x; ys[5][r][c]=v1.y; ys[6][r][c]=v1.z; ys[7][r][c]=v1.w;
  }
  __syncthreads();
  if (tid < 160){
    int oid = tid >> 1, coq = tid & 1;
    int co0 = coq*8;
    int lh = oid >> 4, lw = oid & 15;
    int h2 = th*5+lh, w2c = tw*16+lw;
    float best[8];
    #pragma unroll
    for (int co=0;co<8;co++) best[co]=-1e30f;
    bool many=false;
    #pragma unroll 1
    for (int i=0;i<5;i++)
    #pragma unroll 1
    for (int j=0;j<2;j++){
      int r = lh*5+i+1, c = lw*2+j+1;
      if (!msl[r][c]) continue;
      many=true;
      float a[8];
      #pragma unroll
      for (int co=0;co<8;co++) a[co]=b2s[co0+co];
      #pragma unroll 1
      for (int kh=0;kh<3;kh++)
      #pragma unroll 1
      for (int kw=0;kw<3;kw++){
        #pragma unroll
        for (int ci=0;ci<8;ci++){
          float v = ys[ci][r-1+kh][c-1+kw];
          const float* wr = w2s[(kh*3+kw)*8+ci];
          #pragma unroll
          for (int co=0;co<8;co++) a[co]=fmaf(v,wr[co0+co],a[co]);
        }
      }
      #pragma unroll
      for (int co=0;co<8;co++) best[co]=fmaxf(best[co], lrelu(a[co]));
    }
    float4 o0,o1;
    if (many){
      o0=make_float4(best[0],best[1],best[2],best[3]);
      o1=make_float4(best[4],best[5],best[6],best[7]);
    } else { o0=make_float4(0,0,0,0); o1=o0; }
    float4* op = (float4*)(yout + (((size_t)b*NH2+h2)*NW2+w2c)*16 + co0);
    op[0]=o0; op[1]=o1;
    if (coq==0) m2[(b*NH2+h2)*NW2+w2c] = many?1:0;
  }
}

// ============ conv3 (3x3,16->32) + lrelu + pool 5x2, per-batch LDS-tiled ============
__global__ __launch_bounds__(256) void k_conv3pool(
    const float* __restrict__ yin, const unsigned char* __restrict__ m2,
    const float* __restrict__ w3, const float* __restrict__ b3,
    float* __restrict__ yout, unsigned char* __restrict__ m3,
    float* __restrict__ out_kld){
  __shared__ float ys[16][20][33];
  __shared__ unsigned char msl[20][32];
  __shared__ float w3s[144][32];
  __shared__ float b3s[32];
  int b = blockIdx.x;
  int tid = threadIdx.x;
  if (tid==0) out_kld[b]=0.f;
  for (int i=tid;i<4608;i+=256) w3s[i>>5][i&31] = w3[i];
  if (tid<32) b3s[tid]=b3[tid];
  for (int p=tid;p<640;p+=256){
    int r=p>>5, c=p&31;
    msl[r][c] = m2[(b*NH2+r)*NW2+c];
    const float4* pp = (const float4*)(yin + (((size_t)b*NH2+r)*NW2+c)*16);
    float4 q0=pp[0],q1=pp[1],q2=pp[2],q3=pp[3];
    ys[0][r][c]=q0.x; ys[1][r][c]=q0.y; ys[2][r][c]=q0.z; ys[3][r][c]=q0.w;
    ys[4][r][c]=q1.x; ys[5][r][c]=q1.y; ys[6][r][c]=q1.z; ys[7][r][c]=q1.w;
    ys[8][r][c]=q2.x; ys[9][r][c]=q2.y; ys[10][r][c]=q2.z; ys[11][r][c]=q2.w;
    ys[12][r][c]=q3.x; ys[13][r][c]=q3.y; ys[14][r][c]=q3.z; ys[15][r][c]=q3.w;
  }
  __syncthreads();
  int p = tid>>2, coq = tid&3;
  int co0 = coq*8;
  int hp = p>>4, wp = p&15;
  float best[8];
  #pragma unroll
  for (int co=0;co<8;co++) best[co]=-1e30f;
  bool many=false;
  #pragma unroll 1
  for (int i=0;i<5;i++)
  #pragma unroll 1
  for (int j=0;j<2;j++){
    int h2 = hp*5+i, w2c = wp*2+j;
    if (!msl[h2][w2c]) continue;
    many=true;
    float a[8];
    #pragma unroll
    for (int co=0;co<8;co++) a[co]=b3s[co0+co];
    #pragma unroll 1
    for (int kh=0;kh<3;kh++){
      int hh=h2+kh-1;
      if (hh<0||hh>=NH2) continue;
      #pragma unroll 1
      for (int kw=0;kw<3;kw++){
        int ww=w2c+kw-1;
        if (ww<0||ww>=NW2) continue;
        #pragma unroll
        for (int ci=0;ci<16;ci++){
          float v = ys[ci][hh][ww];
          const float* wr = w3s[(kh*3+kw)*16+ci];
          #pragma unroll
          for (int co=0;co<8;co++) a[co]=fmaf(v,wr[co0+co],a[co]);
        }
      }
    }
    #pragma unroll
    for (int co=0;co<8;co++) best[co]=fmaxf(best[co], lrelu(a[co]));
  }
  float4 o0,o1;
  if (many){
    o0=make_float4(best[0],best[1],best[2],best[3]);
    o1=make_float4(best[4],best[5],best[6],best[7]);
  } else { o0=make_float4(0,0,0,0); o1=o0; }
  float4* op = (float4*)(yout + ((size_t)(b*64+p))*32 + co0);
  op[0]=o0; op[1]=o1;
  if (coq==0) m3[b*64+p] = many?1:0;
}

// ============ latent head + NSF flow + kld + dec; 4 lanes per position ============
__global__ __launch_bounds__(64) void k_latent(
    const float* __restrict__ y3p, const unsigned char* __restrict__ m3,
    const float* __restrict__ eps,
    const float* __restrict__ wmu, const float* __restrict__ bmu,
    const float* __restrict__ wlv, const float* __restrict__ blv,
    const float* __restrict__ wlin, const float* __restrict__ blin,
    const float* __restrict__ fW1, const float* __restrict__ fb1,
    const float* __restrict__ fW2, const float* __restrict__ fb2,
    const float* __restrict__ fW3, const float* __restrict__ fb3,
    float* __restrict__ out_mu, float* __restrict__ out_lv,
    float* __restrict__ out_kld, float* __restrict__ out_zf,
    float* __restrict__ dec)
{
  __shared__ __align__(16) float sW1[NT*HID*LAT];
  __shared__ float sb1[NT*HID];
  __shared__ __align__(16) float sW2[NT*HID*HID];
  __shared__ float sb2[NT*HID];
  __shared__ __align__(16) float sW3[NT*LAT*NPp*HID];
  __shared__ float sb3[NT*LAT*NPp];
  __shared__ __align__(16) float swmu[LAT*NC3];
  __shared__ __align__(16) float swlv[LAT*NC3];
  __shared__ __align__(16) float slin[NC3*LAT];
  __shared__ float sbmu[LAT], sblv[LAT], sblin[NC3];
  int tid = threadIdx.x;
  for (int i=tid;i<NT*HID*LAT;i+=64){ int j=i&3; int r=(i>>2)%HID; sW1[i]=fW1[i]*(((r%3+1)>=(j+1))?1.f:0.f); }
  for (int i=tid;i<NT*HID;i+=64){ sb1[i]=fb1[i]; sb2[i]=fb2[i]; }
  for (int i=tid;i<NT*HID*HID;i+=64){ int j=i&15; int r=(i>>4)%HID; sW2[i]=fW2[i]*(((r%3+1)>=(j%3+1))?1.f:0.f); }
  for (int i=tid;i<NT*LAT*NPp*HID;i+=64){ int j=i&15; int r=(i>>4)%(LAT*NPp); sW3[i]=fW3[i]*(((r/NPp+1)>(j%3+1))?1.f:0.f); }
  for (int i=tid;i<NT*LAT*NPp;i+=64) sb3[i]=fb3[i];
  for (int i=tid;i<LAT*NC3;i+=64){ swmu[i]=wmu[i]; swlv[i]=wlv[i]; slin[i]=wlin[i]; }
  if (tid<LAT){ sbmu[tid]=bmu[tid]; sblv[tid]=blv[tid]; }
  for (int i=tid;i<NC3;i+=64) sblin[i]=blin[i];
  __syncthreads();

  int blk = blockIdx.x;
  int b   = blk >> 2;
  int gpos = b*64 + (blk&3)*16 + (tid>>2);
  int g = tid & 3;
  bool msk = m3[gpos]!=0;
  float kld_part = 0.f;
  if (msk){
    const float4* yp = (const float4*)(y3p + (size_t)gpos*NC3);
    const float4* wm = (const float4*)(swmu + g*NC3);
    const float4* wl = (const float4*)(swlv + g*NC3);
    float mu_g = sbmu[g], lv_g = sblv[g];
    #pragma unroll
    for (int q=0;q<8;q++){
      float4 yq = yp[q], a = wm[q], c = wl[q];
      mu_g = fmaf(yq.x,a.x, fmaf(yq.y,a.y, fmaf(yq.z,a.z, fmaf(yq.w,a.w, mu_g))));
      lv_g = fmaf(yq.x,c.x, fmaf(yq.y,c.y, fmaf(yq.z,c.z, fmaf(yq.w,c.w, lv_g))));
    }
    float std_g = fexpf(0.5f*lv_g);
    float ev_g  = eps[(size_t)gpos*LAT+g];
    float z0_g  = fmaf(ev_g, std_g, mu_g);
    float zg = z0_g;
    float z[4];
    z[g]=zg; z[g^1]=__shfl_xor(zg,1); z[g^2]=__shfl_xor(zg,2); z[g^3]=__shfl_xor(zg,3);
    float ld_g = 0.f;
    for (int t=0;t<NT;t++){
      float h1[16];
      const float4* W1t = (const float4*)(sW1 + t*HID*LAT);
      const float*  b1t = sb1 + t*HID;
      #pragma unroll
      for (int i2=0;i2<16;i2++){
        float4 w = W1t[i2];
        float a = b1t[i2];
        a = fmaf(z[0],w.x, fmaf(z[1],w.y, fmaf(z[2],w.z, fmaf(z[3],w.w, a))));
        h1[i2]=fmaxf(a,0.f);
      }
      float h2o[4];
      const float* W2t = sW2 + t*HID*HID;
      const float* b2t = sb2 + t*HID;
      #pragma unroll
      for (int k=0;k<4;k++){
        int row = g*4+k;
        const float4* wr = (const float4*)(W2t + row*HID);
        float a = b2t[row];
        #pragma unroll
        for (int q=0;q<4;q++){
          float4 w = wr[q];
          a = fmaf(h1[q*4+0],w.x, fmaf(h1[q*4+1],w.y, fmaf(h1[q*4+2],w.z, fmaf(h1[q*4+3],w.w, a))));
        }
        h2o[k]=fmaxf(a,0.f);
      }
      float h2[16];
      #pragma unroll
      for (int k=0;k<4;k++) h2[g*4+k]=h2o[k];
      #pragma unroll
      for (int mski=1;mski<4;mski++){
        int og = g^mski;
        #pragma unroll
        for (int k=0;k<4;k++) h2[og*4+k]=__shfl_xor(h2o[k],mski);
      }
      float p[NPp];
      const float* W3t = sW3 + t*LAT*NPp*HID;
      const float* b3t = sb3 + t*LAT*NPp;
      #pragma unroll
      for (int r=0;r<NPp;r++){
        int row = g*NPp+r;
        const float4* wr = (const float4*)(W3t + row*HID);
        float a = b3t[row];
        #pragma unroll
        for (int q=0;q<4;q++){
          float4 w = wr[q];
          a = fmaf(h2[q*4+0],w.x, fmaf(h2[q*4+1],w.y, fmaf(h2[q*4+2],w.z, fmaf(h2[q*4+3],w.w, a))));
        }
        p[r]=a;
      }
      float mw=fmaxf(fmaxf(p[0],p[1]),fmaxf(p[2],p[3]));
      float e0=fexpf(p[0]-mw), e1=fexpf(p[1]-mw), e2=fexpf(p[2]-mw), e3=fexpf(p[3]-mw);
      float wsc=10.f/(e0+e1+e2+e3);
      float xk1=fmaf(e0,wsc,-BOUNDf), xk2=fmaf(e1,wsc,xk1), xk3=fmaf(e2,wsc,xk2), xk4=fmaf(e3,wsc,xk3);
      float mh=fmaxf(fmaxf(p[4],p[5]),fmaxf(p[6],p[7]));
      float f0=fexpf(p[4]-mh), f1=fexpf(p[5]-mh), f2=fexpf(p[6]-mh), f3=fexpf(p[7]-mh);
      float hsc=10.f/(f0+f1+f2+f3);
      float yk1=fmaf(f0,hsc,-BOUNDf), yk2=fmaf(f1,hsc,yk1), yk3=fmaf(f2,hsc,yk2), yk4=fmaf(f3,hsc,yk3);
      float dk1=softplusf(p[8]), dk2=softplusf(p[9]), dk3=softplusf(p[10]);
      float xv=z[g];
      bool inside = (xv>=-BOUNDf)&&(xv<=BOUNDf);
      float xc=fminf(fmaxf(xv,-BOUNDf),BOUNDf);
      float x0=-BOUNDf, x1=xk1, y0=-BOUNDf, y1=yk1, d0=1.f, d1=dk1;
      if (xc>=xk1){x0=xk1;x1=xk2;y0=yk1;y1=yk2;d0=dk1;d1=dk2;}
      if (xc>=xk2){x0=xk2;x1=xk3;y0=yk2;y1=yk3;d0=dk2;d1=dk3;}
      if (xc>=xk3){x0=xk3;x1=xk4;y0=yk3;y1=yk4;d0=dk3;d1=1.f;}
      float dxv=x1-x0, dyv=y1-y0;
      float sl=dyv/dxv, ttv=(xc-x0)/dxv, omt=1.f-ttv;
      float den=sl + (d1+d0-2.f*sl)*ttv*omt;
      float yo=y0 + dyv*(sl*ttv*ttv + d0*ttv*omt)/den;
      float ldv=flogf(sl*sl*(d1*ttv*ttv + 2.f*sl*ttv*omt + d0*omt*omt)) - 2.f*flogf(den);
      float zn_g = inside ? yo : xv;
      ld_g += inside ? ldv : 0.f;
      float znf[4];
      znf[g]=zn_g; znf[g^1]=__shfl_xor(zn_g,1); znf[g^2]=__shfl_xor(zn_g,2); znf[g^3]=__shfl_xor(zn_g,3);
      if (t<NT-1){ z[0]=znf[3]; z[1]=znf[2]; z[2]=znf[1]; z[3]=znf[0]; }
      else       { z[0]=znf[0]; z[1]=znf[1]; z[2]=znf[2]; z[3]=znf[3]; }
    }
    float lq_g = -0.5f*ev_g*ev_g - 0.5f*lv_g - 0.5f*LOG2PI;
    float lp_g = -0.5f*z[g]*z[g] - 0.5f*LOG2PI;
    kld_part = lq_g - ld_g - lp_g;
    out_mu[(size_t)gpos*LAT+g]=mu_g;
    out_lv[(size_t)gpos*LAT+g]=lv_g;
    out_zf[(size_t)gpos*LAT+g]=z[g];
    float4 d0v, d1v;
    {
      float dv[8];
      #pragma unroll
      for (int k=0;k<8;k++){
        int c = g*8+k;
        const float4 w = ((const float4*)slin)[c];
        dv[k] = fmaf(z[0],w.x, fmaf(z[1],w.y, fmaf(z[2],w.z, fmaf(z[3],w.w, sblin[c]))));
      }
      d0v=make_float4(dv[0],dv[1],dv[2],dv[3]);
      d1v=make_float4(dv[4],dv[5],dv[6],dv[7]);
    }
    float4* dp = (float4*)(dec + (size_t)gpos*NC3 + g*8);
    dp[0]=d0v; dp[1]=d1v;
  } else {
    out_mu[(size_t)gpos*LAT+g]=0.f;
    out_lv[(size_t)gpos*LAT+g]=0.f;
    out_zf[(size_t)gpos*LAT+g]=0.f;
    float4 zv = make_float4(0,0,0,0);
    float4* dp = (float4*)(dec + (size_t)gpos*NC3 + g*8);
    dp[0]=zv; dp[1]=zv;
  }
  float s = kld_part;
  s += __shfl_xor(s,1);  s += __shfl_xor(s,2);
  s += __shfl_xor(s,4);  s += __shfl_xor(s,8);
  s += __shfl_xor(s,16); s += __shfl_xor(s,32);
  if (tid==0) atomicAdd(&out_kld[b], s);
}

// ============ fused invconv1(5,2,32,32) + conv4(3x3,32->16) -> t2, mask m2 ============
__global__ __launch_bounds__(256) void k_ic4(
    const float* __restrict__ dec, const unsigned char* __restrict__ m2,
    const float* __restrict__ u1, const float* __restrict__ bu1,
    const float* __restrict__ w4, const float* __restrict__ b4,
    float* __restrict__ t2){
  __shared__ __align__(16) float vs[12][18][32];
  __shared__ __align__(16) float w4s[288][16];
  __shared__ unsigned char msl[12][18];
  int blk = blockIdx.x;
  int b  = blk >> 2;
  int t  = blk & 3;
  int th = t >> 1, tw = t & 1;
  int h0 = th*10, w0 = tw*16;
  int tid = threadIdx.x;
  for (int i=tid;i<288*16;i+=256) w4s[i>>4][i&15] = w4[i];
  if (tid < 216){
    int lr = tid/18, lc = tid%18;
    int h2 = h0-1+lr, w2 = w0-1+lc;
    bool mk = (h2>=0 && h2<NH2 && w2>=0 && w2<NW2) && m2[(b*NH2+h2)*NW2+w2];
    msl[lr][lc] = mk?1:0;
    float acc[32];
    if (mk){
      const float* dp = dec + (((size_t)b*NH3 + h2/5)*NW3 + w2/2)*NC3;
      const float* up = u1 + ((h2%5)*2 + (w2&1))*1024;
      #pragma unroll
      for (int co=0;co<32;co++) acc[co]=bu1[co];
      #pragma unroll 1
      for (int ci=0;ci<32;ci++){
        float dv = dp[ci];
        const float* ur = up + ci*32;
        #pragma unroll
        for (int co=0;co<32;co++) acc[co]=fmaf(dv,ur[co],acc[co]);
      }
    } else {
      #pragma unroll
      for (int co=0;co<32;co++) acc[co]=0.f;
    }
    #pragma unroll
    for (int co=0;co<32;co++) vs[lr][lc][co]=acc[co];
  }
  __syncthreads();
  if (tid < 160){
    int lh = tid/16, lw = tid%16;
    int h2 = h0+lh, w2 = w0+lw;
    float a[16];
    if (msl[lh+1][lw+1]){
      #pragma unroll
      for (int co=0;co<16;co++) a[co]=b4[co];
      #pragma unroll 1
      for (int kh=0;kh<3;kh++)
      #pragma unroll 1
      for (int kw=0;kw<3;kw++){
        const float* vp = vs[lh+kh][lw+kw];
        #pragma unroll
        for (int ci=0;ci<32;ci++){
          float v = vp[ci];
          const float* wr = w4s[(kh*3+kw)*32+ci];
          #pragma unroll
          for (int co=0;co<16;co++) a[co]=fmaf(v,wr[co],a[co]);
        }
      }
    } else {
      #pragma unroll
      for (int co=0;co<16;co++) a[co]=0.f;
    }
    float* op = t2 + (((size_t)b*NH2+h2)*NW2+w2)*NC2;
    #pragma unroll
    for (int co=0;co<16;co++) op[co]=a[co];
  }
}

// ============ fused invconv2(5,2,16,16) + conv5(3x3,16->8) -> t4, mask m1 ============
__global__ __launch_bounds__(256) void k_ic5(
    const float* __restrict__ t2, const unsigned char* __restrict__ m1,
    const float* __restrict__ u2, const float* __restrict__ bu2,
    const float* __restrict__ w5, const float* __restrict__ b5,
    float* __restrict__ t4){
  __shared__ __align__(16) float vs[12][18][16];
  __shared__ __align__(16) float w5s[144][8];
  __shared__ unsigned char msl[12][18];
  int blk = blockIdx.x;
  int b  = blk / 40;
  int t  = blk % 40;
  int th = t >> 2, tw = t & 3;
  int h0 = th*10, w0 = tw*16;
  int tid = threadIdx.x;
  for (int i=tid;i<144*8;i+=256) w5s[i>>3][i&7] = w5[i];
  if (tid < 216){
    int lr = tid/18, lc = tid%18;
    int h1 = h0-1+lr, w1c = w0-1+lc;
    bool mk = (h1>=0 && h1<NH1 && w1c>=0 && w1c<NW1) && m1[(b*NH1+h1)*NW1+w1c];
    msl[lr][lc] = mk?1:0;
    float acc[16];
    if (mk){
      const float* dp = t2 + (((size_t)b*NH2 + h1/5)*NW2 + w1c/2)*NC2;
      const float* up = u2 + ((h1%5)*2 + (w1c&1))*256;
      #pragma unroll
      for (int co=0;co<16;co++) acc[co]=bu2[co];
      #pragma unroll 1
      for (int ci=0;ci<16;ci++){
        float dv = dp[ci];
        const float* ur = up + ci*16;
        #pragma unroll
        for (int co=0;co<16;co++) acc[co]=fmaf(dv,ur[co],acc[co]);
      }
    } else {
      #pragma unroll
      for (int co=0;co<16;co++) acc[co]=0.f;
    }
    #pragma unroll
    for (int co=0;co<16;co++) vs[lr][lc][co]=acc[co];
  }
  __syncthreads();
  if (tid < 160){
    int lh = tid/16, lw = tid%16;
    int h1 = h0+lh, w1c = w0+lw;
    float a[8];
    if (msl[lh+1][lw+1]){
      #pragma unroll
      for (int co=0;co<8;co++) a[co]=b5[co];
      #pragma unroll 1
      for (int kh=0;kh<3;kh++)
      #pragma unroll 1
      for (int kw=0;kw<3;kw++){
        const float* vp = vs[lh+kh][lw+kw];
        #pragma unroll
        for (int ci=0;ci<16;ci++){
          float v = vp[ci];
          const float* wr = w5s[(kh*3+kw)*16+ci];
          #pragma unroll
          for (int co=0;co<8;co++) a[co]=fmaf(v,wr[co],a[co]);
        }
      }
    } else {
      #pragma unroll
      for (int co=0;co<8;co++) a[co]=0.f;
    }
    float* op = t4 + (((size_t)b*NH1+h1)*NW1+w1c)*NC1;
    #pragma unroll
    for (int co=0;co<8;co++) op[co]=a[co];
  }
}

// ============ fused invconv3 (2,2,8,8) + conv6 (3x3,8->6), two-phase LDS ============
__global__ __launch_bounds__(256) void k_inv3conv6(
    const float* __restrict__ t4, const unsigned char* __restrict__ m0,
    const float* __restrict__ u3, const float* __restrict__ bu3,
    const float* __restrict__ w6, const float* __restrict__ b6,
    float* __restrict__ out){
  __shared__ float vs[8][18][68];
  __shared__ unsigned char msl[18][66];
  __shared__ float u3s[4][8][8];
  __shared__ float w6s[9][8][6];
  __shared__ float bu3s[8];
  __shared__ float b6s[6];
  int blk = blockIdx.x;
  int b  = blk / 26;
  int t  = blk % 26;
  int th = t >> 1, tw = t & 1;
  int h0 = th*16, w0 = tw*64;
  int tid = threadIdx.x;
  for (int i=tid;i<256;i+=256){ u3s[i>>6][(i>>3)&7][i&7]=u3[i]; }
  for (int i=tid;i<432;i+=256){ int tap=i/48; int rem=i%48; w6s[tap][rem/6][rem%6]=w6[i]; }
  if (tid<8) bu3s[tid]=bu3[tid];
  if (tid<6) b6s[tid]=b6[tid];
  __syncthreads();
  for (int p=tid;p<18*66;p+=256){
    int r=p/66, c=p-(p/66)*66;
    int h=h0-1+r, w=w0-1+c;
    bool act = (h>=0 && h<NH0 && w>=0 && w<NW0) && m0[(b*NH0+h)*NW0+w];
    msl[r][c] = act?1:0;
    float v8[8];
    if (act){
      const float4* tp = (const float4*)(t4 + (((size_t)b*NH1 + (h>>1))*NW1 + (w>>1))*8);
      float4 q0=tp[0], q1=tp[1];
      float tin[8]={q0.x,q0.y,q0.z,q0.w,q1.x,q1.y,q1.z,q1.w};
      const float (*up)[8] = u3s[(h&1)*2+(w&1)];
      #pragma unroll
      for (int c8=0;c8<8;c8++) v8[c8]=bu3s[c8];
      #pragma unroll
      for (int ci=0;ci<8;ci++){
        float v=tin[ci];
        #pragma unroll
        for (int c8=0;c8<8;c8++) v8[c8]=fmaf(v, up[ci][c8], v8[c8]);
      }
    } else {
      #pragma unroll
      for (int c8=0;c8<8;c8++) v8[c8]=0.f;
    }
    #pragma unroll
    for (int c8=0;c8<8;c8++) vs[c8][r][c]=v8[c8];
  }
  __syncthreads();
  #pragma unroll 1
  for (int k=0;k<4;k++){
    int p = tid + k*256;
    int lh = p>>6, lw = p&63;
    int h = h0+lh, w = w0+lw;
    if (h >= NH0) continue;
    float acc[6];
    if (msl[lh+1][lw+1]){
      #pragma unroll
      for (int co=0;co<6;co++) acc[co]=b6s[co];
      #pragma unroll 1
      for (int kh=0;kh<3;kh++)
      #pragma unroll 1
      for (int kw=0;kw<3;kw++){
        const float (*wt)[6] = w6s[kh*3+kw];
        #pragma unroll
        for (int ci=0;ci<8;ci++){
          float v = vs[ci][lh+kh][lw+kw];
          #pragma unroll
          for (int co=0;co<6;co++) acc[co]=fmaf(v, wt[ci][co], acc[co]);
        }
      }
    } else {
      #pragma unroll
      for (int co=0;co<6;co++) acc[co]=0.f;
    }
    size_t base = (size_t)b*6*NH0*NW0 + (size_t)h*NW0 + w;
    #pragma unroll
    for (int co=0;co<6;co++) out[base + (size_t)co*NH0*NW0] = acc[co];
  }
}

extern "C" void kernel_launch(void* const* d_in, const int* in_sizes, int n_in,
                              void* d_out, int out_size, void* d_ws, size_t ws_size,
                              hipStream_t stream){
  (void)in_sizes; (void)n_in; (void)out_size; (void)ws_size;
  const float* x    = (const float*)d_in[0];
  const float* eps  = (const float*)d_in[1];
  const float* w1   = (const float*)d_in[2];
  const float* b1   = (const float*)d_in[3];
  const float* w2   = (const float*)d_in[4];
  const float* b2   = (const float*)d_in[5];
  const float* w3   = (const float*)d_in[6];
  const float* b3   = (const float*)d_in[7];
  const float* wmu  = (const float*)d_in[8];
  const float* bmu  = (const float*)d_in[9];
  const float* wlv  = (const float*)d_in[10];
  const float* blv  = (const float*)d_in[11];
  const float* wlin = (const float*)d_in[12];
  const float* blin = (const float*)d_in[13];
  const float* u1   = (const float*)d_in[14];
  const float* bu1  = (const float*)d_in[15];
  const float* w4   = (const float*)d_in[16];
  const float* b4   = (const float*)d_in[17];
  const float* u2   = (const float*)d_in[18];
  const float* bu2  = (const float*)d_in[19];
  const float* w5   = (const float*)d_in[20];
  const float* b5   = (const float*)d_in[21];
  const float* u3   = (const float*)d_in[22];
  const float* bu3  = (const float*)d_in[23];
  const float* w6   = (const float*)d_in[24];
  const float* b6   = (const float*)d_in[25];
  const float* fW1  = (const float*)d_in[26];
  const float* fb1  = (const float*)d_in[27];
  const float* fW2  = (const float*)d_in[28];
  const float* fb2  = (const float*)d_in[29];
  const float* fW3  = (const float*)d_in[30];
  const float* fb3  = (const float*)d_in[31];

  char* ws = (char*)d_ws;
  unsigned char* m0 = (unsigned char*)(ws);
  unsigned char* m1 = (unsigned char*)(ws + 3276800);
  unsigned char* m2 = (unsigned char*)(ws + 4096000);
  unsigned char* m3 = (unsigned char*)(ws + 4177920);
  float* y1p = (float*)(ws + 4194304);    // [B][100][64][8]
  float* y2p = (float*)(ws + 30408704);   // [B][20][32][16]
  float* y3p = (float*)(ws + 35651584);   // [B][4][16][32]
  float* dec = (float*)(ws + 36700160);   // [B][4][16][32]
  float* t2  = y2p;  // reuse
  float* t4  = y1p;  // reuse

  float* out   = (float*)d_out;
  float* o_mu  = out + 19660800;
  float* o_lv  = out + 19693568;
  float* o_kld = out + 19726336;
  float* o_zf  = out + 19726464;

  k_conv1pool<<< 7168,256,0,stream>>>(x, w1, b1, y1p, m0, m1);
  k_conv2pool<<< 1024,256,0,stream>>>(y1p, m1, w2, b2, y2p, m2);
  k_conv3pool<<<  128,256,0,stream>>>(y2p, m2, w3, b3, y3p, m3, o_kld);
  k_latent   <<<  512, 64,0,stream>>>(y3p, m3, eps, wmu,bmu,wlv,blv,wlin,blin,
                                      fW1,fb1,fW2,fb2,fW3,fb3, o_mu,o_lv,o_kld,o_zf, dec);
  k_ic4      <<<  512,256,0,stream>>>(dec, m2, u1, bu1, w4, b4, t2);
  k_ic5      <<< 5120,256,0,stream>>>(t2, m1, u2, bu2, w5, b5, t4);
  k_inv3conv6<<< 3328,256,0,stream>>>(t4, m0, u3, bu3, w6, b6, out);
}

// Round 10
// 437.068 us; speedup vs baseline: 3.5100x; 1.0079x over previous
//
#include <hip/hip_runtime.h>
#include <math.h>

constexpr int NB=128;
constexpr int NH0=200, NW0=128, NC0=6;
constexpr int NH1=100, NW1=64,  NC1=8;
constexpr int NH2=20,  NW2=32,  NC2=16;
constexpr int NH3=4,   NW3=16,  NC3=32;
constexpr int LAT=4, NPp=11, HID=16, NT=10;
constexpr float BOUNDf=5.0f;
constexpr float LOG2PI=1.8378770664093453f;

__device__ __forceinline__ float fexpf(float v){ return __expf(v); }
__device__ __forceinline__ float flogf(float v){ return __logf(v); }
__device__ __forceinline__ float softplusf(float v){ return v>20.f ? v : __logf(1.f+__expf(v)); }
__device__ __forceinline__ float lrelu(float v){ return v>0.f ? v : 0.01f*v; }

// ============ conv1 (3x3,6->8) + lrelu + pool2x2 ============
// one 2x2 pool window per thread; 32x32 pre-pool tile; weights live in regs per (ci,kh)
__global__ __launch_bounds__(256) void k_conv1pool(
    const float* __restrict__ x, const float* __restrict__ w1, const float* __restrict__ b1,
    float* __restrict__ y1p, unsigned char* __restrict__ m0, unsigned char* __restrict__ m1){
  __shared__ float xs[6][34][35];
  __shared__ float ws1[54][8];
  __shared__ float b1s[8];
  int blk = blockIdx.x;
  int b  = blk / 28;
  int t  = blk % 28;
  int th = t >> 2, tw = t & 3;      // th 0..6 (32 pre rows), tw 0..3 (32 pre cols)
  int h0 = th*32, w0 = tw*32;
  int tid = threadIdx.x;
  for (int i=tid;i<432;i+=256) ws1[i>>3][i&7] = w1[i];
  if (tid<8) b1s[tid]=b1[tid];
  for (int i=tid;i<6*34*34;i+=256){
    int ci=i/1156; int rem=i-ci*1156; int r2=rem/34, c2=rem-r2*34;
    int h=h0-1+r2, w=w0-1+c2;
    float v=0.f;
    if (h>=0 && h<NH0 && w>=0 && w<NW0) v = x[((size_t)(b*NC0+ci)*NH0+h)*NW0+w];
    xs[ci][r2][c2]=v;
  }
  __syncthreads();
  int r = tid>>4, c = tid&15;       // window (r,c): pre rows 2r,2r+1, cols 2c,2c+1
  // center-tap activity for the 4 pixels
  bool a00=false,a01=false,a10=false,a11=false;
  #pragma unroll
  for (int ci=0;ci<6;ci++){
    a00 |= (xs[ci][2*r+1][2*c+1]!=0.f);
    a01 |= (xs[ci][2*r+1][2*c+2]!=0.f);
    a10 |= (xs[ci][2*r+2][2*c+1]!=0.f);
    a11 |= (xs[ci][2*r+2][2*c+2]!=0.f);
  }
  float acc[4][8];
  #pragma unroll
  for (int px=0;px<4;px++)
    #pragma unroll
    for (int co=0;co<8;co++) acc[px][co]=b1s[co];
  #pragma unroll 1
  for (int ci=0;ci<6;ci++){
    #pragma unroll 1
    for (int kh=0;kh<3;kh++){
      const float* xr0 = &xs[ci][2*r+kh][2*c];
      const float* xr1 = &xs[ci][2*r+kh+1][2*c];
      float t0a=xr0[0], t0b=xr0[1], t0c=xr0[2], t0d=xr0[3];
      float t1a=xr1[0], t1b=xr1[1], t1c=xr1[2], t1d=xr1[3];
      const float4* wrow = (const float4*)&ws1[(kh*3)*6+ci][0];
      #pragma unroll
      for (int kw=0;kw<3;kw++){
        float4 wlo = wrow[kw*12], whi = wrow[kw*12+1];  // ws1 row stride = 6 rows of 8 floats = 12 float4
        float wv[8] = {wlo.x,wlo.y,wlo.z,wlo.w,whi.x,whi.y,whi.z,whi.w};
        float t00 = (kw==0)?t0a:((kw==1)?t0b:t0c);
        float t01 = (kw==0)?t0b:((kw==1)?t0c:t0d);
        float t10 = (kw==0)?t1a:((kw==1)?t1b:t1c);
        float t11 = (kw==0)?t1b:((kw==1)?t1c:t1d);
        #pragma unroll
        for (int co=0;co<8;co++){
          float wc = wv[co];
          acc[0][co]=fmaf(t00,wc,acc[0][co]);
          acc[1][co]=fmaf(t01,wc,acc[1][co]);
          acc[2][co]=fmaf(t10,wc,acc[2][co]);
          acc[3][co]=fmaf(t11,wc,acc[3][co]);
        }
      }
    }
  }
  int hA = h0 + 2*r;
  bool valid = (hA < NH0);
  bool anyact = (a00|a01|a10|a11) && valid;
  float best[8];
  #pragma unroll
  for (int co=0;co<8;co++){
    float v0 = a00 ? lrelu(acc[0][co]) : -1e30f;
    float v1 = a01 ? lrelu(acc[1][co]) : -1e30f;
    float v2 = a10 ? lrelu(acc[2][co]) : -1e30f;
    float v3 = a11 ? lrelu(acc[3][co]) : -1e30f;
    best[co] = fmaxf(fmaxf(v0,v1),fmaxf(v2,v3));
  }
  if (valid){
    int wA = w0 + 2*c;
    unsigned short p0 = (unsigned short)((a00?1:0) | ((a01?1:0)<<8));
    unsigned short p1 = (unsigned short)((a10?1:0) | ((a11?1:0)<<8));
    *(unsigned short*)(m0 + (size_t)(b*NH0+hA  )*NW0 + wA) = p0;
    *(unsigned short*)(m0 + (size_t)(b*NH0+hA+1)*NW0 + wA) = p1;
    int hp = th*16 + r, wp = tw*16 + c;
    float4 o0,o1;
    if (anyact){
      o0=make_float4(best[0],best[1],best[2],best[3]);
      o1=make_float4(best[4],best[5],best[6],best[7]);
    } else { o0=make_float4(0,0,0,0); o1=o0; }
    float4* yp = (float4*)(y1p + (((size_t)b*NH1+hp)*NW1+wp)*8);
    yp[0]=o0; yp[1]=o1;
    m1[(b*NH1+hp)*NW1+wp] = anyact?1:0;
  }
}

// ============ conv2 (3x3,8->16) + lrelu + pool 5x2, small-tile LDS, co-split ============
__global__ __launch_bounds__(256) void k_conv2pool(
    const float* __restrict__ yin, const unsigned char* __restrict__ m1,
    const float* __restrict__ w2, const float* __restrict__ b2,
    float* __restrict__ yout, unsigned char* __restrict__ m2){
  __shared__ float ys[8][27][35];
  __shared__ unsigned char msl[27][35];
  __shared__ float w2s[72][16];
  __shared__ float b2s[16];
  int blk = blockIdx.x;
  int b  = blk >> 3;
  int t  = blk & 7;
  int th = t >> 1, tw = t & 1;
  int r0 = th*25 - 1, c0 = tw*32 - 1;
  int tid = threadIdx.x;
  for (int i=tid;i<1152;i+=256) w2s[i>>4][i&15] = w2[i];
  if (tid<16) b2s[tid]=b2[tid];
  for (int p=tid;p<27*34;p+=256){
    int r=p/34, c=p-(p/34)*34;
    int h1=r0+r, w1c=c0+c;
    bool ok = (h1>=0 && h1<NH1 && w1c>=0 && w1c<NW1);
    msl[r][c] = ok ? m1[(b*NH1+h1)*NW1+w1c] : 0;
    float4 v0=make_float4(0,0,0,0), v1=v0;
    if (ok){
      const float4* pp = (const float4*)(yin + (((size_t)b*NH1+h1)*NW1+w1c)*8);
      v0=pp[0]; v1=pp[1];
    }
    ys[0][r][c]=v0.x; ys[1][r][c]=v0.y; ys[2][r][c]=v0.z; ys[3][r][c]=v0.w;
    ys[4][r][c]=v1.x; ys[5][r][c]=v1.y; ys[6][r][c]=v1.z; ys[7][r][c]=v1.w;
  }
  __syncthreads();
  if (tid < 160){
    int oid = tid >> 1, coq = tid & 1;
    int co0 = coq*8;
    int lh = oid >> 4, lw = oid & 15;
    int h2 = th*5+lh, w2c = tw*16+lw;
    float best[8];
    #pragma unroll
    for (int co=0;co<8;co++) best[co]=-1e30f;
    bool many=false;
    #pragma unroll 1
    for (int i=0;i<5;i++)
    #pragma unroll 1
    for (int j=0;j<2;j++){
      int r = lh*5+i+1, c = lw*2+j+1;
      if (!msl[r][c]) continue;
      many=true;
      float a[8];
      #pragma unroll
      for (int co=0;co<8;co++) a[co]=b2s[co0+co];
      #pragma unroll 1
      for (int kh=0;kh<3;kh++)
      #pragma unroll 1
      for (int kw=0;kw<3;kw++){
        #pragma unroll
        for (int ci=0;ci<8;ci++){
          float v = ys[ci][r-1+kh][c-1+kw];
          const float* wr = w2s[(kh*3+kw)*8+ci];
          #pragma unroll
          for (int co=0;co<8;co++) a[co]=fmaf(v,wr[co0+co],a[co]);
        }
      }
      #pragma unroll
      for (int co=0;co<8;co++) best[co]=fmaxf(best[co], lrelu(a[co]));
    }
    float4 o0,o1;
    if (many){
      o0=make_float4(best[0],best[1],best[2],best[3]);
      o1=make_float4(best[4],best[5],best[6],best[7]);
    } else { o0=make_float4(0,0,0,0); o1=o0; }
    float4* op = (float4*)(yout + (((size_t)b*NH2+h2)*NW2+w2c)*16 + co0);
    op[0]=o0; op[1]=o1;
    if (coq==0) m2[(b*NH2+h2)*NW2+w2c] = many?1:0;
  }
}

// ============ conv3 (3x3,16->32) + lrelu + pool 5x2, per-batch LDS-tiled ============
__global__ __launch_bounds__(256) void k_conv3pool(
    const float* __restrict__ yin, const unsigned char* __restrict__ m2,
    const float* __restrict__ w3, const float* __restrict__ b3,
    float* __restrict__ yout, unsigned char* __restrict__ m3,
    float* __restrict__ out_kld){
  __shared__ float ys[16][20][33];
  __shared__ unsigned char msl[20][32];
  __shared__ float w3s[144][32];
  __shared__ float b3s[32];
  int b = blockIdx.x;
  int tid = threadIdx.x;
  if (tid==0) out_kld[b]=0.f;
  for (int i=tid;i<4608;i+=256) w3s[i>>5][i&31] = w3[i];
  if (tid<32) b3s[tid]=b3[tid];
  for (int p=tid;p<640;p+=256){
    int r=p>>5, c=p&31;
    msl[r][c] = m2[(b*NH2+r)*NW2+c];
    const float4* pp = (const float4*)(yin + (((size_t)b*NH2+r)*NW2+c)*16);
    float4 q0=pp[0],q1=pp[1],q2=pp[2],q3=pp[3];
    ys[0][r][c]=q0.x; ys[1][r][c]=q0.y; ys[2][r][c]=q0.z; ys[3][r][c]=q0.w;
    ys[4][r][c]=q1.x; ys[5][r][c]=q1.y; ys[6][r][c]=q1.z; ys[7][r][c]=q1.w;
    ys[8][r][c]=q2.x; ys[9][r][c]=q2.y; ys[10][r][c]=q2.z; ys[11][r][c]=q2.w;
    ys[12][r][c]=q3.x; ys[13][r][c]=q3.y; ys[14][r][c]=q3.z; ys[15][r][c]=q3.w;
  }
  __syncthreads();
  int p = tid>>2, coq = tid&3;
  int co0 = coq*8;
  int hp = p>>4, wp = p&15;
  float best[8];
  #pragma unroll
  for (int co=0;co<8;co++) best[co]=-1e30f;
  bool many=false;
  #pragma unroll 1
  for (int i=0;i<5;i++)
  #pragma unroll 1
  for (int j=0;j<2;j++){
    int h2 = hp*5+i, w2c = wp*2+j;
    if (!msl[h2][w2c]) continue;
    many=true;
    float a[8];
    #pragma unroll
    for (int co=0;co<8;co++) a[co]=b3s[co0+co];
    #pragma unroll 1
    for (int kh=0;kh<3;kh++){
      int hh=h2+kh-1;
      if (hh<0||hh>=NH2) continue;
      #pragma unroll 1
      for (int kw=0;kw<3;kw++){
        int ww=w2c+kw-1;
        if (ww<0||ww>=NW2) continue;
        #pragma unroll
        for (int ci=0;ci<16;ci++){
          float v = ys[ci][hh][ww];
          const float* wr = w3s[(kh*3+kw)*16+ci];
          #pragma unroll
          for (int co=0;co<8;co++) a[co]=fmaf(v,wr[co0+co],a[co]);
        }
      }
    }
    #pragma unroll
    for (int co=0;co<8;co++) best[co]=fmaxf(best[co], lrelu(a[co]));
  }
  float4 o0,o1;
  if (many){
    o0=make_float4(best[0],best[1],best[2],best[3]);
    o1=make_float4(best[4],best[5],best[6],best[7]);
  } else { o0=make_float4(0,0,0,0); o1=o0; }
  float4* op = (float4*)(yout + ((size_t)(b*64+p))*32 + co0);
  op[0]=o0; op[1]=o1;
  if (coq==0) m3[b*64+p] = many?1:0;
}

// ============ latent head + NSF flow + kld + dec; 4 lanes per position ============
__global__ __launch_bounds__(64) void k_latent(
    const float* __restrict__ y3p, const unsigned char* __restrict__ m3,
    const float* __restrict__ eps,
    const float* __restrict__ wmu, const float* __restrict__ bmu,
    const float* __restrict__ wlv, const float* __restrict__ blv,
    const float* __restrict__ wlin, const float* __restrict__ blin,
    const float* __restrict__ fW1, const float* __restrict__ fb1,
    const float* __restrict__ fW2, const float* __restrict__ fb2,
    const float* __restrict__ fW3, const float* __restrict__ fb3,
    float* __restrict__ out_mu, float* __restrict__ out_lv,
    float* __restrict__ out_kld, float* __restrict__ out_zf,
    float* __restrict__ dec)
{
  __shared__ __align__(16) float sW1[NT*HID*LAT];
  __shared__ float sb1[NT*HID];
  __shared__ __align__(16) float sW2[NT*HID*HID];
  __shared__ float sb2[NT*HID];
  __shared__ __align__(16) float sW3[NT*LAT*NPp*HID];
  __shared__ float sb3[NT*LAT*NPp];
  __shared__ __align__(16) float swmu[LAT*NC3];
  __shared__ __align__(16) float swlv[LAT*NC3];
  __shared__ __align__(16) float slin[NC3*LAT];
  __shared__ float sbmu[LAT], sblv[LAT], sblin[NC3];
  int tid = threadIdx.x;
  for (int i=tid;i<NT*HID*LAT;i+=64){ int j=i&3; int r=(i>>2)%HID; sW1[i]=fW1[i]*(((r%3+1)>=(j+1))?1.f:0.f); }
  for (int i=tid;i<NT*HID;i+=64){ sb1[i]=fb1[i]; sb2[i]=fb2[i]; }
  for (int i=tid;i<NT*HID*HID;i+=64){ int j=i&15; int r=(i>>4)%HID; sW2[i]=fW2[i]*(((r%3+1)>=(j%3+1))?1.f:0.f); }
  for (int i=tid;i<NT*LAT*NPp*HID;i+=64){ int j=i&15; int r=(i>>4)%(LAT*NPp); sW3[i]=fW3[i]*(((r/NPp+1)>(j%3+1))?1.f:0.f); }
  for (int i=tid;i<NT*LAT*NPp;i+=64) sb3[i]=fb3[i];
  for (int i=tid;i<LAT*NC3;i+=64){ swmu[i]=wmu[i]; swlv[i]=wlv[i]; slin[i]=wlin[i]; }
  if (tid<LAT){ sbmu[tid]=bmu[tid]; sblv[tid]=blv[tid]; }
  for (int i=tid;i<NC3;i+=64) sblin[i]=blin[i];
  __syncthreads();

  int blk = blockIdx.x;
  int b   = blk >> 2;
  int gpos = b*64 + (blk&3)*16 + (tid>>2);
  int g = tid & 3;
  bool msk = m3[gpos]!=0;
  float kld_part = 0.f;
  if (msk){
    const float4* yp = (const float4*)(y3p + (size_t)gpos*NC3);
    const float4* wm = (const float4*)(swmu + g*NC3);
    const float4* wl = (const float4*)(swlv + g*NC3);
    float mu_g = sbmu[g], lv_g = sblv[g];
    #pragma unroll
    for (int q=0;q<8;q++){
      float4 yq = yp[q], a = wm[q], c = wl[q];
      mu_g = fmaf(yq.x,a.x, fmaf(yq.y,a.y, fmaf(yq.z,a.z, fmaf(yq.w,a.w, mu_g))));
      lv_g = fmaf(yq.x,c.x, fmaf(yq.y,c.y, fmaf(yq.z,c.z, fmaf(yq.w,c.w, lv_g))));
    }
    float std_g = fexpf(0.5f*lv_g);
    float ev_g  = eps[(size_t)gpos*LAT+g];
    float z0_g  = fmaf(ev_g, std_g, mu_g);
    float zg = z0_g;
    float z[4];
    z[g]=zg; z[g^1]=__shfl_xor(zg,1); z[g^2]=__shfl_xor(zg,2); z[g^3]=__shfl_xor(zg,3);
    float ld_g = 0.f;
    for (int t=0;t<NT;t++){
      float h1[16];
      const float4* W1t = (const float4*)(sW1 + t*HID*LAT);
      const float*  b1t = sb1 + t*HID;
      #pragma unroll
      for (int i2=0;i2<16;i2++){
        float4 w = W1t[i2];
        float a = b1t[i2];
        a = fmaf(z[0],w.x, fmaf(z[1],w.y, fmaf(z[2],w.z, fmaf(z[3],w.w, a))));
        h1[i2]=fmaxf(a,0.f);
      }
      float h2o[4];
      const float* W2t = sW2 + t*HID*HID;
      const float* b2t = sb2 + t*HID;
      #pragma unroll
      for (int k=0;k<4;k++){
        int row = g*4+k;
        const float4* wr = (const float4*)(W2t + row*HID);
        float a = b2t[row];
        #pragma unroll
        for (int q=0;q<4;q++){
          float4 w = wr[q];
          a = fmaf(h1[q*4+0],w.x, fmaf(h1[q*4+1],w.y, fmaf(h1[q*4+2],w.z, fmaf(h1[q*4+3],w.w, a))));
        }
        h2o[k]=fmaxf(a,0.f);
      }
      float h2[16];
      #pragma unroll
      for (int k=0;k<4;k++) h2[g*4+k]=h2o[k];
      #pragma unroll
      for (int mski=1;mski<4;mski++){
        int og = g^mski;
        #pragma unroll
        for (int k=0;k<4;k++) h2[og*4+k]=__shfl_xor(h2o[k],mski);
      }
      float p[NPp];
      const float* W3t = sW3 + t*LAT*NPp*HID;
      const float* b3t = sb3 + t*LAT*NPp;
      #pragma unroll
      for (int r=0;r<NPp;r++){
        int row = g*NPp+r;
        const float4* wr = (const float4*)(W3t + row*HID);
        float a = b3t[row];
        #pragma unroll
        for (int q=0;q<4;q++){
          float4 w = wr[q];
          a = fmaf(h2[q*4+0],w.x, fmaf(h2[q*4+1],w.y, fmaf(h2[q*4+2],w.z, fmaf(h2[q*4+3],w.w, a))));
        }
        p[r]=a;
      }
      float mw=fmaxf(fmaxf(p[0],p[1]),fmaxf(p[2],p[3]));
      float e0=fexpf(p[0]-mw), e1=fexpf(p[1]-mw), e2=fexpf(p[2]-mw), e3=fexpf(p[3]-mw);
      float wsc=10.f/(e0+e1+e2+e3);
      float xk1=fmaf(e0,wsc,-BOUNDf), xk2=fmaf(e1,wsc,xk1), xk3=fmaf(e2,wsc,xk2), xk4=fmaf(e3,wsc,xk3);
      float mh=fmaxf(fmaxf(p[4],p[5]),fmaxf(p[6],p[7]));
      float f0=fexpf(p[4]-mh), f1=fexpf(p[5]-mh), f2=fexpf(p[6]-mh), f3=fexpf(p[7]-mh);
      float hsc=10.f/(f0+f1+f2+f3);
      float yk1=fmaf(f0,hsc,-BOUNDf), yk2=fmaf(f1,hsc,yk1), yk3=fmaf(f2,hsc,yk2), yk4=fmaf(f3,hsc,yk3);
      float dk1=softplusf(p[8]), dk2=softplusf(p[9]), dk3=softplusf(p[10]);
      float xv=z[g];
      bool inside = (xv>=-BOUNDf)&&(xv<=BOUNDf);
      float xc=fminf(fmaxf(xv,-BOUNDf),BOUNDf);
      float x0=-BOUNDf, x1=xk1, y0=-BOUNDf, y1=yk1, d0=1.f, d1=dk1;
      if (xc>=xk1){x0=xk1;x1=xk2;y0=yk1;y1=yk2;d0=dk1;d1=dk2;}
      if (xc>=xk2){x0=xk2;x1=xk3;y0=yk2;y1=yk3;d0=dk2;d1=dk3;}
      if (xc>=xk3){x0=xk3;x1=xk4;y0=yk3;y1=yk4;d0=dk3;d1=1.f;}
      float dxv=x1-x0, dyv=y1-y0;
      float sl=dyv/dxv, ttv=(xc-x0)/dxv, omt=1.f-ttv;
      float den=sl + (d1+d0-2.f*sl)*ttv*omt;
      float yo=y0 + dyv*(sl*ttv*ttv + d0*ttv*omt)/den;
      float ldv=flogf(sl*sl*(d1*ttv*ttv + 2.f*sl*ttv*omt + d0*omt*omt)) - 2.f*flogf(den);
      float zn_g = inside ? yo : xv;
      ld_g += inside ? ldv : 0.f;
      float znf[4];
      znf[g]=zn_g; znf[g^1]=__shfl_xor(zn_g,1); znf[g^2]=__shfl_xor(zn_g,2); znf[g^3]=__shfl_xor(zn_g,3);
      if (t<NT-1){ z[0]=znf[3]; z[1]=znf[2]; z[2]=znf[1]; z[3]=znf[0]; }
      else       { z[0]=znf[0]; z[1]=znf[1]; z[2]=znf[2]; z[3]=znf[3]; }
    }
    float lq_g = -0.5f*ev_g*ev_g - 0.5f*lv_g - 0.5f*LOG2PI;
    float lp_g = -0.5f*z[g]*z[g] - 0.5f*LOG2PI;
    kld_part = lq_g - ld_g - lp_g;
    out_mu[(size_t)gpos*LAT+g]=mu_g;
    out_lv[(size_t)gpos*LAT+g]=lv_g;
    out_zf[(size_t)gpos*LAT+g]=z[g];
    float4 d0v, d1v;
    {
      float dv[8];
      #pragma unroll
      for (int k=0;k<8;k++){
        int c = g*8+k;
        const float4 w = ((const float4*)slin)[c];
        dv[k] = fmaf(z[0],w.x, fmaf(z[1],w.y, fmaf(z[2],w.z, fmaf(z[3],w.w, sblin[c]))));
      }
      d0v=make_float4(dv[0],dv[1],dv[2],dv[3]);
      d1v=make_float4(dv[4],dv[5],dv[6],dv[7]);
    }
    float4* dp = (float4*)(dec + (size_t)gpos*NC3 + g*8);
    dp[0]=d0v; dp[1]=d1v;
  } else {
    out_mu[(size_t)gpos*LAT+g]=0.f;
    out_lv[(size_t)gpos*LAT+g]=0.f;
    out_zf[(size_t)gpos*LAT+g]=0.f;
    float4 zv = make_float4(0,0,0,0);
    float4* dp = (float4*)(dec + (size_t)gpos*NC3 + g*8);
    dp[0]=zv; dp[1]=zv;
  }
  float s = kld_part;
  s += __shfl_xor(s,1);  s += __shfl_xor(s,2);
  s += __shfl_xor(s,4);  s += __shfl_xor(s,8);
  s += __shfl_xor(s,16); s += __shfl_xor(s,32);
  if (tid==0) atomicAdd(&out_kld[b], s);
}

// ============ fused invconv1(5,2,32,32) + conv4(3x3,32->16) -> t2, mask m2 ============
__global__ __launch_bounds__(256) void k_ic4(
    const float* __restrict__ dec, const unsigned char* __restrict__ m2,
    const float* __restrict__ u1, const float* __restrict__ bu1,
    const float* __restrict__ w4, const float* __restrict__ b4,
    float* __restrict__ t2){
  __shared__ __align__(16) float vs[12][18][32];
  __shared__ __align__(16) float w4s[288][16];
  __shared__ unsigned char msl[12][18];
  int blk = blockIdx.x;
  int b  = blk >> 2;
  int t  = blk & 3;
  int th = t >> 1, tw = t & 1;
  int h0 = th*10, w0 = tw*16;
  int tid = threadIdx.x;
  for (int i=tid;i<288*16;i+=256) w4s[i>>4][i&15] = w4[i];
  if (tid < 216){
    int lr = tid/18, lc = tid%18;
    int h2 = h0-1+lr, w2 = w0-1+lc;
    bool mk = (h2>=0 && h2<NH2 && w2>=0 && w2<NW2) && m2[(b*NH2+h2)*NW2+w2];
    msl[lr][lc] = mk?1:0;
    float acc[32];
    if (mk){
      const float* dp = dec + (((size_t)b*NH3 + h2/5)*NW3 + w2/2)*NC3;
      const float* up = u1 + ((h2%5)*2 + (w2&1))*1024;
      #pragma unroll
      for (int co=0;co<32;co++) acc[co]=bu1[co];
      #pragma unroll 1
      for (int ci=0;ci<32;ci++){
        float dv = dp[ci];
        const float* ur = up + ci*32;
        #pragma unroll
        for (int co=0;co<32;co++) acc[co]=fmaf(dv,ur[co],acc[co]);
      }
    } else {
      #pragma unroll
      for (int co=0;co<32;co++) acc[co]=0.f;
    }
    #pragma unroll
    for (int co=0;co<32;co++) vs[lr][lc][co]=acc[co];
  }
  __syncthreads();
  if (tid < 160){
    int lh = tid/16, lw = tid%16;
    int h2 = h0+lh, w2 = w0+lw;
    float a[16];
    if (msl[lh+1][lw+1]){
      #pragma unroll
      for (int co=0;co<16;co++) a[co]=b4[co];
      #pragma unroll 1
      for (int kh=0;kh<3;kh++)
      #pragma unroll 1
      for (int kw=0;kw<3;kw++){
        const float* vp = vs[lh+kh][lw+kw];
        #pragma unroll
        for (int ci=0;ci<32;ci++){
          float v = vp[ci];
          const float* wr = w4s[(kh*3+kw)*32+ci];
          #pragma unroll
          for (int co=0;co<16;co++) a[co]=fmaf(v,wr[co],a[co]);
        }
      }
    } else {
      #pragma unroll
      for (int co=0;co<16;co++) a[co]=0.f;
    }
    float* op = t2 + (((size_t)b*NH2+h2)*NW2+w2)*NC2;
    #pragma unroll
    for (int co=0;co<16;co++) op[co]=a[co];
  }
}

// ============ fused invconv2(5,2,16,16) + conv5(3x3,16->8) -> t4, mask m1 ============
__global__ __launch_bounds__(256) void k_ic5(
    const float* __restrict__ t2, const unsigned char* __restrict__ m1,
    const float* __restrict__ u2, const float* __restrict__ bu2,
    const float* __restrict__ w5, const float* __restrict__ b5,
    float* __restrict__ t4){
  __shared__ __align__(16) float vs[12][18][16];
  __shared__ __align__(16) float w5s[144][8];
  __shared__ unsigned char msl[12][18];
  int blk = blockIdx.x;
  int b  = blk / 40;
  int t  = blk % 40;
  int th = t >> 2, tw = t & 3;
  int h0 = th*10, w0 = tw*16;
  int tid = threadIdx.x;
  for (int i=tid;i<144*8;i+=256) w5s[i>>3][i&7] = w5[i];
  if (tid < 216){
    int lr = tid/18, lc = tid%18;
    int h1 = h0-1+lr, w1c = w0-1+lc;
    bool mk = (h1>=0 && h1<NH1 && w1c>=0 && w1c<NW1) && m1[(b*NH1+h1)*NW1+w1c];
    msl[lr][lc] = mk?1:0;
    float acc[16];
    if (mk){
      const float* dp = t2 + (((size_t)b*NH2 + h1/5)*NW2 + w1c/2)*NC2;
      const float* up = u2 + ((h1%5)*2 + (w1c&1))*256;
      #pragma unroll
      for (int co=0;co<16;co++) acc[co]=bu2[co];
      #pragma unroll 1
      for (int ci=0;ci<16;ci++){
        float dv = dp[ci];
        const float* ur = up + ci*16;
        #pragma unroll
        for (int co=0;co<16;co++) acc[co]=fmaf(dv,ur[co],acc[co]);
      }
    } else {
      #pragma unroll
      for (int co=0;co<16;co++) acc[co]=0.f;
    }
    #pragma unroll
    for (int co=0;co<16;co++) vs[lr][lc][co]=acc[co];
  }
  __syncthreads();
  if (tid < 160){
    int lh = tid/16, lw = tid%16;
    int h1 = h0+lh, w1c = w0+lw;
    float a[8];
    if (msl[lh+1][lw+1]){
      #pragma unroll
      for (int co=0;co<8;co++) a[co]=b5[co];
      #pragma unroll 1
      for (int kh=0;kh<3;kh++)
      #pragma unroll 1
      for (int kw=0;kw<3;kw++){
        const float* vp = vs[lh+kh][lw+kw];
        #pragma unroll
        for (int ci=0;ci<16;ci++){
          float v = vp[ci];
          const float* wr = w5s[(kh*3+kw)*16+ci];
          #pragma unroll
          for (int co=0;co<8;co++) a[co]=fmaf(v,wr[co],a[co]);
        }
      }
    } else {
      #pragma unroll
      for (int co=0;co<8;co++) a[co]=0.f;
    }
    float* op = t4 + (((size_t)b*NH1+h1)*NW1+w1c)*NC1;
    #pragma unroll
    for (int co=0;co<8;co++) op[co]=a[co];
  }
}

// ============ fused invconv3 (2,2,8,8) + conv6 (3x3,8->6), two-phase LDS ============
__global__ __launch_bounds__(256) void k_inv3conv6(
    const float* __restrict__ t4, const unsigned char* __restrict__ m0,
    const float* __restrict__ u3, const float* __restrict__ bu3,
    const float* __restrict__ w6, const float* __restrict__ b6,
    float* __restrict__ out){
  __shared__ float vs[8][18][68];
  __shared__ unsigned char msl[18][66];
  __shared__ float u3s[4][8][8];
  __shared__ float w6s[9][8][6];
  __shared__ float bu3s[8];
  __shared__ float b6s[6];
  int blk = blockIdx.x;
  int b  = blk / 26;
  int t  = blk % 26;
  int th = t >> 1, tw = t & 1;
  int h0 = th*16, w0 = tw*64;
  int tid = threadIdx.x;
  for (int i=tid;i<256;i+=256){ u3s[i>>6][(i>>3)&7][i&7]=u3[i]; }
  for (int i=tid;i<432;i+=256){ int tap=i/48; int rem=i%48; w6s[tap][rem/6][rem%6]=w6[i]; }
  if (tid<8) bu3s[tid]=bu3[tid];
  if (tid<6) b6s[tid]=b6[tid];
  __syncthreads();
  for (int p=tid;p<18*66;p+=256){
    int r=p/66, c=p-(p/66)*66;
    int h=h0-1+r, w=w0-1+c;
    bool act = (h>=0 && h<NH0 && w>=0 && w<NW0) && m0[(b*NH0+h)*NW0+w];
    msl[r][c] = act?1:0;
    float v8[8];
    if (act){
      const float4* tp = (const float4*)(t4 + (((size_t)b*NH1 + (h>>1))*NW1 + (w>>1))*8);
      float4 q0=tp[0], q1=tp[1];
      float tin[8]={q0.x,q0.y,q0.z,q0.w,q1.x,q1.y,q1.z,q1.w};
      const float (*up)[8] = u3s[(h&1)*2+(w&1)];
      #pragma unroll
      for (int c8=0;c8<8;c8++) v8[c8]=bu3s[c8];
      #pragma unroll
      for (int ci=0;ci<8;ci++){
        float v=tin[ci];
        #pragma unroll
        for (int c8=0;c8<8;c8++) v8[c8]=fmaf(v, up[ci][c8], v8[c8]);
      }
    } else {
      #pragma unroll
      for (int c8=0;c8<8;c8++) v8[c8]=0.f;
    }
    #pragma unroll
    for (int c8=0;c8<8;c8++) vs[c8][r][c]=v8[c8];
  }
  __syncthreads();
  #pragma unroll 1
  for (int k=0;k<4;k++){
    int p = tid + k*256;
    int lh = p>>6, lw = p&63;
    int h = h0+lh, w = w0+lw;
    if (h >= NH0) continue;
    float acc[6];
    if (msl[lh+1][lw+1]){
      #pragma unroll
      for (int co=0;co<6;co++) acc[co]=b6s[co];
      #pragma unroll 1
      for (int kh=0;kh<3;kh++)
      #pragma unroll 1
      for (int kw=0;kw<3;kw++){
        const float (*wt)[6] = w6s[kh*3+kw];
        #pragma unroll
        for (int ci=0;ci<8;ci++){
          float v = vs[ci][lh+kh][lw+kw];
          #pragma unroll
          for (int co=0;co<6;co++) acc[co]=fmaf(v, wt[ci][co], acc[co]);
        }
      }
    } else {
      #pragma unroll
      for (int co=0;co<6;co++) acc[co]=0.f;
    }
    size_t base = (size_t)b*6*NH0*NW0 + (size_t)h*NW0 + w;
    #pragma unroll
    for (int co=0;co<6;co++) out[base + (size_t)co*NH0*NW0] = acc[co];
  }
}

extern "C" void kernel_launch(void* const* d_in, const int* in_sizes, int n_in,
                              void* d_out, int out_size, void* d_ws, size_t ws_size,
                              hipStream_t stream){
  (void)in_sizes; (void)n_in; (void)out_size; (void)ws_size;
  const float* x    = (const float*)d_in[0];
  const float* eps  = (const float*)d_in[1];
  const float* w1   = (const float*)d_in[2];
  const float* b1   = (const float*)d_in[3];
  const float* w2   = (const float*)d_in[4];
  const float* b2   = (const float*)d_in[5];
  const float* w3   = (const float*)d_in[6];
  const float* b3   = (const float*)d_in[7];
  const float* wmu  = (const float*)d_in[8];
  const float* bmu  = (const float*)d_in[9];
  const float* wlv  = (const float*)d_in[10];
  const float* blv  = (const float*)d_in[11];
  const float* wlin = (const float*)d_in[12];
  const float* blin = (const float*)d_in[13];
  const float* u1   = (const float*)d_in[14];
  const float* bu1  = (const float*)d_in[15];
  const float* w4   = (const float*)d_in[16];
  const float* b4   = (const float*)d_in[17];
  const float* u2   = (const float*)d_in[18];
  const float* bu2  = (const float*)d_in[19];
  const float* w5   = (const float*)d_in[20];
  const float* b5   = (const float*)d_in[21];
  const float* u3   = (const float*)d_in[22];
  const float* bu3  = (const float*)d_in[23];
  const float* w6   = (const float*)d_in[24];
  const float* b6   = (const float*)d_in[25];
  const float* fW1  = (const float*)d_in[26];
  const float* fb1  = (const float*)d_in[27];
  const float* fW2  = (const float*)d_in[28];
  const float* fb2  = (const float*)d_in[29];
  const float* fW3  = (const float*)d_in[30];
  const float* fb3  = (const float*)d_in[31];

  char* ws = (char*)d_ws;
  unsigned char* m0 = (unsigned char*)(ws);
  unsigned char* m1 = (unsigned char*)(ws + 3276800);
  unsigned char* m2 = (unsigned char*)(ws + 4096000);
  unsigned char* m3 = (unsigned char*)(ws + 4177920);
  float* y1p = (float*)(ws + 4194304);    // [B][100][64][8]
  float* y2p = (float*)(ws + 30408704);   // [B][20][32][16]
  float* y3p = (float*)(ws + 35651584);   // [B][4][16][32]
  float* dec = (float*)(ws + 36700160);   // [B][4][16][32]
  float* t2  = y2p;  // reuse
  float* t4  = y1p;  // reuse

  float* out   = (float*)d_out;
  float* o_mu  = out + 19660800;
  float* o_lv  = out + 19693568;
  float* o_kld = out + 19726336;
  float* o_zf  = out + 19726464;

  k_conv1pool<<< 3584,256,0,stream>>>(x, w1, b1, y1p, m0, m1);
  k_conv2pool<<< 1024,256,0,stream>>>(y1p, m1, w2, b2, y2p, m2);
  k_conv3pool<<<  128,256,0,stream>>>(y2p, m2, w3, b3, y3p, m3, o_kld);
  k_latent   <<<  512, 64,0,stream>>>(y3p, m3, eps, wmu,bmu,wlv,blv,wlin,blin,
                                      fW1,fb1,fW2,fb2,fW3,fb3, o_mu,o_lv,o_kld,o_zf, dec);
  k_ic4      <<<  512,256,0,stream>>>(dec, m2, u1, bu1, w4, b4, t2);
  k_ic5      <<< 5120,256,0,stream>>>(t2, m1, u2, bu2, w5, b5, t4);
  k_inv3conv6<<< 3328,256,0,stream>>>(t4, m0, u3, bu3, w6, b6, out);
}